// Round 7
// baseline (2480.255 us; speedup 1.0000x reference)
//
#include <hip/hip_runtime.h>
#include <hip/hip_bf16.h>

typedef __hip_bfloat16 bf16;

#define NN 32768   // total nodes
#define EE 262144  // edges
#define GG 512     // graphs

// ---- staged fp32 input offsets (element units) ----
#define O_T      0
#define O_V      393216
#define O_WT     786432
#define O_BT     884736
#define O_WV     884864
#define O_BV     983168
#define O_EMB    983296
#define O_WNODE  989824
#define O_BNODE  1006208
#define O_WSTART 1006336
#define O_BSTART 1039104
#define O_LNG    1039232
#define O_LNB    1039360
#define O_W1     1039488
#define O_ASRC1  1105024
#define O_ADST1  1105536
#define O_B1     1106048
#define O_W2     1106560
#define O_ASRC2  1172096
#define O_ADST2  1172224
#define O_B2     1172352
#define O_WO1    1172480
#define O_BO1    1188864
#define O_WO2    1188992
#define O_BO2    1189120
#define O_TOTAL  1189121

__device__ __forceinline__ float loadf(const float* p) { return *p; }
__device__ __forceinline__ float loadf(const bf16* p) { return __bfloat162float(*p); }

// ---------------- dtype probe ----------------
__global__ __launch_bounds__(256) void probe_kernel(const void* t, int* flag) {
  const unsigned short* u = (const unsigned short*)t;
  int big = 0;
  for (int k = threadIdx.x; k < 1024; k += 256) {
    unsigned e = (u[k] >> 7) & 0xFF;
    if (e >= 141) big = 1;
  }
  __shared__ int sh;
  if (threadIdx.x == 0) sh = 0;
  __syncthreads();
  if (big) atomicOr(&sh, 1);
  __syncthreads();
  if (threadIdx.x == 0) *flag = sh;  // 1 = fp32, 0 = bf16
}

// ---------------- stage all float inputs as fp32 ----------------
__global__ __launch_bounds__(256) void cvt_kernel(
    const void* p0, const void* p1, const void* p2, const void* p3, const void* p4,
    const void* p5, const void* p6, const void* p7, const void* p8, const void* p9,
    const void* p10, const void* p11, const void* p12, const void* p13, const void* p14,
    const void* p15, const void* p16, const void* p17, const void* p18, const void* p19,
    const void* p20, const void* p21, const void* p22, const void* p23, const void* p24,
    const int* flag, float* dst) {
  const void* srcs[25] = {p0, p1, p2, p3, p4, p5, p6, p7, p8, p9, p10, p11, p12,
                          p13, p14, p15, p16, p17, p18, p19, p20, p21, p22, p23, p24};
  const int off[26] = {O_T, O_V, O_WT, O_BT, O_WV, O_BV, O_EMB, O_WNODE, O_BNODE,
                       O_WSTART, O_BSTART, O_LNG, O_LNB, O_W1, O_ASRC1, O_ADST1,
                       O_B1, O_W2, O_ASRC2, O_ADST2, O_B2, O_WO1, O_BO1, O_WO2,
                       O_BO2, O_TOTAL};
  bool f32 = (*flag != 0);
  int i = blockIdx.x * 256 + threadIdx.x;
  if (i >= O_TOTAL) return;
  int tsel = 0;
#pragma unroll
  for (int k = 1; k < 25; k++)
    if (i >= off[k]) tsel = k;
  int j = i - off[tsel];
  const void* s = srcs[tsel];
  dst[i] = f32 ? ((const float*)s)[j] : __bfloat162float(((const bf16*)s)[j]);
}

// ---------------- CSR build ----------------
__global__ __launch_bounds__(256) void hist_kernel(const int* __restrict__ dst,
                                                   int* __restrict__ indeg) {
  int e = blockIdx.x * 256 + threadIdx.x;
  if (e < EE) atomicAdd(&indeg[dst[e]], 1);
}

__global__ __launch_bounds__(256) void scanA_kernel(const int* indeg, int* bsum) {
  int t = threadIdx.x;
  int s = 0;
  for (int j = 0; j < 128; j++) s += indeg[t * 128 + j];
  bsum[t] = s;
}
__global__ void scanB_kernel(const int* bsum, int* bpre) {
  int run = 0;
  for (int k = 0; k < 256; k++) { bpre[k] = run; run += bsum[k]; }
}
__global__ __launch_bounds__(256) void scanC_kernel(const int* indeg, const int* bpre,
                                                    int* off, int* cursor) {
  int t = threadIdx.x;
  int run = bpre[t];
  for (int j = 0; j < 128; j++) {
    int i = t * 128 + j;
    off[i] = run; cursor[i] = run; run += indeg[i];
  }
  if (t == 255) off[NN] = run;
}

__global__ __launch_bounds__(256) void fill_kernel(const int* __restrict__ src,
                                                   const int* __restrict__ dst,
                                                   int* __restrict__ cursor,
                                                   int* __restrict__ esrc) {
  int e = blockIdx.x * 256 + threadIdx.x;
  if (e < EE) {
    int p = atomicAdd(&cursor[dst[e]], 1);
    esrc[p] = src[e];
  }
}

// ---------------- naive GEMM: one thread per output ----------------
template <typename TA>
__global__ __launch_bounds__(256) void ngemm_kernel(const TA* __restrict__ A,
                                                    const float* __restrict__ B,
                                                    const float* __restrict__ bias,
                                                    float* __restrict__ C,
                                                    int M, int N, int K, int ldc, int act) {
  long gid = (long)blockIdx.x * 256 + threadIdx.x;
  if (gid >= (long)M * N) return;
  int m = (int)(gid / N), n = (int)(gid % N);
  float acc = bias ? bias[n] : 0.f;
  for (int k = 0; k < K; k++)
    acc = fmaf(loadf(&A[(size_t)m * K + k]), B[(size_t)k * N + n], acc);
  if (act == 1) acc = acc > 0.f ? acc : 0.01f * acc;
  C[(size_t)m * ldc + n] = acc;
}

// ---------------- naive layernorm: one thread per node ----------------
__global__ __launch_bounds__(256) void ln_naive(const float* __restrict__ start,
                                                const float* __restrict__ emb2,
                                                const int* __restrict__ m_idx,
                                                const float* __restrict__ lng,
                                                const float* __restrict__ lnb,
                                                float* __restrict__ x0) {
  int i = blockIdx.x * 256 + threadIdx.x;
  if (i >= NN) return;
  int g = i >> 6, n = i & 63;
  const float* row = (n == 0) ? (start + (size_t)g * 128) : (emb2 + (size_t)m_idx[i] * 128);
  float mu = 0.f;
  for (int c = 0; c < 128; c++) mu += row[c];
  mu *= (1.f / 128.f);
  float var = 0.f;
  for (int c = 0; c < 128; c++) { float d = row[c] - mu; var += d * d; }
  var *= (1.f / 128.f);
  float rstd = rsqrtf(var + 1e-6f);
  for (int c = 0; c < 128; c++)
    x0[(size_t)i * 128 + c] = (row[c] - mu) * rstd * lng[c] + lnb[c];
}

// ---------------- naive attention coefficients ----------------
__global__ __launch_bounds__(256) void al1_naive(const float* __restrict__ xp,
                                                 const float* __restrict__ a_src,
                                                 const float* __restrict__ a_dst,
                                                 float* __restrict__ als,
                                                 float* __restrict__ ald) {
  int id = blockIdx.x * 256 + threadIdx.x;
  if (id >= NN * 4) return;
  int i = id >> 2, h = id & 3;
  const float* row = xp + (size_t)i * 512 + h * 128;
  float ps = 0.f, pd = 0.f;
  for (int c = 0; c < 128; c++) {
    ps = fmaf(row[c], a_src[h * 128 + c], ps);
    pd = fmaf(row[c], a_dst[h * 128 + c], pd);
  }
  als[id] = ps; ald[id] = pd;
}

__global__ __launch_bounds__(256) void al2_naive(const float* __restrict__ xp,
                                                 const float* __restrict__ a_src,
                                                 const float* __restrict__ a_dst,
                                                 float* __restrict__ als,
                                                 float* __restrict__ ald) {
  int i = blockIdx.x * 256 + threadIdx.x;
  if (i >= NN) return;
  const float* row = xp + (size_t)i * 128;
  float ps = 0.f, pd = 0.f;
  for (int c = 0; c < 128; c++) {
    ps = fmaf(row[c], a_src[c], ps);
    pd = fmaf(row[c], a_dst[c], pd);
  }
  als[i] = ps; ald[i] = pd;
}

// ---------------- naive GAT aggregation conv1 ----------------
__global__ __launch_bounds__(256) void agg1_naive(const float* __restrict__ xp,
                                                  const float* __restrict__ als,
                                                  const float* __restrict__ ald,
                                                  const int* __restrict__ off,
                                                  const int* __restrict__ esrc,
                                                  const float* __restrict__ b1,
                                                  bf16* __restrict__ x1) {
  long gid = (long)blockIdx.x * 256 + threadIdx.x;
  if (gid >= (long)NN * 512) return;
  int i = (int)(gid >> 9), col = (int)(gid & 511), h = col >> 7;
  float adi = ald[i * 4 + h];
  float selfSc = als[i * 4 + h] + adi;
  selfSc = selfSc > 0.f ? selfSc : 0.2f * selfSc;
  int s0 = off[i], s1 = off[i + 1];
  float m = selfSc;
  for (int e = s0; e < s1; e++) {
    int s = esrc[e];
    float sc = als[s * 4 + h] + adi;
    sc = sc > 0.f ? sc : 0.2f * sc;
    m = fmaxf(m, sc);
  }
  float denom = __expf(selfSc - m);
  float acc = __expf(selfSc - m) * xp[(size_t)i * 512 + col];
  for (int e = s0; e < s1; e++) {
    int s = esrc[e];
    float sc = als[s * 4 + h] + adi;
    sc = sc > 0.f ? sc : 0.2f * sc;
    float w = __expf(sc - m);
    denom += w;
    acc = fmaf(w, xp[(size_t)s * 512 + col], acc);
  }
  float v = acc / denom + b1[col];
  v = v > 0.f ? v : (__expf(v) - 1.f);
  x1[gid] = __float2bfloat16(v);
}

// ---------------- naive GAT aggregation conv2 ----------------
__global__ __launch_bounds__(256) void agg2_naive(const float* __restrict__ xp,
                                                  const float* __restrict__ als,
                                                  const float* __restrict__ ald,
                                                  const int* __restrict__ off,
                                                  const int* __restrict__ esrc,
                                                  const float* __restrict__ b2,
                                                  float* __restrict__ x2) {
  long gid = (long)blockIdx.x * 256 + threadIdx.x;
  if (gid >= (long)NN * 128) return;
  int i = (int)(gid >> 7), col = (int)(gid & 127);
  float adi = ald[i];
  float selfSc = als[i] + adi;
  selfSc = selfSc > 0.f ? selfSc : 0.2f * selfSc;
  int s0 = off[i], s1 = off[i + 1];
  float m = selfSc;
  for (int e = s0; e < s1; e++) {
    int s = esrc[e];
    float sc = als[s] + adi;
    sc = sc > 0.f ? sc : 0.2f * sc;
    m = fmaxf(m, sc);
  }
  float denom = __expf(selfSc - m);
  float acc = __expf(selfSc - m) * xp[(size_t)i * 128 + col];
  for (int e = s0; e < s1; e++) {
    int s = esrc[e];
    float sc = als[s] + adi;
    sc = sc > 0.f ? sc : 0.2f * sc;
    float w = __expf(sc - m);
    denom += w;
    acc = fmaf(w, xp[(size_t)s * 128 + col], acc);
  }
  float v = acc / denom + b2[col];
  v = v > 0.f ? v : (__expf(v) - 1.f);
  x2[gid] = v;
}

// ---------------- masked mean pool ----------------
__global__ __launch_bounds__(128) void pool_kernel(const float* __restrict__ x2,
                                                   const int* __restrict__ m_idx,
                                                   float* __restrict__ pooled) {
  int g = blockIdx.x, c = threadIdx.x;
  float acc = 0.f, cnt = 0.f;
  const float* xr = x2 + (size_t)g * 64 * 128;
  const int* mi = m_idx + g * 64;
  for (int n = 0; n < 64; n++) {
    if (mi[n] >= 1) { cnt += 1.f; acc += xr[n * 128 + c]; }
  }
  pooled[(size_t)g * 128 + c] = acc / cnt;
}

// ---------------- final logit: one thread per graph, FP32 OUTPUT ----------------
__global__ __launch_bounds__(256) void head2_naive(const float* __restrict__ h1,
                                                   const float* __restrict__ Wo2,
                                                   const float* __restrict__ bo2,
                                                   float* __restrict__ out) {
  int g = blockIdx.x * 256 + threadIdx.x;
  if (g >= GG) return;
  float p = bo2[0];
  for (int c = 0; c < 128; c++) p = fmaf(h1[(size_t)g * 128 + c], Wo2[c], p);
  out[g] = p;   // fp32: reference output dtype is float32 per harness doc
}

extern "C" void kernel_launch(void* const* d_in, const int* in_sizes, int n_in, void* d_out,
                              int out_size, void* d_ws, size_t ws_size, hipStream_t stream) {
  (void)n_in; (void)out_size; (void)ws_size;
  bool dict_order = (in_sizes[2] == NN);  // m_idx(32768) vs Wt(98304)
  int IM, IE, IF[25];
  if (dict_order) {
    IM = 2; IE = 3;
    const int f[25] = {0, 1, 4, 5, 6, 7, 8, 9, 10, 11, 12, 13, 14, 15, 16, 17, 18,
                       19, 20, 21, 22, 23, 24, 25, 26};
    for (int k = 0; k < 25; k++) IF[k] = f[k];
  } else {
    IM = 25; IE = 26;
    for (int k = 0; k < 25; k++) IF[k] = k;
  }
  const int* m_idx = (const int*)d_in[IM];
  const int* eidx = (const int*)d_in[IE];
  float* out = (float*)d_out;
  const int* e_src = eidx;
  const int* e_dst = eidx + EE;

  char* w = (char*)d_ws;
  float* xp1 = (float*)(w);                          // [NN,512] f32 [0,64) MB
  float* x0 = (float*)(w + ((size_t)64 << 20));      // [NN,128] f32 [64,80) MB
  bf16* x1 = (bf16*)(w + ((size_t)80 << 20));        // [NN,512] bf16 [80,112) MB
  float* xp2 = (float*)(w);                          // [NN,128] f32 [0,16)  (xp1 dead)
  float* x2 = (float*)(w + ((size_t)16 << 20));      // [NN,128] f32 [16,32)
  size_t so = (size_t)112 << 20;
  float* vt = (float*)(w + so); so += 512 * 256 * 4;
  float* start = (float*)(w + so); so += 512 * 128 * 4;
  float* emb2 = (float*)(w + so); so += 51 * 128 * 4 + 256;
  float* als1 = (float*)(w + so); so += NN * 4 * 4;
  float* ald1 = (float*)(w + so); so += NN * 4 * 4;
  float* als2 = (float*)(w + so); so += NN * 4;
  float* ald2 = (float*)(w + so); so += NN * 4;
  float* pooled = (float*)(w + so); so += 512 * 128 * 4;
  float* h1 = (float*)(w + so); so += 512 * 128 * 4;
  int* indeg = (int*)(w + so); so += NN * 4;
  int* csroff = (int*)(w + so); so += (NN + 1) * 4 + 252;
  int* cursor = (int*)(w + so); so += NN * 4;
  int* esrc = (int*)(w + so); so += EE * 4;
  int* bsum = (int*)(w + so); so += 256 * 4;
  int* bpre = (int*)(w + so); so += 256 * 4;
  int* dflag = (int*)(w + so); so += 256;
  float* stage = (float*)(w + ((size_t)117 << 20));

  probe_kernel<<<1, 256, 0, stream>>>(d_in[0], dflag);
  cvt_kernel<<<(O_TOTAL + 255) / 256, 256, 0, stream>>>(
      d_in[IF[0]], d_in[IF[1]], d_in[IF[2]], d_in[IF[3]], d_in[IF[4]], d_in[IF[5]],
      d_in[IF[6]], d_in[IF[7]], d_in[IF[8]], d_in[IF[9]], d_in[IF[10]], d_in[IF[11]],
      d_in[IF[12]], d_in[IF[13]], d_in[IF[14]], d_in[IF[15]], d_in[IF[16]], d_in[IF[17]],
      d_in[IF[18]], d_in[IF[19]], d_in[IF[20]], d_in[IF[21]], d_in[IF[22]], d_in[IF[23]],
      d_in[IF[24]], dflag, stage);

  const float* t = stage + O_T;
  const float* v = stage + O_V;
  const float* Wt = stage + O_WT;       const float* bt = stage + O_BT;
  const float* Wv = stage + O_WV;       const float* bv = stage + O_BV;
  const float* emb = stage + O_EMB;
  const float* Wnode = stage + O_WNODE; const float* bnode = stage + O_BNODE;
  const float* Wstart = stage + O_WSTART; const float* bstart = stage + O_BSTART;
  const float* ln_g = stage + O_LNG;    const float* ln_b = stage + O_LNB;
  const float* W1 = stage + O_W1;
  const float* a_src1 = stage + O_ASRC1; const float* a_dst1 = stage + O_ADST1;
  const float* b1 = stage + O_B1;
  const float* W2 = stage + O_W2;
  const float* a_src2 = stage + O_ASRC2; const float* a_dst2 = stage + O_ADST2;
  const float* b2 = stage + O_B2;
  const float* Wo1 = stage + O_WO1;     const float* bo1 = stage + O_BO1;
  const float* Wo2 = stage + O_WO2;     const float* bo2 = stage + O_BO2;

  hipMemsetAsync(indeg, 0, NN * 4, stream);
  hist_kernel<<<EE / 256, 256, 0, stream>>>(e_dst, indeg);
  scanA_kernel<<<1, 256, 0, stream>>>(indeg, bsum);
  scanB_kernel<<<1, 1, 0, stream>>>(bsum, bpre);
  scanC_kernel<<<1, 256, 0, stream>>>(indeg, bpre, csroff, cursor);
  fill_kernel<<<EE / 256, 256, 0, stream>>>(e_src, e_dst, cursor, esrc);

  ngemm_kernel<float><<<(51 * 128 + 255) / 256, 256, 0, stream>>>(emb, Wnode, bnode, emb2, 51, 128, 128, 128, 0);
  ngemm_kernel<float><<<(512 * 128 + 255) / 256, 256, 0, stream>>>(v, Wv, bv, vt, 512, 128, 768, 256, 0);
  ngemm_kernel<float><<<(512 * 128 + 255) / 256, 256, 0, stream>>>(t, Wt, bt, vt + 128, 512, 128, 768, 256, 0);
  ngemm_kernel<float><<<(512 * 128 + 255) / 256, 256, 0, stream>>>(vt, Wstart, bstart, start, 512, 128, 256, 128, 0);
  ln_naive<<<NN / 256, 256, 0, stream>>>(start, emb2, m_idx, ln_g, ln_b, x0);

  ngemm_kernel<float><<<(int)(((long)NN * 512 + 255) / 256), 256, 0, stream>>>(x0, W1, nullptr, xp1, NN, 512, 128, 512, 0);
  al1_naive<<<NN * 4 / 256, 256, 0, stream>>>(xp1, a_src1, a_dst1, als1, ald1);
  agg1_naive<<<(int)(((long)NN * 512 + 255) / 256), 256, 0, stream>>>(xp1, als1, ald1, csroff, esrc, b1, x1);

  ngemm_kernel<bf16><<<(int)(((long)NN * 128 + 255) / 256), 256, 0, stream>>>(x1, W2, nullptr, xp2, NN, 128, 512, 128, 0);
  al2_naive<<<NN / 256, 256, 0, stream>>>(xp2, a_src2, a_dst2, als2, ald2);
  agg2_naive<<<(int)(((long)NN * 128 + 255) / 256), 256, 0, stream>>>(xp2, als2, ald2, csroff, esrc, b2, x2);

  pool_kernel<<<GG, 128, 0, stream>>>(x2, m_idx, pooled);
  ngemm_kernel<float><<<(512 * 128 + 255) / 256, 256, 0, stream>>>(pooled, Wo1, bo1, h1, 512, 128, 128, 128, 1);
  head2_naive<<<(GG + 255) / 256, 256, 0, stream>>>(h1, Wo2, bo2, out);
}

// Round 8
// 1103.426 us; speedup vs baseline: 2.2478x; 2.2478x over previous
//
#include <hip/hip_runtime.h>
#include <hip/hip_bf16.h>

typedef __hip_bfloat16 bf16;

#define NN 32768   // total nodes
#define EE 262144  // edges
#define GG 512     // graphs

// ---- staged fp32 input offsets (element units) ----
#define O_T      0
#define O_V      393216
#define O_WT     786432
#define O_BT     884736
#define O_WV     884864
#define O_BV     983168
#define O_EMB    983296
#define O_WNODE  989824
#define O_BNODE  1006208
#define O_WSTART 1006336
#define O_BSTART 1039104
#define O_LNG    1039232
#define O_LNB    1039360
#define O_W1     1039488
#define O_ASRC1  1105024
#define O_ADST1  1105536
#define O_B1     1106048
#define O_W2     1106560
#define O_ASRC2  1172096
#define O_ADST2  1172224
#define O_B2     1172352
#define O_WO1    1172480
#define O_BO1    1188864
#define O_WO2    1188992
#define O_BO2    1189120
#define O_TOTAL  1189121

__device__ __forceinline__ float loadf(const float* p) { return *p; }
__device__ __forceinline__ float loadf(const bf16* p) { return __bfloat162float(*p); }

// ---------------- dtype probe ----------------
__global__ __launch_bounds__(256) void probe_kernel(const void* t, int* flag) {
  const unsigned short* u = (const unsigned short*)t;
  int big = 0;
  for (int k = threadIdx.x; k < 1024; k += 256) {
    unsigned e = (u[k] >> 7) & 0xFF;
    if (e >= 141) big = 1;
  }
  __shared__ int sh;
  if (threadIdx.x == 0) sh = 0;
  __syncthreads();
  if (big) atomicOr(&sh, 1);
  __syncthreads();
  if (threadIdx.x == 0) *flag = sh;  // 1 = fp32, 0 = bf16
}

// ---------------- stage all float inputs as fp32 ----------------
__global__ __launch_bounds__(256) void cvt_kernel(
    const void* p0, const void* p1, const void* p2, const void* p3, const void* p4,
    const void* p5, const void* p6, const void* p7, const void* p8, const void* p9,
    const void* p10, const void* p11, const void* p12, const void* p13, const void* p14,
    const void* p15, const void* p16, const void* p17, const void* p18, const void* p19,
    const void* p20, const void* p21, const void* p22, const void* p23, const void* p24,
    const int* flag, float* dst) {
  const void* srcs[25] = {p0, p1, p2, p3, p4, p5, p6, p7, p8, p9, p10, p11, p12,
                          p13, p14, p15, p16, p17, p18, p19, p20, p21, p22, p23, p24};
  const int off[26] = {O_T, O_V, O_WT, O_BT, O_WV, O_BV, O_EMB, O_WNODE, O_BNODE,
                       O_WSTART, O_BSTART, O_LNG, O_LNB, O_W1, O_ASRC1, O_ADST1,
                       O_B1, O_W2, O_ASRC2, O_ADST2, O_B2, O_WO1, O_BO1, O_WO2,
                       O_BO2, O_TOTAL};
  bool f32 = (*flag != 0);
  int i = blockIdx.x * 256 + threadIdx.x;
  if (i >= O_TOTAL) return;
  int tsel = 0;
#pragma unroll
  for (int k = 1; k < 25; k++)
    if (i >= off[k]) tsel = k;
  int j = i - off[tsel];
  const void* s = srcs[tsel];
  dst[i] = f32 ? ((const float*)s)[j] : __bfloat162float(((const bf16*)s)[j]);
}

// ---------------- CSR build ----------------
__global__ __launch_bounds__(256) void hist_kernel(const int* __restrict__ dst,
                                                   int* __restrict__ indeg) {
  int e = blockIdx.x * 256 + threadIdx.x;
  if (e < EE) atomicAdd(&indeg[dst[e]], 1);
}

__global__ __launch_bounds__(256) void scanA_kernel(const int* indeg, int* bsum) {
  int t = threadIdx.x;
  int s = 0;
  for (int j = 0; j < 128; j++) s += indeg[t * 128 + j];
  bsum[t] = s;
}
__global__ void scanB_kernel(const int* bsum, int* bpre) {
  int run = 0;
  for (int k = 0; k < 256; k++) { bpre[k] = run; run += bsum[k]; }
}
__global__ __launch_bounds__(256) void scanC_kernel(const int* indeg, const int* bpre,
                                                    int* off, int* cursor) {
  int t = threadIdx.x;
  int run = bpre[t];
  for (int j = 0; j < 128; j++) {
    int i = t * 128 + j;
    off[i] = run; cursor[i] = run; run += indeg[i];
  }
  if (t == 255) off[NN] = run;
}

__global__ __launch_bounds__(256) void fill_kernel(const int* __restrict__ src,
                                                   const int* __restrict__ dst,
                                                   int* __restrict__ cursor,
                                                   int* __restrict__ esrc) {
  int e = blockIdx.x * 256 + threadIdx.x;
  if (e < EE) {
    int p = atomicAdd(&cursor[dst[e]], 1);
    esrc[p] = src[e];
  }
}

// ---------------- naive GEMM (small problems only) ----------------
template <typename TA>
__global__ __launch_bounds__(256) void ngemm_kernel(const TA* __restrict__ A,
                                                    const float* __restrict__ B,
                                                    const float* __restrict__ bias,
                                                    float* __restrict__ C,
                                                    int M, int N, int K, int ldc, int act) {
  long gid = (long)blockIdx.x * 256 + threadIdx.x;
  if (gid >= (long)M * N) return;
  int m = (int)(gid / N), n = (int)(gid % N);
  float acc = bias ? bias[n] : 0.f;
  for (int k = 0; k < K; k++)
    acc = fmaf(loadf(&A[(size_t)m * K + k]), B[(size_t)k * N + n], acc);
  if (act == 1) acc = acc > 0.f ? acc : 0.01f * acc;
  C[(size_t)m * ldc + n] = acc;
}

// ---------------- tiled LDS GEMM, 64x64 tile, 4x4/thread ----------------
// C[M,N] = A[M,K] @ B[K,N] (+bias) (+leaky 0.01 if act==1), C row stride ldc
// requires M%64==0, N%64==0, K%16==0
template <typename TA>
__global__ __launch_bounds__(256) void gemm_kernel(const TA* __restrict__ A,
                                                   const float* __restrict__ B,
                                                   const float* __restrict__ bias,
                                                   float* __restrict__ C, int M, int N, int K,
                                                   int ldc, int act) {
  __shared__ float As[16][65];
  __shared__ float Bs[16][65];
  int tid = threadIdx.x;
  int brow = blockIdx.y * 64;
  int bcol = blockIdx.x * 64;
  int tr = (tid >> 4) << 2;
  int tc = (tid & 15) << 2;
  float acc[4][4] = {};
  for (int k0 = 0; k0 < K; k0 += 16) {
#pragma unroll
    for (int l = 0; l < 4; l++) {
      int idx = tid + l * 256;
      int r = idx >> 4, kk = idx & 15;
      As[kk][r] = loadf(&A[(size_t)(brow + r) * K + (k0 + kk)]);
    }
#pragma unroll
    for (int l = 0; l < 4; l++) {
      int idx = tid + l * 256;
      int kk = idx >> 6, c = idx & 63;
      Bs[kk][c] = B[(size_t)(k0 + kk) * N + (bcol + c)];
    }
    __syncthreads();
#pragma unroll
    for (int kk = 0; kk < 16; kk++) {
      float a[4], b[4];
#pragma unroll
      for (int i = 0; i < 4; i++) a[i] = As[kk][tr + i];
#pragma unroll
      for (int j = 0; j < 4; j++) b[j] = Bs[kk][tc + j];
#pragma unroll
      for (int i = 0; i < 4; i++)
#pragma unroll
        for (int j = 0; j < 4; j++) acc[i][j] = fmaf(a[i], b[j], acc[i][j]);
    }
    __syncthreads();
  }
#pragma unroll
  for (int i = 0; i < 4; i++) {
#pragma unroll
    for (int j = 0; j < 4; j++) {
      float v = acc[i][j];
      if (bias) v += bias[bcol + tc + j];
      if (act == 1) v = v > 0.f ? v : 0.01f * v;
      C[(size_t)(brow + tr + i) * ldc + (bcol + tc + j)] = v;
    }
  }
}

// ---------------- naive layernorm: one thread per node ----------------
__global__ __launch_bounds__(256) void ln_naive(const float* __restrict__ start,
                                                const float* __restrict__ emb2,
                                                const int* __restrict__ m_idx,
                                                const float* __restrict__ lng,
                                                const float* __restrict__ lnb,
                                                float* __restrict__ x0) {
  int i = blockIdx.x * 256 + threadIdx.x;
  if (i >= NN) return;
  int g = i >> 6, n = i & 63;
  const float* row = (n == 0) ? (start + (size_t)g * 128) : (emb2 + (size_t)m_idx[i] * 128);
  float mu = 0.f;
  for (int c = 0; c < 128; c++) mu += row[c];
  mu *= (1.f / 128.f);
  float var = 0.f;
  for (int c = 0; c < 128; c++) { float d = row[c] - mu; var += d * d; }
  var *= (1.f / 128.f);
  float rstd = rsqrtf(var + 1e-6f);
  for (int c = 0; c < 128; c++)
    x0[(size_t)i * 128 + c] = (row[c] - mu) * rstd * lng[c] + lnb[c];
}

// ---------------- naive attention coefficients ----------------
__global__ __launch_bounds__(256) void al1_naive(const float* __restrict__ xp,
                                                 const float* __restrict__ a_src,
                                                 const float* __restrict__ a_dst,
                                                 float* __restrict__ als,
                                                 float* __restrict__ ald) {
  int id = blockIdx.x * 256 + threadIdx.x;
  if (id >= NN * 4) return;
  int i = id >> 2, h = id & 3;
  const float* row = xp + (size_t)i * 512 + h * 128;
  float ps = 0.f, pd = 0.f;
  for (int c = 0; c < 128; c++) {
    ps = fmaf(row[c], a_src[h * 128 + c], ps);
    pd = fmaf(row[c], a_dst[h * 128 + c], pd);
  }
  als[id] = ps; ald[id] = pd;
}

__global__ __launch_bounds__(256) void al2_naive(const float* __restrict__ xp,
                                                 const float* __restrict__ a_src,
                                                 const float* __restrict__ a_dst,
                                                 float* __restrict__ als,
                                                 float* __restrict__ ald) {
  int i = blockIdx.x * 256 + threadIdx.x;
  if (i >= NN) return;
  const float* row = xp + (size_t)i * 128;
  float ps = 0.f, pd = 0.f;
  for (int c = 0; c < 128; c++) {
    ps = fmaf(row[c], a_src[c], ps);
    pd = fmaf(row[c], a_dst[c], pd);
  }
  als[i] = ps; ald[i] = pd;
}

// ---------------- naive GAT aggregation conv1 ----------------
__global__ __launch_bounds__(256) void agg1_naive(const float* __restrict__ xp,
                                                  const float* __restrict__ als,
                                                  const float* __restrict__ ald,
                                                  const int* __restrict__ off,
                                                  const int* __restrict__ esrc,
                                                  const float* __restrict__ b1,
                                                  bf16* __restrict__ x1) {
  long gid = (long)blockIdx.x * 256 + threadIdx.x;
  if (gid >= (long)NN * 512) return;
  int i = (int)(gid >> 9), col = (int)(gid & 511), h = col >> 7;
  float adi = ald[i * 4 + h];
  float selfSc = als[i * 4 + h] + adi;
  selfSc = selfSc > 0.f ? selfSc : 0.2f * selfSc;
  int s0 = off[i], s1 = off[i + 1];
  float m = selfSc;
  for (int e = s0; e < s1; e++) {
    int s = esrc[e];
    float sc = als[s * 4 + h] + adi;
    sc = sc > 0.f ? sc : 0.2f * sc;
    m = fmaxf(m, sc);
  }
  float denom = __expf(selfSc - m);
  float acc = __expf(selfSc - m) * xp[(size_t)i * 512 + col];
  for (int e = s0; e < s1; e++) {
    int s = esrc[e];
    float sc = als[s * 4 + h] + adi;
    sc = sc > 0.f ? sc : 0.2f * sc;
    float w = __expf(sc - m);
    denom += w;
    acc = fmaf(w, xp[(size_t)s * 512 + col], acc);
  }
  float v = acc / denom + b1[col];
  v = v > 0.f ? v : (__expf(v) - 1.f);
  x1[gid] = __float2bfloat16(v);
}

// ---------------- naive GAT aggregation conv2 ----------------
__global__ __launch_bounds__(256) void agg2_naive(const float* __restrict__ xp,
                                                  const float* __restrict__ als,
                                                  const float* __restrict__ ald,
                                                  const int* __restrict__ off,
                                                  const int* __restrict__ esrc,
                                                  const float* __restrict__ b2,
                                                  float* __restrict__ x2) {
  long gid = (long)blockIdx.x * 256 + threadIdx.x;
  if (gid >= (long)NN * 128) return;
  int i = (int)(gid >> 7), col = (int)(gid & 127);
  float adi = ald[i];
  float selfSc = als[i] + adi;
  selfSc = selfSc > 0.f ? selfSc : 0.2f * selfSc;
  int s0 = off[i], s1 = off[i + 1];
  float m = selfSc;
  for (int e = s0; e < s1; e++) {
    int s = esrc[e];
    float sc = als[s] + adi;
    sc = sc > 0.f ? sc : 0.2f * sc;
    m = fmaxf(m, sc);
  }
  float denom = __expf(selfSc - m);
  float acc = __expf(selfSc - m) * xp[(size_t)i * 128 + col];
  for (int e = s0; e < s1; e++) {
    int s = esrc[e];
    float sc = als[s] + adi;
    sc = sc > 0.f ? sc : 0.2f * sc;
    float w = __expf(sc - m);
    denom += w;
    acc = fmaf(w, xp[(size_t)s * 128 + col], acc);
  }
  float v = acc / denom + b2[col];
  v = v > 0.f ? v : (__expf(v) - 1.f);
  x2[gid] = v;
}

// ---------------- masked mean pool ----------------
__global__ __launch_bounds__(128) void pool_kernel(const float* __restrict__ x2,
                                                   const int* __restrict__ m_idx,
                                                   float* __restrict__ pooled) {
  int g = blockIdx.x, c = threadIdx.x;
  float acc = 0.f, cnt = 0.f;
  const float* xr = x2 + (size_t)g * 64 * 128;
  const int* mi = m_idx + g * 64;
  for (int n = 0; n < 64; n++) {
    if (mi[n] >= 1) { cnt += 1.f; acc += xr[n * 128 + c]; }
  }
  pooled[(size_t)g * 128 + c] = acc / cnt;
}

// ---------------- final logit: one thread per graph, fp32 out ----------------
__global__ __launch_bounds__(256) void head2_naive(const float* __restrict__ h1,
                                                   const float* __restrict__ Wo2,
                                                   const float* __restrict__ bo2,
                                                   float* __restrict__ out) {
  int g = blockIdx.x * 256 + threadIdx.x;
  if (g >= GG) return;
  float p = bo2[0];
  for (int c = 0; c < 128; c++) p = fmaf(h1[(size_t)g * 128 + c], Wo2[c], p);
  out[g] = p;
}

extern "C" void kernel_launch(void* const* d_in, const int* in_sizes, int n_in, void* d_out,
                              int out_size, void* d_ws, size_t ws_size, hipStream_t stream) {
  (void)n_in; (void)out_size; (void)ws_size;
  bool dict_order = (in_sizes[2] == NN);  // m_idx(32768) vs Wt(98304)
  int IM, IE, IF[25];
  if (dict_order) {
    IM = 2; IE = 3;
    const int f[25] = {0, 1, 4, 5, 6, 7, 8, 9, 10, 11, 12, 13, 14, 15, 16, 17, 18,
                       19, 20, 21, 22, 23, 24, 25, 26};
    for (int k = 0; k < 25; k++) IF[k] = f[k];
  } else {
    IM = 25; IE = 26;
    for (int k = 0; k < 25; k++) IF[k] = k;
  }
  const int* m_idx = (const int*)d_in[IM];
  const int* eidx = (const int*)d_in[IE];
  float* out = (float*)d_out;
  const int* e_src = eidx;
  const int* e_dst = eidx + EE;

  char* w = (char*)d_ws;
  float* xp1 = (float*)(w);                          // [NN,512] f32 [0,64) MB
  float* x0 = (float*)(w + ((size_t)64 << 20));      // [NN,128] f32 [64,80) MB
  bf16* x1 = (bf16*)(w + ((size_t)80 << 20));        // [NN,512] bf16 [80,112) MB
  float* xp2 = (float*)(w);                          // [NN,128] f32 [0,16)  (xp1 dead)
  float* x2 = (float*)(w + ((size_t)16 << 20));      // [NN,128] f32 [16,32)
  size_t so = (size_t)112 << 20;
  float* vt = (float*)(w + so); so += 512 * 256 * 4;
  float* start = (float*)(w + so); so += 512 * 128 * 4;
  float* emb2 = (float*)(w + so); so += 51 * 128 * 4 + 256;
  float* als1 = (float*)(w + so); so += NN * 4 * 4;
  float* ald1 = (float*)(w + so); so += NN * 4 * 4;
  float* als2 = (float*)(w + so); so += NN * 4;
  float* ald2 = (float*)(w + so); so += NN * 4;
  float* pooled = (float*)(w + so); so += 512 * 128 * 4;
  float* h1 = (float*)(w + so); so += 512 * 128 * 4;
  int* indeg = (int*)(w + so); so += NN * 4;
  int* csroff = (int*)(w + so); so += (NN + 1) * 4 + 252;
  int* cursor = (int*)(w + so); so += NN * 4;
  int* esrc = (int*)(w + so); so += EE * 4;
  int* bsum = (int*)(w + so); so += 256 * 4;
  int* bpre = (int*)(w + so); so += 256 * 4;
  int* dflag = (int*)(w + so); so += 256;
  float* stage = (float*)(w + ((size_t)117 << 20));

  probe_kernel<<<1, 256, 0, stream>>>(d_in[0], dflag);
  cvt_kernel<<<(O_TOTAL + 255) / 256, 256, 0, stream>>>(
      d_in[IF[0]], d_in[IF[1]], d_in[IF[2]], d_in[IF[3]], d_in[IF[4]], d_in[IF[5]],
      d_in[IF[6]], d_in[IF[7]], d_in[IF[8]], d_in[IF[9]], d_in[IF[10]], d_in[IF[11]],
      d_in[IF[12]], d_in[IF[13]], d_in[IF[14]], d_in[IF[15]], d_in[IF[16]], d_in[IF[17]],
      d_in[IF[18]], d_in[IF[19]], d_in[IF[20]], d_in[IF[21]], d_in[IF[22]], d_in[IF[23]],
      d_in[IF[24]], dflag, stage);

  const float* t = stage + O_T;
  const float* v = stage + O_V;
  const float* Wt = stage + O_WT;       const float* bt = stage + O_BT;
  const float* Wv = stage + O_WV;       const float* bv = stage + O_BV;
  const float* emb = stage + O_EMB;
  const float* Wnode = stage + O_WNODE; const float* bnode = stage + O_BNODE;
  const float* Wstart = stage + O_WSTART; const float* bstart = stage + O_BSTART;
  const float* ln_g = stage + O_LNG;    const float* ln_b = stage + O_LNB;
  const float* W1 = stage + O_W1;
  const float* a_src1 = stage + O_ASRC1; const float* a_dst1 = stage + O_ADST1;
  const float* b1 = stage + O_B1;
  const float* W2 = stage + O_W2;
  const float* a_src2 = stage + O_ASRC2; const float* a_dst2 = stage + O_ADST2;
  const float* b2 = stage + O_B2;
  const float* Wo1 = stage + O_WO1;     const float* bo1 = stage + O_BO1;
  const float* Wo2 = stage + O_WO2;     const float* bo2 = stage + O_BO2;

  hipMemsetAsync(indeg, 0, NN * 4, stream);
  hist_kernel<<<EE / 256, 256, 0, stream>>>(e_dst, indeg);
  scanA_kernel<<<1, 256, 0, stream>>>(indeg, bsum);
  scanB_kernel<<<1, 1, 0, stream>>>(bsum, bpre);
  scanC_kernel<<<1, 256, 0, stream>>>(indeg, bpre, csroff, cursor);
  fill_kernel<<<EE / 256, 256, 0, stream>>>(e_src, e_dst, cursor, esrc);

  // small: naive (M=51 not tile-divisible)
  ngemm_kernel<float><<<(51 * 128 + 255) / 256, 256, 0, stream>>>(emb, Wnode, bnode, emb2, 51, 128, 128, 128, 0);
  // medium/large: tiled LDS GEMM
  gemm_kernel<float><<<dim3(2, 8), 256, 0, stream>>>(v, Wv, bv, vt, 512, 128, 768, 256, 0);
  gemm_kernel<float><<<dim3(2, 8), 256, 0, stream>>>(t, Wt, bt, vt + 128, 512, 128, 768, 256, 0);
  gemm_kernel<float><<<dim3(2, 8), 256, 0, stream>>>(vt, Wstart, bstart, start, 512, 128, 256, 128, 0);
  ln_naive<<<NN / 256, 256, 0, stream>>>(start, emb2, m_idx, ln_g, ln_b, x0);

  gemm_kernel<float><<<dim3(8, NN / 64), 256, 0, stream>>>(x0, W1, nullptr, xp1, NN, 512, 128, 512, 0);
  al1_naive<<<NN * 4 / 256, 256, 0, stream>>>(xp1, a_src1, a_dst1, als1, ald1);
  agg1_naive<<<(int)(((long)NN * 512 + 255) / 256), 256, 0, stream>>>(xp1, als1, ald1, csroff, esrc, b1, x1);

  gemm_kernel<bf16><<<dim3(2, NN / 64), 256, 0, stream>>>(x1, W2, nullptr, xp2, NN, 128, 512, 128, 0);
  al2_naive<<<NN / 256, 256, 0, stream>>>(xp2, a_src2, a_dst2, als2, ald2);
  agg2_naive<<<(int)(((long)NN * 128 + 255) / 256), 256, 0, stream>>>(xp2, als2, ald2, csroff, esrc, b2, x2);

  pool_kernel<<<GG, 128, 0, stream>>>(x2, m_idx, pooled);
  gemm_kernel<float><<<dim3(2, 8), 256, 0, stream>>>(pooled, Wo1, bo1, h1, 512, 128, 128, 128, 1);
  head2_naive<<<(GG + 255) / 256, 256, 0, stream>>>(h1, Wo2, bo2, out);
}

// Round 9
// 871.697 us; speedup vs baseline: 2.8453x; 1.2658x over previous
//
#include <hip/hip_runtime.h>
#include <hip/hip_bf16.h>

typedef __hip_bfloat16 bf16;

#define NN 32768   // total nodes
#define EE 262144  // edges
#define GG 512     // graphs

// ---- staged fp32 input offsets (element units) ----
#define O_T      0
#define O_V      393216
#define O_WT     786432
#define O_BT     884736
#define O_WV     884864
#define O_BV     983168
#define O_EMB    983296
#define O_WNODE  989824
#define O_BNODE  1006208
#define O_WSTART 1006336
#define O_BSTART 1039104
#define O_LNG    1039232
#define O_LNB    1039360
#define O_W1     1039488
#define O_ASRC1  1105024
#define O_ADST1  1105536
#define O_B1     1106048
#define O_W2     1106560
#define O_ASRC2  1172096
#define O_ADST2  1172224
#define O_B2     1172352
#define O_WO1    1172480
#define O_BO1    1188864
#define O_WO2    1188992
#define O_BO2    1189120
#define O_TOTAL  1189121

__device__ __forceinline__ float loadf(const float* p) { return *p; }
__device__ __forceinline__ float loadf(const bf16* p) { return __bfloat162float(*p); }
__device__ __forceinline__ void storef(float* p, float v) { *p = v; }
__device__ __forceinline__ void storef(bf16* p, float v) { *p = __float2bfloat16(v); }

__device__ __forceinline__ float2 unpk(unsigned u) {
  float2 r;
  r.x = __uint_as_float(u << 16);
  r.y = __uint_as_float(u & 0xffff0000u);
  return r;
}
__device__ __forceinline__ unsigned pk(float x, float y) {
  union { bf16 h[2]; unsigned u; } p;
  p.h[0] = __float2bfloat16(x);
  p.h[1] = __float2bfloat16(y);
  return p.u;
}

// ---------------- dtype probe ----------------
__global__ __launch_bounds__(256) void probe_kernel(const void* t, int* flag) {
  const unsigned short* u = (const unsigned short*)t;
  int big = 0;
  for (int k = threadIdx.x; k < 1024; k += 256) {
    unsigned e = (u[k] >> 7) & 0xFF;
    if (e >= 141) big = 1;
  }
  __shared__ int sh;
  if (threadIdx.x == 0) sh = 0;
  __syncthreads();
  if (big) atomicOr(&sh, 1);
  __syncthreads();
  if (threadIdx.x == 0) *flag = sh;  // 1 = fp32, 0 = bf16
}

// ---------------- stage all float inputs as fp32 ----------------
__global__ __launch_bounds__(256) void cvt_kernel(
    const void* p0, const void* p1, const void* p2, const void* p3, const void* p4,
    const void* p5, const void* p6, const void* p7, const void* p8, const void* p9,
    const void* p10, const void* p11, const void* p12, const void* p13, const void* p14,
    const void* p15, const void* p16, const void* p17, const void* p18, const void* p19,
    const void* p20, const void* p21, const void* p22, const void* p23, const void* p24,
    const int* flag, float* dst) {
  const void* srcs[25] = {p0, p1, p2, p3, p4, p5, p6, p7, p8, p9, p10, p11, p12,
                          p13, p14, p15, p16, p17, p18, p19, p20, p21, p22, p23, p24};
  const int off[26] = {O_T, O_V, O_WT, O_BT, O_WV, O_BV, O_EMB, O_WNODE, O_BNODE,
                       O_WSTART, O_BSTART, O_LNG, O_LNB, O_W1, O_ASRC1, O_ADST1,
                       O_B1, O_W2, O_ASRC2, O_ADST2, O_B2, O_WO1, O_BO1, O_WO2,
                       O_BO2, O_TOTAL};
  bool f32 = (*flag != 0);
  int i = blockIdx.x * 256 + threadIdx.x;
  if (i >= O_TOTAL) return;
  int tsel = 0;
#pragma unroll
  for (int k = 1; k < 25; k++)
    if (i >= off[k]) tsel = k;
  int j = i - off[tsel];
  const void* s = srcs[tsel];
  dst[i] = f32 ? ((const float*)s)[j] : __bfloat162float(((const bf16*)s)[j]);
}

// ---------------- CSR build ----------------
__global__ __launch_bounds__(256) void hist_kernel(const int* __restrict__ dst,
                                                   int* __restrict__ indeg) {
  int e = blockIdx.x * 256 + threadIdx.x;
  if (e < EE) atomicAdd(&indeg[dst[e]], 1);
}

__global__ __launch_bounds__(256) void scanA_kernel(const int* indeg, int* bsum) {
  int t = threadIdx.x;
  int s = 0;
  for (int j = 0; j < 128; j++) s += indeg[t * 128 + j];
  bsum[t] = s;
}
__global__ void scanB_kernel(const int* bsum, int* bpre) {
  int run = 0;
  for (int k = 0; k < 256; k++) { bpre[k] = run; run += bsum[k]; }
}
__global__ __launch_bounds__(256) void scanC_kernel(const int* indeg, const int* bpre,
                                                    int* off, int* cursor) {
  int t = threadIdx.x;
  int run = bpre[t];
  for (int j = 0; j < 128; j++) {
    int i = t * 128 + j;
    off[i] = run; cursor[i] = run; run += indeg[i];
  }
  if (t == 255) off[NN] = run;
}

__global__ __launch_bounds__(256) void fill_kernel(const int* __restrict__ src,
                                                   const int* __restrict__ dst,
                                                   int* __restrict__ cursor,
                                                   int* __restrict__ esrc) {
  int e = blockIdx.x * 256 + threadIdx.x;
  if (e < EE) {
    int p = atomicAdd(&cursor[dst[e]], 1);
    esrc[p] = src[e];
  }
}

// ---------------- naive GEMM (small problems only) ----------------
template <typename TA>
__global__ __launch_bounds__(256) void ngemm_kernel(const TA* __restrict__ A,
                                                    const float* __restrict__ B,
                                                    const float* __restrict__ bias,
                                                    float* __restrict__ C,
                                                    int M, int N, int K, int ldc, int act) {
  long gid = (long)blockIdx.x * 256 + threadIdx.x;
  if (gid >= (long)M * N) return;
  int m = (int)(gid / N), n = (int)(gid % N);
  float acc = bias ? bias[n] : 0.f;
  for (int k = 0; k < K; k++)
    acc = fmaf(loadf(&A[(size_t)m * K + k]), B[(size_t)k * N + n], acc);
  if (act == 1) acc = acc > 0.f ? acc : 0.01f * acc;
  C[(size_t)m * ldc + n] = acc;
}

// ---------------- tiled LDS GEMM, 64x64 tile, 4x4/thread ----------------
template <typename TA, typename TC>
__global__ __launch_bounds__(256) void gemm_kernel(const TA* __restrict__ A,
                                                   const float* __restrict__ B,
                                                   const float* __restrict__ bias,
                                                   TC* __restrict__ C, int M, int N, int K,
                                                   int ldc, int act) {
  __shared__ float As[16][65];
  __shared__ float Bs[16][65];
  int tid = threadIdx.x;
  int brow = blockIdx.y * 64;
  int bcol = blockIdx.x * 64;
  int tr = (tid >> 4) << 2;
  int tc = (tid & 15) << 2;
  float acc[4][4] = {};
  for (int k0 = 0; k0 < K; k0 += 16) {
#pragma unroll
    for (int l = 0; l < 4; l++) {
      int idx = tid + l * 256;
      int r = idx >> 4, kk = idx & 15;
      As[kk][r] = loadf(&A[(size_t)(brow + r) * K + (k0 + kk)]);
    }
#pragma unroll
    for (int l = 0; l < 4; l++) {
      int idx = tid + l * 256;
      int kk = idx >> 6, c = idx & 63;
      Bs[kk][c] = B[(size_t)(k0 + kk) * N + (bcol + c)];
    }
    __syncthreads();
#pragma unroll
    for (int kk = 0; kk < 16; kk++) {
      float a[4], b[4];
#pragma unroll
      for (int i = 0; i < 4; i++) a[i] = As[kk][tr + i];
#pragma unroll
      for (int j = 0; j < 4; j++) b[j] = Bs[kk][tc + j];
#pragma unroll
      for (int i = 0; i < 4; i++)
#pragma unroll
        for (int j = 0; j < 4; j++) acc[i][j] = fmaf(a[i], b[j], acc[i][j]);
    }
    __syncthreads();
  }
#pragma unroll
  for (int i = 0; i < 4; i++) {
#pragma unroll
    for (int j = 0; j < 4; j++) {
      float v = acc[i][j];
      if (bias) v += bias[bcol + tc + j];
      if (act == 1) v = v > 0.f ? v : 0.01f * v;
      storef(&C[(size_t)(brow + tr + i) * ldc + (bcol + tc + j)], v);
    }
  }
}

// ---------------- naive layernorm ----------------
__global__ __launch_bounds__(256) void ln_naive(const float* __restrict__ start,
                                                const float* __restrict__ emb2,
                                                const int* __restrict__ m_idx,
                                                const float* __restrict__ lng,
                                                const float* __restrict__ lnb,
                                                float* __restrict__ x0) {
  int i = blockIdx.x * 256 + threadIdx.x;
  if (i >= NN) return;
  int g = i >> 6, n = i & 63;
  const float* row = (n == 0) ? (start + (size_t)g * 128) : (emb2 + (size_t)m_idx[i] * 128);
  float mu = 0.f;
  for (int c = 0; c < 128; c++) mu += row[c];
  mu *= (1.f / 128.f);
  float var = 0.f;
  for (int c = 0; c < 128; c++) { float d = row[c] - mu; var += d * d; }
  var *= (1.f / 128.f);
  float rstd = rsqrtf(var + 1e-6f);
  for (int c = 0; c < 128; c++)
    x0[(size_t)i * 128 + c] = (row[c] - mu) * rstd * lng[c] + lnb[c];
}

// ---------------- attention coefficients (xp bf16) ----------------
__global__ __launch_bounds__(256) void al1_naive(const bf16* __restrict__ xp,
                                                 const float* __restrict__ a_src,
                                                 const float* __restrict__ a_dst,
                                                 float* __restrict__ als,
                                                 float* __restrict__ ald) {
  int id = blockIdx.x * 256 + threadIdx.x;
  if (id >= NN * 4) return;
  int i = id >> 2, h = id & 3;
  const bf16* row = xp + (size_t)i * 512 + h * 128;
  float ps = 0.f, pd = 0.f;
  for (int c = 0; c < 128; c++) {
    float x = loadf(&row[c]);
    ps = fmaf(x, a_src[h * 128 + c], ps);
    pd = fmaf(x, a_dst[h * 128 + c], pd);
  }
  als[id] = ps; ald[id] = pd;
}

__global__ __launch_bounds__(256) void al2_naive(const bf16* __restrict__ xp,
                                                 const float* __restrict__ a_src,
                                                 const float* __restrict__ a_dst,
                                                 float* __restrict__ als,
                                                 float* __restrict__ ald) {
  int i = blockIdx.x * 256 + threadIdx.x;
  if (i >= NN) return;
  const bf16* row = xp + (size_t)i * 128;
  float ps = 0.f, pd = 0.f;
  for (int c = 0; c < 128; c++) {
    float x = loadf(&row[c]);
    ps = fmaf(x, a_src[c], ps);
    pd = fmaf(x, a_dst[c], pd);
  }
  als[i] = ps; ald[i] = pd;
}

// ---------------- softmax weights, conv1: thread per (node,head) ----------------
// stores unnormalized w per CSR slot + self weight + 1/denom
__global__ __launch_bounds__(256) void alpha1_kernel(const float* __restrict__ als,
                                                     const float* __restrict__ ald,
                                                     const int* __restrict__ off,
                                                     const int* __restrict__ esrc,
                                                     float* __restrict__ aw,
                                                     float* __restrict__ selfw,
                                                     float* __restrict__ inv) {
  int id = blockIdx.x * 256 + threadIdx.x;
  if (id >= NN * 4) return;
  int i = id >> 2, h = id & 3;
  float adi = ald[id];
  float selfSc = als[id] + adi;
  selfSc = selfSc > 0.f ? selfSc : 0.2f * selfSc;
  int s0 = off[i], s1 = off[i + 1];
  float m = selfSc;
  for (int e = s0; e < s1; e++) {
    float sc = als[esrc[e] * 4 + h] + adi;
    sc = sc > 0.f ? sc : 0.2f * sc;
    m = fmaxf(m, sc);
  }
  float sw = __expf(selfSc - m);
  float denom = sw;
  for (int e = s0; e < s1; e++) {
    float sc = als[esrc[e] * 4 + h] + adi;
    sc = sc > 0.f ? sc : 0.2f * sc;
    float w = __expf(sc - m);
    aw[e * 4 + h] = w;
    denom += w;
  }
  selfw[id] = sw;
  inv[id] = 1.f / denom;
}

__global__ __launch_bounds__(256) void alpha2_kernel(const float* __restrict__ als,
                                                     const float* __restrict__ ald,
                                                     const int* __restrict__ off,
                                                     const int* __restrict__ esrc,
                                                     float* __restrict__ aw,
                                                     float* __restrict__ selfw,
                                                     float* __restrict__ inv) {
  int i = blockIdx.x * 256 + threadIdx.x;
  if (i >= NN) return;
  float adi = ald[i];
  float selfSc = als[i] + adi;
  selfSc = selfSc > 0.f ? selfSc : 0.2f * selfSc;
  int s0 = off[i], s1 = off[i + 1];
  float m = selfSc;
  for (int e = s0; e < s1; e++) {
    float sc = als[esrc[e]] + adi;
    sc = sc > 0.f ? sc : 0.2f * sc;
    m = fmaxf(m, sc);
  }
  float sw = __expf(selfSc - m);
  float denom = sw;
  for (int e = s0; e < s1; e++) {
    float sc = als[esrc[e]] + adi;
    sc = sc > 0.f ? sc : 0.2f * sc;
    float w = __expf(sc - m);
    aw[e] = w;
    denom += w;
  }
  selfw[i] = sw;
  inv[i] = 1.f / denom;
}

// ---------------- weighted gather, conv1: thread per (node, col-pair) ----------------
// xp bf16-packed; h uniform per wave (c2 block of 64)
__global__ __launch_bounds__(256) void agg1w_kernel(const unsigned* __restrict__ xp,
                                                    const float* __restrict__ aw,
                                                    const float* __restrict__ selfw,
                                                    const float* __restrict__ inv,
                                                    const int* __restrict__ off,
                                                    const int* __restrict__ esrc,
                                                    const float* __restrict__ b1,
                                                    unsigned* __restrict__ x1) {
  long gid = (long)blockIdx.x * 256 + threadIdx.x;
  if (gid >= (long)NN * 256) return;
  int i = (int)(gid >> 8), c2 = (int)(gid & 255), h = c2 >> 6;
  float sw = selfw[i * 4 + h];
  float iv = inv[i * 4 + h];
  float2 xv = unpk(xp[(size_t)i * 256 + c2]);
  float2 acc = make_float2(sw * xv.x, sw * xv.y);
  int s0 = off[i], s1 = off[i + 1];
  for (int e = s0; e < s1; e++) {
    int s = esrc[e];
    float w = aw[e * 4 + h];
    float2 m = unpk(xp[(size_t)s * 256 + c2]);
    acc.x = fmaf(w, m.x, acc.x);
    acc.y = fmaf(w, m.y, acc.y);
  }
  float2 bb = ((const float2*)b1)[c2];
  float vx = acc.x * iv + bb.x;
  float vy = acc.y * iv + bb.y;
  vx = vx > 0.f ? vx : (__expf(vx) - 1.f);
  vy = vy > 0.f ? vy : (__expf(vy) - 1.f);
  x1[gid] = pk(vx, vy);
}

// ---------------- weighted gather, conv2: thread per (node, col-pair) ----------------
__global__ __launch_bounds__(256) void agg2w_kernel(const unsigned* __restrict__ xp,
                                                    const float* __restrict__ aw,
                                                    const float* __restrict__ selfw,
                                                    const float* __restrict__ inv,
                                                    const int* __restrict__ off,
                                                    const int* __restrict__ esrc,
                                                    const float* __restrict__ b2,
                                                    float2* __restrict__ x2) {
  long gid = (long)blockIdx.x * 256 + threadIdx.x;
  if (gid >= (long)NN * 64) return;
  int i = (int)(gid >> 6), c2 = (int)(gid & 63);
  float sw = selfw[i];
  float iv = inv[i];
  float2 xv = unpk(xp[(size_t)i * 64 + c2]);
  float2 acc = make_float2(sw * xv.x, sw * xv.y);
  int s0 = off[i], s1 = off[i + 1];
  for (int e = s0; e < s1; e++) {
    int s = esrc[e];
    float w = aw[e];
    float2 m = unpk(xp[(size_t)s * 64 + c2]);
    acc.x = fmaf(w, m.x, acc.x);
    acc.y = fmaf(w, m.y, acc.y);
  }
  float2 bb = ((const float2*)b2)[c2];
  float vx = acc.x * iv + bb.x;
  float vy = acc.y * iv + bb.y;
  vx = vx > 0.f ? vx : (__expf(vx) - 1.f);
  vy = vy > 0.f ? vy : (__expf(vy) - 1.f);
  x2[gid] = make_float2(vx, vy);
}

// ---------------- masked mean pool ----------------
__global__ __launch_bounds__(128) void pool_kernel(const float* __restrict__ x2,
                                                   const int* __restrict__ m_idx,
                                                   float* __restrict__ pooled) {
  int g = blockIdx.x, c = threadIdx.x;
  float acc = 0.f, cnt = 0.f;
  const float* xr = x2 + (size_t)g * 64 * 128;
  const int* mi = m_idx + g * 64;
  for (int n = 0; n < 64; n++) {
    if (mi[n] >= 1) { cnt += 1.f; acc += xr[n * 128 + c]; }
  }
  pooled[(size_t)g * 128 + c] = acc / cnt;
}

// ---------------- final logit ----------------
__global__ __launch_bounds__(256) void head2_naive(const float* __restrict__ h1,
                                                   const float* __restrict__ Wo2,
                                                   const float* __restrict__ bo2,
                                                   float* __restrict__ out) {
  int g = blockIdx.x * 256 + threadIdx.x;
  if (g >= GG) return;
  float p = bo2[0];
  for (int c = 0; c < 128; c++) p = fmaf(h1[(size_t)g * 128 + c], Wo2[c], p);
  out[g] = p;
}

extern "C" void kernel_launch(void* const* d_in, const int* in_sizes, int n_in, void* d_out,
                              int out_size, void* d_ws, size_t ws_size, hipStream_t stream) {
  (void)n_in; (void)out_size; (void)ws_size;
  bool dict_order = (in_sizes[2] == NN);
  int IM, IE, IF[25];
  if (dict_order) {
    IM = 2; IE = 3;
    const int f[25] = {0, 1, 4, 5, 6, 7, 8, 9, 10, 11, 12, 13, 14, 15, 16, 17, 18,
                       19, 20, 21, 22, 23, 24, 25, 26};
    for (int k = 0; k < 25; k++) IF[k] = f[k];
  } else {
    IM = 25; IE = 26;
    for (int k = 0; k < 25; k++) IF[k] = k;
  }
  const int* m_idx = (const int*)d_in[IM];
  const int* eidx = (const int*)d_in[IE];
  float* out = (float*)d_out;
  const int* e_src = eidx;
  const int* e_dst = eidx + EE;

  // workspace layout (peak ~101 MB)
  char* w = (char*)d_ws;
  bf16* xp1b = (bf16*)(w);                           // [NN,512] bf16 [0,32) MB
  float* x0 = (float*)(w + ((size_t)32 << 20));      // [NN,128] f32 [32,48) MB
  bf16* x1 = (bf16*)(w + ((size_t)48 << 20));        // [NN,512] bf16 [48,80) MB
  bf16* xp2b = (bf16*)(w);                           // [NN,128] bf16 [0,8)  (xp1b dead)
  float* x2 = (float*)(w + ((size_t)8 << 20));       // [NN,128] f32 [8,24)
  size_t so = (size_t)80 << 20;                      // smalls [80,~95) MB
  float* vt = (float*)(w + so); so += 512 * 256 * 4;
  float* start = (float*)(w + so); so += 512 * 128 * 4;
  float* emb2 = (float*)(w + so); so += 51 * 128 * 4 + 256;
  float* als1 = (float*)(w + so); so += NN * 4 * 4;
  float* ald1 = (float*)(w + so); so += NN * 4 * 4;
  float* als2 = (float*)(w + so); so += NN * 4;
  float* ald2 = (float*)(w + so); so += NN * 4;
  float* aw1 = (float*)(w + so); so += EE * 4 * 4;   // 4 MB
  float* selfw1 = (float*)(w + so); so += NN * 4 * 4;
  float* inv1 = (float*)(w + so); so += NN * 4 * 4;
  float* aw2 = (float*)(w + so); so += EE * 4;       // 1 MB
  float* selfw2 = (float*)(w + so); so += NN * 4;
  float* inv2 = (float*)(w + so); so += NN * 4;
  float* pooled = (float*)(w + so); so += 512 * 128 * 4;
  float* h1 = (float*)(w + so); so += 512 * 128 * 4;
  int* indeg = (int*)(w + so); so += NN * 4;
  int* csroff = (int*)(w + so); so += (NN + 1) * 4 + 252;
  int* cursor = (int*)(w + so); so += NN * 4;
  int* esrc = (int*)(w + so); so += EE * 4;
  int* bsum = (int*)(w + so); so += 256 * 4;
  int* bpre = (int*)(w + so); so += 256 * 4;
  int* dflag = (int*)(w + so); so += 256;
  float* stage = (float*)(w + ((size_t)96 << 20));   // [96,~100.6) MB

  probe_kernel<<<1, 256, 0, stream>>>(d_in[0], dflag);
  cvt_kernel<<<(O_TOTAL + 255) / 256, 256, 0, stream>>>(
      d_in[IF[0]], d_in[IF[1]], d_in[IF[2]], d_in[IF[3]], d_in[IF[4]], d_in[IF[5]],
      d_in[IF[6]], d_in[IF[7]], d_in[IF[8]], d_in[IF[9]], d_in[IF[10]], d_in[IF[11]],
      d_in[IF[12]], d_in[IF[13]], d_in[IF[14]], d_in[IF[15]], d_in[IF[16]], d_in[IF[17]],
      d_in[IF[18]], d_in[IF[19]], d_in[IF[20]], d_in[IF[21]], d_in[IF[22]], d_in[IF[23]],
      d_in[IF[24]], dflag, stage);

  const float* t = stage + O_T;
  const float* v = stage + O_V;
  const float* Wt = stage + O_WT;       const float* bt = stage + O_BT;
  const float* Wv = stage + O_WV;       const float* bv = stage + O_BV;
  const float* emb = stage + O_EMB;
  const float* Wnode = stage + O_WNODE; const float* bnode = stage + O_BNODE;
  const float* Wstart = stage + O_WSTART; const float* bstart = stage + O_BSTART;
  const float* ln_g = stage + O_LNG;    const float* ln_b = stage + O_LNB;
  const float* W1 = stage + O_W1;
  const float* a_src1 = stage + O_ASRC1; const float* a_dst1 = stage + O_ADST1;
  const float* b1 = stage + O_B1;
  const float* W2 = stage + O_W2;
  const float* a_src2 = stage + O_ASRC2; const float* a_dst2 = stage + O_ADST2;
  const float* b2 = stage + O_B2;
  const float* Wo1 = stage + O_WO1;     const float* bo1 = stage + O_BO1;
  const float* Wo2 = stage + O_WO2;     const float* bo2 = stage + O_BO2;

  hipMemsetAsync(indeg, 0, NN * 4, stream);
  hist_kernel<<<EE / 256, 256, 0, stream>>>(e_dst, indeg);
  scanA_kernel<<<1, 256, 0, stream>>>(indeg, bsum);
  scanB_kernel<<<1, 1, 0, stream>>>(bsum, bpre);
  scanC_kernel<<<1, 256, 0, stream>>>(indeg, bpre, csroff, cursor);
  fill_kernel<<<EE / 256, 256, 0, stream>>>(e_src, e_dst, cursor, esrc);

  ngemm_kernel<float><<<(51 * 128 + 255) / 256, 256, 0, stream>>>(emb, Wnode, bnode, emb2, 51, 128, 128, 128, 0);
  gemm_kernel<float, float><<<dim3(2, 8), 256, 0, stream>>>(v, Wv, bv, vt, 512, 128, 768, 256, 0);
  gemm_kernel<float, float><<<dim3(2, 8), 256, 0, stream>>>(t, Wt, bt, vt + 128, 512, 128, 768, 256, 0);
  gemm_kernel<float, float><<<dim3(2, 8), 256, 0, stream>>>(vt, Wstart, bstart, start, 512, 128, 256, 128, 0);
  ln_naive<<<NN / 256, 256, 0, stream>>>(start, emb2, m_idx, ln_g, ln_b, x0);

  // conv1: GEMM -> bf16 xp1
  gemm_kernel<float, bf16><<<dim3(8, NN / 64), 256, 0, stream>>>(x0, W1, nullptr, xp1b, NN, 512, 128, 512, 0);
  al1_naive<<<NN * 4 / 256, 256, 0, stream>>>(xp1b, a_src1, a_dst1, als1, ald1);
  alpha1_kernel<<<NN * 4 / 256, 256, 0, stream>>>(als1, ald1, csroff, esrc, aw1, selfw1, inv1);
  agg1w_kernel<<<(int)(((long)NN * 256 + 255) / 256), 256, 0, stream>>>(
      (const unsigned*)xp1b, aw1, selfw1, inv1, csroff, esrc, b1, (unsigned*)x1);

  // conv2: GEMM -> bf16 xp2
  gemm_kernel<bf16, bf16><<<dim3(2, NN / 64), 256, 0, stream>>>(x1, W2, nullptr, xp2b, NN, 128, 512, 128, 0);
  al2_naive<<<NN / 256, 256, 0, stream>>>(xp2b, a_src2, a_dst2, als2, ald2);
  alpha2_kernel<<<NN / 256, 256, 0, stream>>>(als2, ald2, csroff, esrc, aw2, selfw2, inv2);
  agg2w_kernel<<<(int)(((long)NN * 64 + 255) / 256), 256, 0, stream>>>(
      (const unsigned*)xp2b, aw2, selfw2, inv2, csroff, esrc, b2, (float2*)x2);

  pool_kernel<<<GG, 128, 0, stream>>>(x2, m_idx, pooled);
  gemm_kernel<float, float><<<dim3(2, 8), 256, 0, stream>>>(pooled, Wo1, bo1, h1, 512, 128, 128, 128, 1);
  head2_naive<<<(GG + 255) / 256, 256, 0, stream>>>(h1, Wo2, bo2, out);
}

// Round 10
// 792.640 us; speedup vs baseline: 3.1291x; 1.0997x over previous
//
#include <hip/hip_runtime.h>
#include <hip/hip_bf16.h>

typedef __hip_bfloat16 bf16;

#define NN 32768   // total nodes
#define EE 262144  // edges
#define GG 512     // graphs

// ---- staged fp32 input offsets (element units) ----
#define O_T      0
#define O_V      393216
#define O_WT     786432
#define O_BT     884736
#define O_WV     884864
#define O_BV     983168
#define O_EMB    983296
#define O_WNODE  989824
#define O_BNODE  1006208
#define O_WSTART 1006336
#define O_BSTART 1039104
#define O_LNG    1039232
#define O_LNB    1039360
#define O_W1     1039488
#define O_ASRC1  1105024
#define O_ADST1  1105536
#define O_B1     1106048
#define O_W2     1106560
#define O_ASRC2  1172096
#define O_ADST2  1172224
#define O_B2     1172352
#define O_WO1    1172480
#define O_BO1    1188864
#define O_WO2    1188992
#define O_BO2    1189120
#define O_TOTAL  1189121

__device__ __forceinline__ float loadf(const float* p) { return *p; }
__device__ __forceinline__ float loadf(const bf16* p) { return __bfloat162float(*p); }
__device__ __forceinline__ void storef(float* p, float v) { *p = v; }
__device__ __forceinline__ void storef(bf16* p, float v) { *p = __float2bfloat16(v); }

__device__ __forceinline__ float2 unpk(unsigned u) {
  float2 r;
  r.x = __uint_as_float(u << 16);
  r.y = __uint_as_float(u & 0xffff0000u);
  return r;
}
__device__ __forceinline__ unsigned pk(float x, float y) {
  union { bf16 h[2]; unsigned u; } p;
  p.h[0] = __float2bfloat16(x);
  p.h[1] = __float2bfloat16(y);
  return p.u;
}

__device__ __forceinline__ float wred_sum(float v) {
#pragma unroll
  for (int o = 32; o; o >>= 1) v += __shfl_xor(v, o, 64);
  return v;
}

// ---------------- dtype probe ----------------
__global__ __launch_bounds__(256) void probe_kernel(const void* t, int* flag) {
  const unsigned short* u = (const unsigned short*)t;
  int big = 0;
  for (int k = threadIdx.x; k < 1024; k += 256) {
    unsigned e = (u[k] >> 7) & 0xFF;
    if (e >= 141) big = 1;
  }
  __shared__ int sh;
  if (threadIdx.x == 0) sh = 0;
  __syncthreads();
  if (big) atomicOr(&sh, 1);
  __syncthreads();
  if (threadIdx.x == 0) *flag = sh;  // 1 = fp32, 0 = bf16
}

// ---------------- stage all float inputs as fp32 ----------------
__global__ __launch_bounds__(256) void cvt_kernel(
    const void* p0, const void* p1, const void* p2, const void* p3, const void* p4,
    const void* p5, const void* p6, const void* p7, const void* p8, const void* p9,
    const void* p10, const void* p11, const void* p12, const void* p13, const void* p14,
    const void* p15, const void* p16, const void* p17, const void* p18, const void* p19,
    const void* p20, const void* p21, const void* p22, const void* p23, const void* p24,
    const int* flag, float* dst) {
  const void* srcs[25] = {p0, p1, p2, p3, p4, p5, p6, p7, p8, p9, p10, p11, p12,
                          p13, p14, p15, p16, p17, p18, p19, p20, p21, p22, p23, p24};
  const int off[26] = {O_T, O_V, O_WT, O_BT, O_WV, O_BV, O_EMB, O_WNODE, O_BNODE,
                       O_WSTART, O_BSTART, O_LNG, O_LNB, O_W1, O_ASRC1, O_ADST1,
                       O_B1, O_W2, O_ASRC2, O_ADST2, O_B2, O_WO1, O_BO1, O_WO2,
                       O_BO2, O_TOTAL};
  bool f32 = (*flag != 0);
  int i = blockIdx.x * 256 + threadIdx.x;
  if (i >= O_TOTAL) return;
  int tsel = 0;
#pragma unroll
  for (int k = 1; k < 25; k++)
    if (i >= off[k]) tsel = k;
  int j = i - off[tsel];
  const void* s = srcs[tsel];
  dst[i] = f32 ? ((const float*)s)[j] : __bfloat162float(((const bf16*)s)[j]);
}

// ---------------- CSR build ----------------
__global__ __launch_bounds__(256) void hist_kernel(const int* __restrict__ dst,
                                                   int* __restrict__ indeg) {
  int e = blockIdx.x * 256 + threadIdx.x;
  if (e < EE) atomicAdd(&indeg[dst[e]], 1);
}

__global__ __launch_bounds__(256) void scanA_kernel(const int* indeg, int* bsum) {
  int t = threadIdx.x;
  int s = 0;
  for (int j = 0; j < 128; j++) s += indeg[t * 128 + j];
  bsum[t] = s;
}
__global__ void scanB_kernel(const int* bsum, int* bpre) {
  int run = 0;
  for (int k = 0; k < 256; k++) { bpre[k] = run; run += bsum[k]; }
}
__global__ __launch_bounds__(256) void scanC_kernel(const int* indeg, const int* bpre,
                                                    int* off, int* cursor) {
  int t = threadIdx.x;
  int run = bpre[t];
  for (int j = 0; j < 128; j++) {
    int i = t * 128 + j;
    off[i] = run; cursor[i] = run; run += indeg[i];
  }
  if (t == 255) off[NN] = run;
}

__global__ __launch_bounds__(256) void fill_kernel(const int* __restrict__ src,
                                                   const int* __restrict__ dst,
                                                   int* __restrict__ cursor,
                                                   int* __restrict__ esrc) {
  int e = blockIdx.x * 256 + threadIdx.x;
  if (e < EE) {
    int p = atomicAdd(&cursor[dst[e]], 1);
    esrc[p] = src[e];
  }
}

// ---------------- naive GEMM (small problems only) ----------------
template <typename TA>
__global__ __launch_bounds__(256) void ngemm_kernel(const TA* __restrict__ A,
                                                    const float* __restrict__ B,
                                                    const float* __restrict__ bias,
                                                    float* __restrict__ C,
                                                    int M, int N, int K, int ldc, int act) {
  long gid = (long)blockIdx.x * 256 + threadIdx.x;
  if (gid >= (long)M * N) return;
  int m = (int)(gid / N), n = (int)(gid % N);
  float acc = bias ? bias[n] : 0.f;
  for (int k = 0; k < K; k++)
    acc = fmaf(loadf(&A[(size_t)m * K + k]), B[(size_t)k * N + n], acc);
  if (act == 1) acc = acc > 0.f ? acc : 0.01f * acc;
  C[(size_t)m * ldc + n] = acc;
}

// ---------------- tiled LDS GEMM, 64x64 tile, 4x4/thread ----------------
template <typename TA, typename TC>
__global__ __launch_bounds__(256) void gemm_kernel(const TA* __restrict__ A,
                                                   const float* __restrict__ B,
                                                   const float* __restrict__ bias,
                                                   TC* __restrict__ C, int M, int N, int K,
                                                   int ldc, int act) {
  __shared__ float As[16][65];
  __shared__ float Bs[16][65];
  int tid = threadIdx.x;
  int brow = blockIdx.y * 64;
  int bcol = blockIdx.x * 64;
  int tr = (tid >> 4) << 2;
  int tc = (tid & 15) << 2;
  float acc[4][4] = {};
  for (int k0 = 0; k0 < K; k0 += 16) {
#pragma unroll
    for (int l = 0; l < 4; l++) {
      int idx = tid + l * 256;
      int r = idx >> 4, kk = idx & 15;
      As[kk][r] = loadf(&A[(size_t)(brow + r) * K + (k0 + kk)]);
    }
#pragma unroll
    for (int l = 0; l < 4; l++) {
      int idx = tid + l * 256;
      int kk = idx >> 6, c = idx & 63;
      Bs[kk][c] = B[(size_t)(k0 + kk) * N + (bcol + c)];
    }
    __syncthreads();
#pragma unroll
    for (int kk = 0; kk < 16; kk++) {
      float a[4], b[4];
#pragma unroll
      for (int i = 0; i < 4; i++) a[i] = As[kk][tr + i];
#pragma unroll
      for (int j = 0; j < 4; j++) b[j] = Bs[kk][tc + j];
#pragma unroll
      for (int i = 0; i < 4; i++)
#pragma unroll
        for (int j = 0; j < 4; j++) acc[i][j] = fmaf(a[i], b[j], acc[i][j]);
    }
    __syncthreads();
  }
#pragma unroll
  for (int i = 0; i < 4; i++) {
#pragma unroll
    for (int j = 0; j < 4; j++) {
      float v = acc[i][j];
      if (bias) v += bias[bcol + tc + j];
      if (act == 1) v = v > 0.f ? v : 0.01f * v;
      storef(&C[(size_t)(brow + tr + i) * ldc + (bcol + tc + j)], v);
    }
  }
}

// ---------------- layernorm, wave per node (coalesced) ----------------
__global__ __launch_bounds__(256) void ln_wave(const float* __restrict__ start,
                                               const float* __restrict__ emb2,
                                               const int* __restrict__ m_idx,
                                               const float* __restrict__ lng,
                                               const float* __restrict__ lnb,
                                               float* __restrict__ x0) {
  int i = blockIdx.x * 4 + (threadIdx.x >> 6);
  int lane = threadIdx.x & 63;
  int g = i >> 6, n = i & 63;
  const float* row = (n == 0) ? (start + (size_t)g * 128) : (emb2 + (size_t)m_idx[i] * 128);
  float2 v = ((const float2*)row)[lane];
  float mu = wred_sum(v.x + v.y) * (1.f / 128.f);
  float dx = v.x - mu, dy = v.y - mu;
  float var = wred_sum(dx * dx + dy * dy) * (1.f / 128.f);
  float rstd = rsqrtf(var + 1e-6f);
  float2 gg = ((const float2*)lng)[lane];
  float2 bb = ((const float2*)lnb)[lane];
  ((float2*)(x0 + (size_t)i * 128))[lane] =
      make_float2(dx * rstd * gg.x + bb.x, dy * rstd * gg.y + bb.y);
}

// ---------------- attention coefficients, wave per (node,head), xp bf16 ----------------
__global__ __launch_bounds__(256) void al1_wave(const unsigned* __restrict__ xp,
                                                const float* __restrict__ a_src,
                                                const float* __restrict__ a_dst,
                                                float* __restrict__ als,
                                                float* __restrict__ ald) {
  int id = blockIdx.x * 4 + (threadIdx.x >> 6);  // (node,head)
  int lane = threadIdx.x & 63;
  int i = id >> 2, h = id & 3;
  float2 x = unpk(xp[(size_t)i * 256 + h * 64 + lane]);
  float2 as = ((const float2*)(a_src + h * 128))[lane];
  float2 ad = ((const float2*)(a_dst + h * 128))[lane];
  float ps = wred_sum(x.x * as.x + x.y * as.y);
  float pd = wred_sum(x.x * ad.x + x.y * ad.y);
  if (lane == 0) { als[id] = ps; ald[id] = pd; }
}

__global__ __launch_bounds__(256) void al2_wave(const unsigned* __restrict__ xp,
                                                const float* __restrict__ a_src,
                                                const float* __restrict__ a_dst,
                                                float* __restrict__ als,
                                                float* __restrict__ ald) {
  int i = blockIdx.x * 4 + (threadIdx.x >> 6);
  int lane = threadIdx.x & 63;
  float2 x = unpk(xp[(size_t)i * 64 + lane]);
  float2 as = ((const float2*)a_src)[lane];
  float2 ad = ((const float2*)a_dst)[lane];
  float ps = wred_sum(x.x * as.x + x.y * as.y);
  float pd = wred_sum(x.x * ad.x + x.y * ad.y);
  if (lane == 0) { als[i] = ps; ald[i] = pd; }
}

// ---------------- softmax weights ----------------
__global__ __launch_bounds__(256) void alpha1_kernel(const float* __restrict__ als,
                                                     const float* __restrict__ ald,
                                                     const int* __restrict__ off,
                                                     const int* __restrict__ esrc,
                                                     float* __restrict__ aw,
                                                     float* __restrict__ selfw,
                                                     float* __restrict__ inv) {
  int id = blockIdx.x * 256 + threadIdx.x;
  if (id >= NN * 4) return;
  int i = id >> 2, h = id & 3;
  float adi = ald[id];
  float selfSc = als[id] + adi;
  selfSc = selfSc > 0.f ? selfSc : 0.2f * selfSc;
  int s0 = off[i], s1 = off[i + 1];
  float m = selfSc;
  for (int e = s0; e < s1; e++) {
    float sc = als[esrc[e] * 4 + h] + adi;
    sc = sc > 0.f ? sc : 0.2f * sc;
    m = fmaxf(m, sc);
  }
  float sw = __expf(selfSc - m);
  float denom = sw;
  for (int e = s0; e < s1; e++) {
    float sc = als[esrc[e] * 4 + h] + adi;
    sc = sc > 0.f ? sc : 0.2f * sc;
    float w = __expf(sc - m);
    aw[e * 4 + h] = w;
    denom += w;
  }
  selfw[id] = sw;
  inv[id] = 1.f / denom;
}

__global__ __launch_bounds__(256) void alpha2_kernel(const float* __restrict__ als,
                                                     const float* __restrict__ ald,
                                                     const int* __restrict__ off,
                                                     const int* __restrict__ esrc,
                                                     float* __restrict__ aw,
                                                     float* __restrict__ selfw,
                                                     float* __restrict__ inv) {
  int i = blockIdx.x * 256 + threadIdx.x;
  if (i >= NN) return;
  float adi = ald[i];
  float selfSc = als[i] + adi;
  selfSc = selfSc > 0.f ? selfSc : 0.2f * selfSc;
  int s0 = off[i], s1 = off[i + 1];
  float m = selfSc;
  for (int e = s0; e < s1; e++) {
    float sc = als[esrc[e]] + adi;
    sc = sc > 0.f ? sc : 0.2f * sc;
    m = fmaxf(m, sc);
  }
  float sw = __expf(selfSc - m);
  float denom = sw;
  for (int e = s0; e < s1; e++) {
    float sc = als[esrc[e]] + adi;
    sc = sc > 0.f ? sc : 0.2f * sc;
    float w = __expf(sc - m);
    aw[e] = w;
    denom += w;
  }
  selfw[i] = sw;
  inv[i] = 1.f / denom;
}

// ---------------- weighted gather, conv1: thread per (node, uint2) ----------------
// 4 cols/thread, 2-wide edge unroll for MLP
__global__ __launch_bounds__(256) void agg1w_kernel(const uint2* __restrict__ xp,
                                                    const float* __restrict__ aw,
                                                    const float* __restrict__ selfw,
                                                    const float* __restrict__ inv,
                                                    const int* __restrict__ off,
                                                    const int* __restrict__ esrc,
                                                    const float* __restrict__ b1,
                                                    uint2* __restrict__ x1) {
  long gid = (long)blockIdx.x * 256 + threadIdx.x;
  if (gid >= (long)NN * 128) return;
  int i = (int)(gid >> 7), c4 = (int)(gid & 127), h = c4 >> 5;
  float sw = selfw[i * 4 + h];
  float iv = inv[i * 4 + h];
  uint2 xv = xp[(size_t)i * 128 + c4];
  float2 xa = unpk(xv.x), xb = unpk(xv.y);
  float4 acc = make_float4(sw * xa.x, sw * xa.y, sw * xb.x, sw * xb.y);
  int s0 = off[i], s1 = off[i + 1];
  int e = s0;
  for (; e + 1 < s1; e += 2) {
    int sA = esrc[e], sB = esrc[e + 1];
    float wA = aw[e * 4 + h], wB = aw[(e + 1) * 4 + h];
    uint2 mA = xp[(size_t)sA * 128 + c4];
    uint2 mB = xp[(size_t)sB * 128 + c4];
    float2 a0 = unpk(mA.x), a1 = unpk(mA.y);
    float2 b0 = unpk(mB.x), b1v = unpk(mB.y);
    acc.x = fmaf(wA, a0.x, acc.x); acc.y = fmaf(wA, a0.y, acc.y);
    acc.z = fmaf(wA, a1.x, acc.z); acc.w = fmaf(wA, a1.y, acc.w);
    acc.x = fmaf(wB, b0.x, acc.x); acc.y = fmaf(wB, b0.y, acc.y);
    acc.z = fmaf(wB, b1v.x, acc.z); acc.w = fmaf(wB, b1v.y, acc.w);
  }
  if (e < s1) {
    int sA = esrc[e];
    float wA = aw[e * 4 + h];
    uint2 mA = xp[(size_t)sA * 128 + c4];
    float2 a0 = unpk(mA.x), a1 = unpk(mA.y);
    acc.x = fmaf(wA, a0.x, acc.x); acc.y = fmaf(wA, a0.y, acc.y);
    acc.z = fmaf(wA, a1.x, acc.z); acc.w = fmaf(wA, a1.y, acc.w);
  }
  float4 bb = ((const float4*)b1)[c4];
  float v0 = acc.x * iv + bb.x;
  float v1 = acc.y * iv + bb.y;
  float v2 = acc.z * iv + bb.z;
  float v3 = acc.w * iv + bb.w;
  v0 = v0 > 0.f ? v0 : (__expf(v0) - 1.f);
  v1 = v1 > 0.f ? v1 : (__expf(v1) - 1.f);
  v2 = v2 > 0.f ? v2 : (__expf(v2) - 1.f);
  v3 = v3 > 0.f ? v3 : (__expf(v3) - 1.f);
  uint2 o;
  o.x = pk(v0, v1);
  o.y = pk(v2, v3);
  x1[gid] = o;
}

// ---------------- weighted gather, conv2: thread per (node, uint2) ----------------
__global__ __launch_bounds__(256) void agg2w_kernel(const uint2* __restrict__ xp,
                                                    const float* __restrict__ aw,
                                                    const float* __restrict__ selfw,
                                                    const float* __restrict__ inv,
                                                    const int* __restrict__ off,
                                                    const int* __restrict__ esrc,
                                                    const float* __restrict__ b2,
                                                    float4* __restrict__ x2) {
  long gid = (long)blockIdx.x * 256 + threadIdx.x;
  if (gid >= (long)NN * 32) return;
  int i = (int)(gid >> 5), c4 = (int)(gid & 31);
  float sw = selfw[i];
  float iv = inv[i];
  uint2 xv = xp[(size_t)i * 32 + c4];
  float2 xa = unpk(xv.x), xb = unpk(xv.y);
  float4 acc = make_float4(sw * xa.x, sw * xa.y, sw * xb.x, sw * xb.y);
  int s0 = off[i], s1 = off[i + 1];
  int e = s0;
  for (; e + 1 < s1; e += 2) {
    int sA = esrc[e], sB = esrc[e + 1];
    float wA = aw[e], wB = aw[e + 1];
    uint2 mA = xp[(size_t)sA * 32 + c4];
    uint2 mB = xp[(size_t)sB * 32 + c4];
    float2 a0 = unpk(mA.x), a1 = unpk(mA.y);
    float2 b0 = unpk(mB.x), b1v = unpk(mB.y);
    acc.x = fmaf(wA, a0.x, acc.x); acc.y = fmaf(wA, a0.y, acc.y);
    acc.z = fmaf(wA, a1.x, acc.z); acc.w = fmaf(wA, a1.y, acc.w);
    acc.x = fmaf(wB, b0.x, acc.x); acc.y = fmaf(wB, b0.y, acc.y);
    acc.z = fmaf(wB, b1v.x, acc.z); acc.w = fmaf(wB, b1v.y, acc.w);
  }
  if (e < s1) {
    int sA = esrc[e];
    float wA = aw[e];
    uint2 mA = xp[(size_t)sA * 32 + c4];
    float2 a0 = unpk(mA.x), a1 = unpk(mA.y);
    acc.x = fmaf(wA, a0.x, acc.x); acc.y = fmaf(wA, a0.y, acc.y);
    acc.z = fmaf(wA, a1.x, acc.z); acc.w = fmaf(wA, a1.y, acc.w);
  }
  float4 bb = ((const float4*)b2)[c4];
  float v0 = acc.x * iv + bb.x;
  float v1 = acc.y * iv + bb.y;
  float v2 = acc.z * iv + bb.z;
  float v3 = acc.w * iv + bb.w;
  v0 = v0 > 0.f ? v0 : (__expf(v0) - 1.f);
  v1 = v1 > 0.f ? v1 : (__expf(v1) - 1.f);
  v2 = v2 > 0.f ? v2 : (__expf(v2) - 1.f);
  v3 = v3 > 0.f ? v3 : (__expf(v3) - 1.f);
  x2[gid] = make_float4(v0, v1, v2, v3);
}

// ---------------- masked mean pool ----------------
__global__ __launch_bounds__(128) void pool_kernel(const float* __restrict__ x2,
                                                   const int* __restrict__ m_idx,
                                                   float* __restrict__ pooled) {
  int g = blockIdx.x, c = threadIdx.x;
  float acc = 0.f, cnt = 0.f;
  const float* xr = x2 + (size_t)g * 64 * 128;
  const int* mi = m_idx + g * 64;
  for (int n = 0; n < 64; n++) {
    if (mi[n] >= 1) { cnt += 1.f; acc += xr[n * 128 + c]; }
  }
  pooled[(size_t)g * 128 + c] = acc / cnt;
}

// ---------------- final logit ----------------
__global__ __launch_bounds__(256) void head2_naive(const float* __restrict__ h1,
                                                   const float* __restrict__ Wo2,
                                                   const float* __restrict__ bo2,
                                                   float* __restrict__ out) {
  int g = blockIdx.x * 256 + threadIdx.x;
  if (g >= GG) return;
  float p = bo2[0];
  for (int c = 0; c < 128; c++) p = fmaf(h1[(size_t)g * 128 + c], Wo2[c], p);
  out[g] = p;
}

extern "C" void kernel_launch(void* const* d_in, const int* in_sizes, int n_in, void* d_out,
                              int out_size, void* d_ws, size_t ws_size, hipStream_t stream) {
  (void)n_in; (void)out_size; (void)ws_size;
  bool dict_order = (in_sizes[2] == NN);
  int IM, IE, IF[25];
  if (dict_order) {
    IM = 2; IE = 3;
    const int f[25] = {0, 1, 4, 5, 6, 7, 8, 9, 10, 11, 12, 13, 14, 15, 16, 17, 18,
                       19, 20, 21, 22, 23, 24, 25, 26};
    for (int k = 0; k < 25; k++) IF[k] = f[k];
  } else {
    IM = 25; IE = 26;
    for (int k = 0; k < 25; k++) IF[k] = k;
  }
  const int* m_idx = (const int*)d_in[IM];
  const int* eidx = (const int*)d_in[IE];
  float* out = (float*)d_out;
  const int* e_src = eidx;
  const int* e_dst = eidx + EE;

  // workspace layout (peak ~101 MB)
  char* w = (char*)d_ws;
  bf16* xp1b = (bf16*)(w);                           // [NN,512] bf16 [0,32) MB
  float* x0 = (float*)(w + ((size_t)32 << 20));      // [NN,128] f32 [32,48) MB
  bf16* x1 = (bf16*)(w + ((size_t)48 << 20));        // [NN,512] bf16 [48,80) MB
  bf16* xp2b = (bf16*)(w);                           // [NN,128] bf16 [0,8)  (xp1b dead)
  float* x2 = (float*)(w + ((size_t)8 << 20));       // [NN,128] f32 [8,24)
  size_t so = (size_t)80 << 20;                      // smalls [80,~95) MB
  float* vt = (float*)(w + so); so += 512 * 256 * 4;
  float* start = (float*)(w + so); so += 512 * 128 * 4;
  float* emb2 = (float*)(w + so); so += 51 * 128 * 4 + 256;
  float* als1 = (float*)(w + so); so += NN * 4 * 4;
  float* ald1 = (float*)(w + so); so += NN * 4 * 4;
  float* als2 = (float*)(w + so); so += NN * 4;
  float* ald2 = (float*)(w + so); so += NN * 4;
  float* aw1 = (float*)(w + so); so += EE * 4 * 4;   // 4 MB
  float* selfw1 = (float*)(w + so); so += NN * 4 * 4;
  float* inv1 = (float*)(w + so); so += NN * 4 * 4;
  float* aw2 = (float*)(w + so); so += EE * 4;       // 1 MB
  float* selfw2 = (float*)(w + so); so += NN * 4;
  float* inv2 = (float*)(w + so); so += NN * 4;
  float* pooled = (float*)(w + so); so += 512 * 128 * 4;
  float* h1 = (float*)(w + so); so += 512 * 128 * 4;
  int* indeg = (int*)(w + so); so += NN * 4;
  int* csroff = (int*)(w + so); so += (NN + 1) * 4 + 252;
  int* cursor = (int*)(w + so); so += NN * 4;
  int* esrc = (int*)(w + so); so += EE * 4;
  int* bsum = (int*)(w + so); so += 256 * 4;
  int* bpre = (int*)(w + so); so += 256 * 4;
  int* dflag = (int*)(w + so); so += 256;
  float* stage = (float*)(w + ((size_t)96 << 20));   // [96,~100.6) MB

  probe_kernel<<<1, 256, 0, stream>>>(d_in[0], dflag);
  cvt_kernel<<<(O_TOTAL + 255) / 256, 256, 0, stream>>>(
      d_in[IF[0]], d_in[IF[1]], d_in[IF[2]], d_in[IF[3]], d_in[IF[4]], d_in[IF[5]],
      d_in[IF[6]], d_in[IF[7]], d_in[IF[8]], d_in[IF[9]], d_in[IF[10]], d_in[IF[11]],
      d_in[IF[12]], d_in[IF[13]], d_in[IF[14]], d_in[IF[15]], d_in[IF[16]], d_in[IF[17]],
      d_in[IF[18]], d_in[IF[19]], d_in[IF[20]], d_in[IF[21]], d_in[IF[22]], d_in[IF[23]],
      d_in[IF[24]], dflag, stage);

  const float* t = stage + O_T;
  const float* v = stage + O_V;
  const float* Wt = stage + O_WT;       const float* bt = stage + O_BT;
  const float* Wv = stage + O_WV;       const float* bv = stage + O_BV;
  const float* emb = stage + O_EMB;
  const float* Wnode = stage + O_WNODE; const float* bnode = stage + O_BNODE;
  const float* Wstart = stage + O_WSTART; const float* bstart = stage + O_BSTART;
  const float* ln_g = stage + O_LNG;    const float* ln_b = stage + O_LNB;
  const float* W1 = stage + O_W1;
  const float* a_src1 = stage + O_ASRC1; const float* a_dst1 = stage + O_ADST1;
  const float* b1 = stage + O_B1;
  const float* W2 = stage + O_W2;
  const float* a_src2 = stage + O_ASRC2; const float* a_dst2 = stage + O_ADST2;
  const float* b2 = stage + O_B2;
  const float* Wo1 = stage + O_WO1;     const float* bo1 = stage + O_BO1;
  const float* Wo2 = stage + O_WO2;     const float* bo2 = stage + O_BO2;

  hipMemsetAsync(indeg, 0, NN * 4, stream);
  hist_kernel<<<EE / 256, 256, 0, stream>>>(e_dst, indeg);
  scanA_kernel<<<1, 256, 0, stream>>>(indeg, bsum);
  scanB_kernel<<<1, 1, 0, stream>>>(bsum, bpre);
  scanC_kernel<<<1, 256, 0, stream>>>(indeg, bpre, csroff, cursor);
  fill_kernel<<<EE / 256, 256, 0, stream>>>(e_src, e_dst, cursor, esrc);

  ngemm_kernel<float><<<(51 * 128 + 255) / 256, 256, 0, stream>>>(emb, Wnode, bnode, emb2, 51, 128, 128, 128, 0);
  gemm_kernel<float, float><<<dim3(2, 8), 256, 0, stream>>>(v, Wv, bv, vt, 512, 128, 768, 256, 0);
  gemm_kernel<float, float><<<dim3(2, 8), 256, 0, stream>>>(t, Wt, bt, vt + 128, 512, 128, 768, 256, 0);
  gemm_kernel<float, float><<<dim3(2, 8), 256, 0, stream>>>(vt, Wstart, bstart, start, 512, 128, 256, 128, 0);
  ln_wave<<<NN / 4, 256, 0, stream>>>(start, emb2, m_idx, ln_g, ln_b, x0);

  // conv1: GEMM -> bf16 xp1
  gemm_kernel<float, bf16><<<dim3(8, NN / 64), 256, 0, stream>>>(x0, W1, nullptr, xp1b, NN, 512, 128, 512, 0);
  al1_wave<<<NN, 256, 0, stream>>>((const unsigned*)xp1b, a_src1, a_dst1, als1, ald1);
  alpha1_kernel<<<NN * 4 / 256, 256, 0, stream>>>(als1, ald1, csroff, esrc, aw1, selfw1, inv1);
  agg1w_kernel<<<(int)(((long)NN * 128 + 255) / 256), 256, 0, stream>>>(
      (const uint2*)xp1b, aw1, selfw1, inv1, csroff, esrc, b1, (uint2*)x1);

  // conv2: GEMM -> bf16 xp2
  gemm_kernel<bf16, bf16><<<dim3(2, NN / 64), 256, 0, stream>>>(x1, W2, nullptr, xp2b, NN, 128, 512, 128, 0);
  al2_wave<<<NN / 4, 256, 0, stream>>>((const unsigned*)xp2b, a_src2, a_dst2, als2, ald2);
  alpha2_kernel<<<NN / 256, 256, 0, stream>>>(als2, ald2, csroff, esrc, aw2, selfw2, inv2);
  agg2w_kernel<<<(int)(((long)NN * 32 + 255) / 256), 256, 0, stream>>>(
      (const uint2*)xp2b, aw2, selfw2, inv2, csroff, esrc, b2, (float4*)x2);

  pool_kernel<<<GG, 128, 0, stream>>>(x2, m_idx, pooled);
  gemm_kernel<float, float><<<dim3(2, 8), 256, 0, stream>>>(pooled, Wo1, bo1, h1, 512, 128, 128, 128, 1);
  head2_naive<<<(GG + 255) / 256, 256, 0, stream>>>(h1, Wo2, bo2, out);
}

// Round 11
// 659.825 us; speedup vs baseline: 3.7590x; 1.2013x over previous
//
#include <hip/hip_runtime.h>
#include <hip/hip_bf16.h>

typedef __hip_bfloat16 bf16;
typedef __attribute__((ext_vector_type(8))) short s8v;   // 8 bf16 (4 VGPRs)
typedef __attribute__((ext_vector_type(4))) float f4v;   // 4 fp32 acc

#define NN 32768   // total nodes
#define EE 262144  // edges
#define GG 512     // graphs

// ---- staged fp32 input offsets (element units) ----
#define O_T      0
#define O_V      393216
#define O_WT     786432
#define O_BT     884736
#define O_WV     884864
#define O_BV     983168
#define O_EMB    983296
#define O_WNODE  989824
#define O_BNODE  1006208
#define O_WSTART 1006336
#define O_BSTART 1039104
#define O_LNG    1039232
#define O_LNB    1039360
#define O_W1     1039488
#define O_ASRC1  1105024
#define O_ADST1  1105536
#define O_B1     1106048
#define O_W2     1106560
#define O_ASRC2  1172096
#define O_ADST2  1172224
#define O_B2     1172352
#define O_WO1    1172480
#define O_BO1    1188864
#define O_WO2    1188992
#define O_BO2    1189120
#define O_TOTAL  1189121

__device__ __forceinline__ float loadf(const float* p) { return *p; }
__device__ __forceinline__ float loadf(const bf16* p) { return __bfloat162float(*p); }
__device__ __forceinline__ void storef(float* p, float v) { *p = v; }
__device__ __forceinline__ void storef(bf16* p, float v) { *p = __float2bfloat16(v); }

__device__ __forceinline__ float2 unpk(unsigned u) {
  float2 r;
  r.x = __uint_as_float(u << 16);
  r.y = __uint_as_float(u & 0xffff0000u);
  return r;
}
__device__ __forceinline__ unsigned pk(float x, float y) {
  union { bf16 h[2]; unsigned u; } p;
  p.h[0] = __float2bfloat16(x);
  p.h[1] = __float2bfloat16(y);
  return p.u;
}
__device__ __forceinline__ short f2bf_bits(float x) {
  bf16 h = __float2bfloat16(x);
  return *reinterpret_cast<short*>(&h);
}

__device__ __forceinline__ float wred_sum(float v) {
#pragma unroll
  for (int o = 32; o; o >>= 1) v += __shfl_xor(v, o, 64);
  return v;
}

// ---------------- dtype probe ----------------
__global__ __launch_bounds__(256) void probe_kernel(const void* t, int* flag) {
  const unsigned short* u = (const unsigned short*)t;
  int big = 0;
  for (int k = threadIdx.x; k < 1024; k += 256) {
    unsigned e = (u[k] >> 7) & 0xFF;
    if (e >= 141) big = 1;
  }
  __shared__ int sh;
  if (threadIdx.x == 0) sh = 0;
  __syncthreads();
  if (big) atomicOr(&sh, 1);
  __syncthreads();
  if (threadIdx.x == 0) *flag = sh;  // 1 = fp32, 0 = bf16
}

// ---------------- stage all float inputs as fp32 ----------------
__global__ __launch_bounds__(256) void cvt_kernel(
    const void* p0, const void* p1, const void* p2, const void* p3, const void* p4,
    const void* p5, const void* p6, const void* p7, const void* p8, const void* p9,
    const void* p10, const void* p11, const void* p12, const void* p13, const void* p14,
    const void* p15, const void* p16, const void* p17, const void* p18, const void* p19,
    const void* p20, const void* p21, const void* p22, const void* p23, const void* p24,
    const int* flag, float* dst) {
  const void* srcs[25] = {p0, p1, p2, p3, p4, p5, p6, p7, p8, p9, p10, p11, p12,
                          p13, p14, p15, p16, p17, p18, p19, p20, p21, p22, p23, p24};
  const int off[26] = {O_T, O_V, O_WT, O_BT, O_WV, O_BV, O_EMB, O_WNODE, O_BNODE,
                       O_WSTART, O_BSTART, O_LNG, O_LNB, O_W1, O_ASRC1, O_ADST1,
                       O_B1, O_W2, O_ASRC2, O_ADST2, O_B2, O_WO1, O_BO1, O_WO2,
                       O_BO2, O_TOTAL};
  bool f32 = (*flag != 0);
  int i = blockIdx.x * 256 + threadIdx.x;
  if (i >= O_TOTAL) return;
  int tsel = 0;
#pragma unroll
  for (int k = 1; k < 25; k++)
    if (i >= off[k]) tsel = k;
  int j = i - off[tsel];
  const void* s = srcs[tsel];
  dst[i] = f32 ? ((const float*)s)[j] : __bfloat162float(((const bf16*)s)[j]);
}

// ---------------- CSR build ----------------
__global__ __launch_bounds__(256) void hist_kernel(const int* __restrict__ dst,
                                                   int* __restrict__ indeg) {
  int e = blockIdx.x * 256 + threadIdx.x;
  if (e < EE) atomicAdd(&indeg[dst[e]], 1);
}

__global__ __launch_bounds__(256) void scanA_kernel(const int* indeg, int* bsum) {
  int t = threadIdx.x;
  int s = 0;
  for (int j = 0; j < 128; j++) s += indeg[t * 128 + j];
  bsum[t] = s;
}
__global__ void scanB_kernel(const int* bsum, int* bpre) {
  int run = 0;
  for (int k = 0; k < 256; k++) { bpre[k] = run; run += bsum[k]; }
}
__global__ __launch_bounds__(256) void scanC_kernel(const int* indeg, const int* bpre,
                                                    int* off, int* cursor) {
  int t = threadIdx.x;
  int run = bpre[t];
  for (int j = 0; j < 128; j++) {
    int i = t * 128 + j;
    off[i] = run; cursor[i] = run; run += indeg[i];
  }
  if (t == 255) off[NN] = run;
}

__global__ __launch_bounds__(256) void fill_kernel(const int* __restrict__ src,
                                                   const int* __restrict__ dst,
                                                   int* __restrict__ cursor,
                                                   int* __restrict__ esrc) {
  int e = blockIdx.x * 256 + threadIdx.x;
  if (e < EE) {
    int p = atomicAdd(&cursor[dst[e]], 1);
    esrc[p] = src[e];
  }
}

// ---------------- naive GEMM (small problems only) ----------------
template <typename TA>
__global__ __launch_bounds__(256) void ngemm_kernel(const TA* __restrict__ A,
                                                    const float* __restrict__ B,
                                                    const float* __restrict__ bias,
                                                    float* __restrict__ C,
                                                    int M, int N, int K, int ldc, int act) {
  long gid = (long)blockIdx.x * 256 + threadIdx.x;
  if (gid >= (long)M * N) return;
  int m = (int)(gid / N), n = (int)(gid % N);
  float acc = bias ? bias[n] : 0.f;
  for (int k = 0; k < K; k++)
    acc = fmaf(loadf(&A[(size_t)m * K + k]), B[(size_t)k * N + n], acc);
  if (act == 1) acc = acc > 0.f ? acc : 0.01f * acc;
  C[(size_t)m * ldc + n] = acc;
}

// ---------------- tiled LDS GEMM, 64x64 tile, 4x4/thread (small fp32 gemms) ----------------
template <typename TA, typename TC>
__global__ __launch_bounds__(256) void gemm_kernel(const TA* __restrict__ A,
                                                   const float* __restrict__ B,
                                                   const float* __restrict__ bias,
                                                   TC* __restrict__ C, int M, int N, int K,
                                                   int ldc, int act) {
  __shared__ float As[16][65];
  __shared__ float Bs[16][65];
  int tid = threadIdx.x;
  int brow = blockIdx.y * 64;
  int bcol = blockIdx.x * 64;
  int tr = (tid >> 4) << 2;
  int tc = (tid & 15) << 2;
  float acc[4][4] = {};
  for (int k0 = 0; k0 < K; k0 += 16) {
#pragma unroll
    for (int l = 0; l < 4; l++) {
      int idx = tid + l * 256;
      int r = idx >> 4, kk = idx & 15;
      As[kk][r] = loadf(&A[(size_t)(brow + r) * K + (k0 + kk)]);
    }
#pragma unroll
    for (int l = 0; l < 4; l++) {
      int idx = tid + l * 256;
      int kk = idx >> 6, c = idx & 63;
      Bs[kk][c] = B[(size_t)(k0 + kk) * N + (bcol + c)];
    }
    __syncthreads();
#pragma unroll
    for (int kk = 0; kk < 16; kk++) {
      float a[4], b[4];
#pragma unroll
      for (int i = 0; i < 4; i++) a[i] = As[kk][tr + i];
#pragma unroll
      for (int j = 0; j < 4; j++) b[j] = Bs[kk][tc + j];
#pragma unroll
      for (int i = 0; i < 4; i++)
#pragma unroll
        for (int j = 0; j < 4; j++) acc[i][j] = fmaf(a[i], b[j], acc[i][j]);
    }
    __syncthreads();
  }
#pragma unroll
  for (int i = 0; i < 4; i++) {
#pragma unroll
    for (int j = 0; j < 4; j++) {
      float v = acc[i][j];
      if (bias) v += bias[bcol + tc + j];
      if (act == 1) v = v > 0.f ? v : 0.01f * v;
      storef(&C[(size_t)(brow + tr + i) * ldc + (bcol + tc + j)], v);
    }
  }
}

// ---------------- pack W (f32, KxN row-major) into MFMA B-fragment order ----------------
// Bp[(nt*(K/32)+ks)*64+lane] = 8 bf16: B[k][n], n=nt*16+(lane&15), k=ks*32+(lane>>4)*8+j
__global__ __launch_bounds__(256) void packB_kernel(const float* __restrict__ W, int N, int K,
                                                    s8v* __restrict__ Bp) {
  int id = blockIdx.x * 256 + threadIdx.x;
  int total = (N >> 4) * (K >> 5) * 64;
  if (id >= total) return;
  int lane = id & 63;
  int tmp = id >> 6;
  int ksteps = K >> 5;
  int ks = tmp % ksteps;
  int nt = tmp / ksteps;
  int n = nt * 16 + (lane & 15);
  int kbase = ks * 32 + (lane >> 4) * 8;
  s8v r;
#pragma unroll
  for (int j = 0; j < 8; j++) r[j] = f2bf_bits(W[(size_t)(kbase + j) * N + n]);
  Bp[id] = r;
}

// ---------------- MFMA bf16 GEMM: C[M,N] = A[M,K] @ B, no bias/act, bf16 out ----------------
// block 256 = 4 waves; tile 64 rows x 64 cols; wave w covers rows 16w..16w+15.
// A row-major bf16; Bp pre-packed fragments; M%64==0, N%64==0, K%32==0.
__global__ __launch_bounds__(256) void gemm_mfma(const short* __restrict__ A,
                                                 const s8v* __restrict__ Bp,
                                                 short* __restrict__ C,
                                                 int M, int N, int K) {
  __shared__ short lds[64 * 64];
  int tid = threadIdx.x;
  int wv = tid >> 6, lane = tid & 63;
  int quad = lane >> 4, l16 = lane & 15;
  int brow = blockIdx.y * 64, bcol = blockIdx.x * 64;
  int m = brow + wv * 16 + l16;
  int ksteps = K >> 5;
  f4v acc[4] = {};
  const s8v* Arow = (const s8v*)(A + (size_t)m * K);
  for (int ks = 0; ks < ksteps; ks++) {
    s8v a = Arow[ks * 4 + quad];
#pragma unroll
    for (int nt = 0; nt < 4; nt++) {
      s8v b = Bp[(size_t)(((bcol >> 4) + nt) * ksteps + ks) * 64 + lane];
      acc[nt] = __builtin_amdgcn_mfma_f32_16x16x32_bf16(a, b, acc[nt], 0, 0, 0);
    }
  }
  // epilogue: C/D layout col=lane&15, row=quad*4+reg  -> LDS bf16 tile
#pragma unroll
  for (int nt = 0; nt < 4; nt++)
#pragma unroll
    for (int r = 0; r < 4; r++)
      lds[(wv * 16 + quad * 4 + r) * 64 + nt * 16 + l16] = f2bf_bits(acc[nt][r]);
  __syncthreads();
#pragma unroll
  for (int rep = 0; rep < 2; rep++) {
    int idx = rep * 256 + tid;          // 512 x uint4 (8 bf16 each)
    int row = idx >> 3, c16 = idx & 7;
    uint4 val = ((const uint4*)lds)[idx];
    *(uint4*)(C + (size_t)(brow + row) * N + bcol + c16 * 8) = val;
  }
}

// ---------------- layernorm, wave per node -> packed bf16 out ----------------
__global__ __launch_bounds__(256) void ln_wave(const float* __restrict__ start,
                                               const float* __restrict__ emb2,
                                               const int* __restrict__ m_idx,
                                               const float* __restrict__ lng,
                                               const float* __restrict__ lnb,
                                               unsigned* __restrict__ x0b) {
  int i = blockIdx.x * 4 + (threadIdx.x >> 6);
  int lane = threadIdx.x & 63;
  int g = i >> 6, n = i & 63;
  const float* row = (n == 0) ? (start + (size_t)g * 128) : (emb2 + (size_t)m_idx[i] * 128);
  float2 v = ((const float2*)row)[lane];
  float mu = wred_sum(v.x + v.y) * (1.f / 128.f);
  float dx = v.x - mu, dy = v.y - mu;
  float var = wred_sum(dx * dx + dy * dy) * (1.f / 128.f);
  float rstd = rsqrtf(var + 1e-6f);
  float2 gg = ((const float2*)lng)[lane];
  float2 bb = ((const float2*)lnb)[lane];
  x0b[(size_t)i * 64 + lane] = pk(dx * rstd * gg.x + bb.x, dy * rstd * gg.y + bb.y);
}

// ---------------- attention coefficients, wave per (node,head), xp bf16 ----------------
__global__ __launch_bounds__(256) void al1_wave(const unsigned* __restrict__ xp,
                                                const float* __restrict__ a_src,
                                                const float* __restrict__ a_dst,
                                                float* __restrict__ als,
                                                float* __restrict__ ald) {
  int id = blockIdx.x * 4 + (threadIdx.x >> 6);  // (node,head)
  int lane = threadIdx.x & 63;
  int i = id >> 2, h = id & 3;
  float2 x = unpk(xp[(size_t)i * 256 + h * 64 + lane]);
  float2 as = ((const float2*)(a_src + h * 128))[lane];
  float2 ad = ((const float2*)(a_dst + h * 128))[lane];
  float ps = wred_sum(x.x * as.x + x.y * as.y);
  float pd = wred_sum(x.x * ad.x + x.y * ad.y);
  if (lane == 0) { als[id] = ps; ald[id] = pd; }
}

__global__ __launch_bounds__(256) void al2_wave(const unsigned* __restrict__ xp,
                                                const float* __restrict__ a_src,
                                                const float* __restrict__ a_dst,
                                                float* __restrict__ als,
                                                float* __restrict__ ald) {
  int i = blockIdx.x * 4 + (threadIdx.x >> 6);
  int lane = threadIdx.x & 63;
  float2 x = unpk(xp[(size_t)i * 64 + lane]);
  float2 as = ((const float2*)a_src)[lane];
  float2 ad = ((const float2*)a_dst)[lane];
  float ps = wred_sum(x.x * as.x + x.y * as.y);
  float pd = wred_sum(x.x * ad.x + x.y * ad.y);
  if (lane == 0) { als[i] = ps; ald[i] = pd; }
}

// ---------------- softmax weights ----------------
__global__ __launch_bounds__(256) void alpha1_kernel(const float* __restrict__ als,
                                                     const float* __restrict__ ald,
                                                     const int* __restrict__ off,
                                                     const int* __restrict__ esrc,
                                                     float* __restrict__ aw,
                                                     float* __restrict__ selfw,
                                                     float* __restrict__ inv) {
  int id = blockIdx.x * 256 + threadIdx.x;
  if (id >= NN * 4) return;
  int i = id >> 2, h = id & 3;
  float adi = ald[id];
  float selfSc = als[id] + adi;
  selfSc = selfSc > 0.f ? selfSc : 0.2f * selfSc;
  int s0 = off[i], s1 = off[i + 1];
  float m = selfSc;
  for (int e = s0; e < s1; e++) {
    float sc = als[esrc[e] * 4 + h] + adi;
    sc = sc > 0.f ? sc : 0.2f * sc;
    m = fmaxf(m, sc);
  }
  float sw = __expf(selfSc - m);
  float denom = sw;
  for (int e = s0; e < s1; e++) {
    float sc = als[esrc[e] * 4 + h] + adi;
    sc = sc > 0.f ? sc : 0.2f * sc;
    float w = __expf(sc - m);
    aw[e * 4 + h] = w;
    denom += w;
  }
  selfw[id] = sw;
  inv[id] = 1.f / denom;
}

__global__ __launch_bounds__(256) void alpha2_kernel(const float* __restrict__ als,
                                                     const float* __restrict__ ald,
                                                     const int* __restrict__ off,
                                                     const int* __restrict__ esrc,
                                                     float* __restrict__ aw,
                                                     float* __restrict__ selfw,
                                                     float* __restrict__ inv) {
  int i = blockIdx.x * 256 + threadIdx.x;
  if (i >= NN) return;
  float adi = ald[i];
  float selfSc = als[i] + adi;
  selfSc = selfSc > 0.f ? selfSc : 0.2f * selfSc;
  int s0 = off[i], s1 = off[i + 1];
  float m = selfSc;
  for (int e = s0; e < s1; e++) {
    float sc = als[esrc[e]] + adi;
    sc = sc > 0.f ? sc : 0.2f * sc;
    m = fmaxf(m, sc);
  }
  float sw = __expf(selfSc - m);
  float denom = sw;
  for (int e = s0; e < s1; e++) {
    float sc = als[esrc[e]] + adi;
    sc = sc > 0.f ? sc : 0.2f * sc;
    float w = __expf(sc - m);
    aw[e] = w;
    denom += w;
  }
  selfw[i] = sw;
  inv[i] = 1.f / denom;
}

// ---------------- weighted gather, conv1: thread per (node, uint2) ----------------
__global__ __launch_bounds__(256) void agg1w_kernel(const uint2* __restrict__ xp,
                                                    const float* __restrict__ aw,
                                                    const float* __restrict__ selfw,
                                                    const float* __restrict__ inv,
                                                    const int* __restrict__ off,
                                                    const int* __restrict__ esrc,
                                                    const float* __restrict__ b1,
                                                    uint2* __restrict__ x1) {
  long gid = (long)blockIdx.x * 256 + threadIdx.x;
  if (gid >= (long)NN * 128) return;
  int i = (int)(gid >> 7), c4 = (int)(gid & 127), h = c4 >> 5;
  float sw = selfw[i * 4 + h];
  float iv = inv[i * 4 + h];
  uint2 xv = xp[(size_t)i * 128 + c4];
  float2 xa = unpk(xv.x), xb = unpk(xv.y);
  float4 acc = make_float4(sw * xa.x, sw * xa.y, sw * xb.x, sw * xb.y);
  int s0 = off[i], s1 = off[i + 1];
  int e = s0;
  for (; e + 1 < s1; e += 2) {
    int sA = esrc[e], sB = esrc[e + 1];
    float wA = aw[e * 4 + h], wB = aw[(e + 1) * 4 + h];
    uint2 mA = xp[(size_t)sA * 128 + c4];
    uint2 mB = xp[(size_t)sB * 128 + c4];
    float2 a0 = unpk(mA.x), a1 = unpk(mA.y);
    float2 b0 = unpk(mB.x), b1v = unpk(mB.y);
    acc.x = fmaf(wA, a0.x, acc.x); acc.y = fmaf(wA, a0.y, acc.y);
    acc.z = fmaf(wA, a1.x, acc.z); acc.w = fmaf(wA, a1.y, acc.w);
    acc.x = fmaf(wB, b0.x, acc.x); acc.y = fmaf(wB, b0.y, acc.y);
    acc.z = fmaf(wB, b1v.x, acc.z); acc.w = fmaf(wB, b1v.y, acc.w);
  }
  if (e < s1) {
    int sA = esrc[e];
    float wA = aw[e * 4 + h];
    uint2 mA = xp[(size_t)sA * 128 + c4];
    float2 a0 = unpk(mA.x), a1 = unpk(mA.y);
    acc.x = fmaf(wA, a0.x, acc.x); acc.y = fmaf(wA, a0.y, acc.y);
    acc.z = fmaf(wA, a1.x, acc.z); acc.w = fmaf(wA, a1.y, acc.w);
  }
  float4 bb = ((const float4*)b1)[c4];
  float v0 = acc.x * iv + bb.x;
  float v1 = acc.y * iv + bb.y;
  float v2 = acc.z * iv + bb.z;
  float v3 = acc.w * iv + bb.w;
  v0 = v0 > 0.f ? v0 : (__expf(v0) - 1.f);
  v1 = v1 > 0.f ? v1 : (__expf(v1) - 1.f);
  v2 = v2 > 0.f ? v2 : (__expf(v2) - 1.f);
  v3 = v3 > 0.f ? v3 : (__expf(v3) - 1.f);
  uint2 o;
  o.x = pk(v0, v1);
  o.y = pk(v2, v3);
  x1[gid] = o;
}

// ---------------- weighted gather, conv2: thread per (node, uint2) ----------------
__global__ __launch_bounds__(256) void agg2w_kernel(const uint2* __restrict__ xp,
                                                    const float* __restrict__ aw,
                                                    const float* __restrict__ selfw,
                                                    const float* __restrict__ inv,
                                                    const int* __restrict__ off,
                                                    const int* __restrict__ esrc,
                                                    const float* __restrict__ b2,
                                                    float4* __restrict__ x2) {
  long gid = (long)blockIdx.x * 256 + threadIdx.x;
  if (gid >= (long)NN * 32) return;
  int i = (int)(gid >> 5), c4 = (int)(gid & 31);
  float sw = selfw[i];
  float iv = inv[i];
  uint2 xv = xp[(size_t)i * 32 + c4];
  float2 xa = unpk(xv.x), xb = unpk(xv.y);
  float4 acc = make_float4(sw * xa.x, sw * xa.y, sw * xb.x, sw * xb.y);
  int s0 = off[i], s1 = off[i + 1];
  int e = s0;
  for (; e + 1 < s1; e += 2) {
    int sA = esrc[e], sB = esrc[e + 1];
    float wA = aw[e], wB = aw[e + 1];
    uint2 mA = xp[(size_t)sA * 32 + c4];
    uint2 mB = xp[(size_t)sB * 32 + c4];
    float2 a0 = unpk(mA.x), a1 = unpk(mA.y);
    float2 b0 = unpk(mB.x), b1v = unpk(mB.y);
    acc.x = fmaf(wA, a0.x, acc.x); acc.y = fmaf(wA, a0.y, acc.y);
    acc.z = fmaf(wA, a1.x, acc.z); acc.w = fmaf(wA, a1.y, acc.w);
    acc.x = fmaf(wB, b0.x, acc.x); acc.y = fmaf(wB, b0.y, acc.y);
    acc.z = fmaf(wB, b1v.x, acc.z); acc.w = fmaf(wB, b1v.y, acc.w);
  }
  if (e < s1) {
    int sA = esrc[e];
    float wA = aw[e];
    uint2 mA = xp[(size_t)sA * 32 + c4];
    float2 a0 = unpk(mA.x), a1 = unpk(mA.y);
    acc.x = fmaf(wA, a0.x, acc.x); acc.y = fmaf(wA, a0.y, acc.y);
    acc.z = fmaf(wA, a1.x, acc.z); acc.w = fmaf(wA, a1.y, acc.w);
  }
  float4 bb = ((const float4*)b2)[c4];
  float v0 = acc.x * iv + bb.x;
  float v1 = acc.y * iv + bb.y;
  float v2 = acc.z * iv + bb.z;
  float v3 = acc.w * iv + bb.w;
  v0 = v0 > 0.f ? v0 : (__expf(v0) - 1.f);
  v1 = v1 > 0.f ? v1 : (__expf(v1) - 1.f);
  v2 = v2 > 0.f ? v2 : (__expf(v2) - 1.f);
  v3 = v3 > 0.f ? v3 : (__expf(v3) - 1.f);
  x2[gid] = make_float4(v0, v1, v2, v3);
}

// ---------------- masked mean pool ----------------
__global__ __launch_bounds__(128) void pool_kernel(const float* __restrict__ x2,
                                                   const int* __restrict__ m_idx,
                                                   float* __restrict__ pooled) {
  int g = blockIdx.x, c = threadIdx.x;
  float acc = 0.f, cnt = 0.f;
  const float* xr = x2 + (size_t)g * 64 * 128;
  const int* mi = m_idx + g * 64;
  for (int n = 0; n < 64; n++) {
    if (mi[n] >= 1) { cnt += 1.f; acc += xr[n * 128 + c]; }
  }
  pooled[(size_t)g * 128 + c] = acc / cnt;
}

// ---------------- final logit ----------------
__global__ __launch_bounds__(256) void head2_naive(const float* __restrict__ h1,
                                                   const float* __restrict__ Wo2,
                                                   const float* __restrict__ bo2,
                                                   float* __restrict__ out) {
  int g = blockIdx.x * 256 + threadIdx.x;
  if (g >= GG) return;
  float p = bo2[0];
  for (int c = 0; c < 128; c++) p = fmaf(h1[(size_t)g * 128 + c], Wo2[c], p);
  out[g] = p;
}

extern "C" void kernel_launch(void* const* d_in, const int* in_sizes, int n_in, void* d_out,
                              int out_size, void* d_ws, size_t ws_size, hipStream_t stream) {
  (void)n_in; (void)out_size; (void)ws_size;
  bool dict_order = (in_sizes[2] == NN);
  int IM, IE, IF[25];
  if (dict_order) {
    IM = 2; IE = 3;
    const int f[25] = {0, 1, 4, 5, 6, 7, 8, 9, 10, 11, 12, 13, 14, 15, 16, 17, 18,
                       19, 20, 21, 22, 23, 24, 25, 26};
    for (int k = 0; k < 25; k++) IF[k] = f[k];
  } else {
    IM = 25; IE = 26;
    for (int k = 0; k < 25; k++) IF[k] = k;
  }
  const int* m_idx = (const int*)d_in[IM];
  const int* eidx = (const int*)d_in[IE];
  float* out = (float*)d_out;
  const int* e_src = eidx;
  const int* e_dst = eidx + EE;

  // workspace layout (peak ~101 MB)
  char* w = (char*)d_ws;
  bf16* xp1b = (bf16*)(w);                           // [NN,512] bf16 [0,32) MB
  bf16* x0b = (bf16*)(w + ((size_t)32 << 20));       // [NN,128] bf16 [32,40) MB
  bf16* x1 = (bf16*)(w + ((size_t)48 << 20));        // [NN,512] bf16 [48,80) MB
  bf16* xp2b = (bf16*)(w);                           // [NN,128] bf16 [0,8)  (xp1b dead)
  float* x2 = (float*)(w + ((size_t)8 << 20));       // [NN,128] f32 [8,24)
  size_t so = (size_t)80 << 20;                      // smalls [80,~96) MB
  float* vt = (float*)(w + so); so += 512 * 256 * 4;
  float* start = (float*)(w + so); so += 512 * 128 * 4;
  float* emb2 = (float*)(w + so); so += 51 * 128 * 4 + 256;
  float* als1 = (float*)(w + so); so += NN * 4 * 4;
  float* ald1 = (float*)(w + so); so += NN * 4 * 4;
  float* als2 = (float*)(w + so); so += NN * 4;
  float* ald2 = (float*)(w + so); so += NN * 4;
  float* aw1 = (float*)(w + so); so += EE * 4 * 4;   // 4 MB
  float* selfw1 = (float*)(w + so); so += NN * 4 * 4;
  float* inv1 = (float*)(w + so); so += NN * 4 * 4;
  float* aw2 = (float*)(w + so); so += EE * 4;       // 1 MB
  float* selfw2 = (float*)(w + so); so += NN * 4;
  float* inv2 = (float*)(w + so); so += NN * 4;
  float* pooled = (float*)(w + so); so += 512 * 128 * 4;
  float* h1 = (float*)(w + so); so += 512 * 128 * 4;
  int* indeg = (int*)(w + so); so += NN * 4;
  int* csroff = (int*)(w + so); so += (NN + 1) * 4 + 252;
  int* cursor = (int*)(w + so); so += NN * 4;
  int* esrc = (int*)(w + so); so += EE * 4;
  int* bsum = (int*)(w + so); so += 256 * 4;
  int* bpre = (int*)(w + so); so += 256 * 4;
  int* dflag = (int*)(w + so); so += 256;
  s8v* Bp1 = (s8v*)(w + so); so += 32 * 4 * 64 * 16;   // 128 KB (conv1 W1 frags)
  s8v* Bp2 = (s8v*)(w + so); so += 8 * 16 * 64 * 16;   // 128 KB (conv2 W2 frags)
  float* stage = (float*)(w + ((size_t)96 << 20));     // [96,~100.6) MB

  probe_kernel<<<1, 256, 0, stream>>>(d_in[0], dflag);
  cvt_kernel<<<(O_TOTAL + 255) / 256, 256, 0, stream>>>(
      d_in[IF[0]], d_in[IF[1]], d_in[IF[2]], d_in[IF[3]], d_in[IF[4]], d_in[IF[5]],
      d_in[IF[6]], d_in[IF[7]], d_in[IF[8]], d_in[IF[9]], d_in[IF[10]], d_in[IF[11]],
      d_in[IF[12]], d_in[IF[13]], d_in[IF[14]], d_in[IF[15]], d_in[IF[16]], d_in[IF[17]],
      d_in[IF[18]], d_in[IF[19]], d_in[IF[20]], d_in[IF[21]], d_in[IF[22]], d_in[IF[23]],
      d_in[IF[24]], dflag, stage);

  const float* t = stage + O_T;
  const float* v = stage + O_V;
  const float* Wt = stage + O_WT;       const float* bt = stage + O_BT;
  const float* Wv = stage + O_WV;       const float* bv = stage + O_BV;
  const float* emb = stage + O_EMB;
  const float* Wnode = stage + O_WNODE; const float* bnode = stage + O_BNODE;
  const float* Wstart = stage + O_WSTART; const float* bstart = stage + O_BSTART;
  const float* ln_g = stage + O_LNG;    const float* ln_b = stage + O_LNB;
  const float* W1 = stage + O_W1;
  const float* a_src1 = stage + O_ASRC1; const float* a_dst1 = stage + O_ADST1;
  const float* b1 = stage + O_B1;
  const float* W2 = stage + O_W2;
  const float* a_src2 = stage + O_ASRC2; const float* a_dst2 = stage + O_ADST2;
  const float* b2 = stage + O_B2;
  const float* Wo1 = stage + O_WO1;     const float* bo1 = stage + O_BO1;
  const float* Wo2 = stage + O_WO2;     const float* bo2 = stage + O_BO2;

  hipMemsetAsync(indeg, 0, NN * 4, stream);
  hist_kernel<<<EE / 256, 256, 0, stream>>>(e_dst, indeg);
  scanA_kernel<<<1, 256, 0, stream>>>(indeg, bsum);
  scanB_kernel<<<1, 1, 0, stream>>>(bsum, bpre);
  scanC_kernel<<<1, 256, 0, stream>>>(indeg, bpre, csroff, cursor);
  fill_kernel<<<EE / 256, 256, 0, stream>>>(e_src, e_dst, cursor, esrc);

  // pack conv weights into MFMA fragment order
  packB_kernel<<<32, 256, 0, stream>>>(W1, 512, 128, Bp1);
  packB_kernel<<<32, 256, 0, stream>>>(W2, 128, 512, Bp2);

  ngemm_kernel<float><<<(51 * 128 + 255) / 256, 256, 0, stream>>>(emb, Wnode, bnode, emb2, 51, 128, 128, 128, 0);
  gemm_kernel<float, float><<<dim3(2, 8), 256, 0, stream>>>(v, Wv, bv, vt, 512, 128, 768, 256, 0);
  gemm_kernel<float, float><<<dim3(2, 8), 256, 0, stream>>>(t, Wt, bt, vt + 128, 512, 128, 768, 256, 0);
  gemm_kernel<float, float><<<dim3(2, 8), 256, 0, stream>>>(vt, Wstart, bstart, start, 512, 128, 256, 128, 0);
  ln_wave<<<NN / 4, 256, 0, stream>>>(start, emb2, m_idx, ln_g, ln_b, (unsigned*)x0b);

  // conv1: MFMA GEMM (bf16 in/out)
  gemm_mfma<<<dim3(8, NN / 64), 256, 0, stream>>>((const short*)x0b, Bp1, (short*)xp1b, NN, 512, 128);
  al1_wave<<<NN, 256, 0, stream>>>((const unsigned*)xp1b, a_src1, a_dst1, als1, ald1);
  alpha1_kernel<<<NN * 4 / 256, 256, 0, stream>>>(als1, ald1, csroff, esrc, aw1, selfw1, inv1);
  agg1w_kernel<<<(int)(((long)NN * 128 + 255) / 256), 256, 0, stream>>>(
      (const uint2*)xp1b, aw1, selfw1, inv1, csroff, esrc, b1, (uint2*)x1);

  // conv2: MFMA GEMM (bf16 in/out)
  gemm_mfma<<<dim3(2, NN / 64), 256, 0, stream>>>((const short*)x1, Bp2, (short*)xp2b, NN, 128, 512);
  al2_wave<<<NN / 4, 256, 0, stream>>>((const unsigned*)xp2b, a_src2, a_dst2, als2, ald2);
  alpha2_kernel<<<NN / 256, 256, 0, stream>>>(als2, ald2, csroff, esrc, aw2, selfw2, inv2);
  agg2w_kernel<<<(int)(((long)NN * 32 + 255) / 256), 256, 0, stream>>>(
      (const uint2*)xp2b, aw2, selfw2, inv2, csroff, esrc, b2, (float4*)x2);

  pool_kernel<<<GG, 128, 0, stream>>>(x2, m_idx, pooled);
  gemm_kernel<float, float><<<dim3(2, 8), 256, 0, stream>>>(pooled, Wo1, bo1, h1, 512, 128, 128, 128, 1);
  head2_naive<<<(GG + 255) / 256, 256, 0, stream>>>(h1, Wo2, bo2, out);
}

// Round 12
// 524.290 us; speedup vs baseline: 4.7307x; 1.2585x over previous
//
#include <hip/hip_runtime.h>
#include <hip/hip_bf16.h>

typedef __hip_bfloat16 bf16;
typedef __attribute__((ext_vector_type(8))) short s8v;   // 8 bf16 (4 VGPRs)
typedef __attribute__((ext_vector_type(4))) float f4v;   // 4 fp32 acc

#define NN 32768   // total nodes
#define EE 262144  // edges
#define GG 512     // graphs

__device__ __forceinline__ float loadf(const float* p) { return *p; }
__device__ __forceinline__ float loadf(const bf16* p) { return __bfloat162float(*p); }
__device__ __forceinline__ void storef(float* p, float v) { *p = v; }
__device__ __forceinline__ void storef(bf16* p, float v) { *p = __float2bfloat16(v); }

__device__ __forceinline__ float2 unpk(unsigned u) {
  float2 r;
  r.x = __uint_as_float(u << 16);
  r.y = __uint_as_float(u & 0xffff0000u);
  return r;
}
__device__ __forceinline__ unsigned pk(float x, float y) {
  union { bf16 h[2]; unsigned u; } p;
  p.h[0] = __float2bfloat16(x);
  p.h[1] = __float2bfloat16(y);
  return p.u;
}
__device__ __forceinline__ short f2bf_bits(float x) {
  bf16 h = __float2bfloat16(x);
  return *reinterpret_cast<short*>(&h);
}

__device__ __forceinline__ float wred_sum(float v) {
#pragma unroll
  for (int o = 32; o; o >>= 1) v += __shfl_xor(v, o, 64);
  return v;
}

// ---------------- CSR build ----------------
__global__ __launch_bounds__(256) void hist_kernel(const int* __restrict__ dst,
                                                   int* __restrict__ indeg) {
  int e = blockIdx.x * 256 + threadIdx.x;
  if (e < EE) atomicAdd(&indeg[dst[e]], 1);
}

// single-block 1024-thread exclusive scan over NN=32768 (32/thread)
__global__ __launch_bounds__(1024) void scan_kernel(const int* __restrict__ indeg,
                                                    int* __restrict__ off,
                                                    int* __restrict__ cursor) {
  __shared__ int sh[1024];
  int t = threadIdx.x;
  int loc[32];
  int s = 0;
  int base = t * 32;
#pragma unroll
  for (int j = 0; j < 32; j++) { loc[j] = indeg[base + j]; s += loc[j]; }
  sh[t] = s;
  __syncthreads();
  for (int d = 1; d < 1024; d <<= 1) {
    int v = (t >= d) ? sh[t - d] : 0;
    __syncthreads();
    sh[t] += v;
    __syncthreads();
  }
  int run = (t == 0) ? 0 : sh[t - 1];
#pragma unroll
  for (int j = 0; j < 32; j++) { off[base + j] = run; cursor[base + j] = run; run += loc[j]; }
  if (t == 1023) off[NN] = run;
}

__global__ __launch_bounds__(256) void fill_kernel(const int* __restrict__ src,
                                                   const int* __restrict__ dst,
                                                   int* __restrict__ cursor,
                                                   int* __restrict__ esrc) {
  int e = blockIdx.x * 256 + threadIdx.x;
  if (e < EE) {
    int p = atomicAdd(&cursor[dst[e]], 1);
    esrc[p] = src[e];
  }
}

// ---------------- naive GEMM (small problems only) ----------------
template <typename TA>
__global__ __launch_bounds__(256) void ngemm_kernel(const TA* __restrict__ A,
                                                    const float* __restrict__ B,
                                                    const float* __restrict__ bias,
                                                    float* __restrict__ C,
                                                    int M, int N, int K, int ldc, int act) {
  long gid = (long)blockIdx.x * 256 + threadIdx.x;
  if (gid >= (long)M * N) return;
  int m = (int)(gid / N), n = (int)(gid % N);
  float acc = bias ? bias[n] : 0.f;
  for (int k = 0; k < K; k++)
    acc = fmaf(loadf(&A[(size_t)m * K + k]), B[(size_t)k * N + n], acc);
  if (act == 1) acc = acc > 0.f ? acc : 0.01f * acc;
  C[(size_t)m * ldc + n] = acc;
}

// ---------------- tiled LDS GEMM, 64x64 tile, 4x4/thread (small fp32 gemms) ----------------
template <typename TA, typename TC>
__global__ __launch_bounds__(256) void gemm_kernel(const TA* __restrict__ A,
                                                   const float* __restrict__ B,
                                                   const float* __restrict__ bias,
                                                   TC* __restrict__ C, int M, int N, int K,
                                                   int ldc, int act) {
  __shared__ float As[16][65];
  __shared__ float Bs[16][65];
  int tid = threadIdx.x;
  int brow = blockIdx.y * 64;
  int bcol = blockIdx.x * 64;
  int tr = (tid >> 4) << 2;
  int tc = (tid & 15) << 2;
  float acc[4][4] = {};
  for (int k0 = 0; k0 < K; k0 += 16) {
#pragma unroll
    for (int l = 0; l < 4; l++) {
      int idx = tid + l * 256;
      int r = idx >> 4, kk = idx & 15;
      As[kk][r] = loadf(&A[(size_t)(brow + r) * K + (k0 + kk)]);
    }
#pragma unroll
    for (int l = 0; l < 4; l++) {
      int idx = tid + l * 256;
      int kk = idx >> 6, c = idx & 63;
      Bs[kk][c] = B[(size_t)(k0 + kk) * N + (bcol + c)];
    }
    __syncthreads();
#pragma unroll
    for (int kk = 0; kk < 16; kk++) {
      float a[4], b[4];
#pragma unroll
      for (int i = 0; i < 4; i++) a[i] = As[kk][tr + i];
#pragma unroll
      for (int j = 0; j < 4; j++) b[j] = Bs[kk][tc + j];
#pragma unroll
      for (int i = 0; i < 4; i++)
#pragma unroll
        for (int j = 0; j < 4; j++) acc[i][j] = fmaf(a[i], b[j], acc[i][j]);
    }
    __syncthreads();
  }
#pragma unroll
  for (int i = 0; i < 4; i++) {
#pragma unroll
    for (int j = 0; j < 4; j++) {
      float v = acc[i][j];
      if (bias) v += bias[bcol + tc + j];
      if (act == 1) v = v > 0.f ? v : 0.01f * v;
      storef(&C[(size_t)(brow + tr + i) * ldc + (bcol + tc + j)], v);
    }
  }
}

// ---------------- pack W (f32, KxN row-major) into MFMA B-fragment order ----------------
__global__ __launch_bounds__(256) void packB_kernel(const float* __restrict__ W, int N, int K,
                                                    s8v* __restrict__ Bp) {
  int id = blockIdx.x * 256 + threadIdx.x;
  int total = (N >> 4) * (K >> 5) * 64;
  if (id >= total) return;
  int lane = id & 63;
  int tmp = id >> 6;
  int ksteps = K >> 5;
  int ks = tmp % ksteps;
  int nt = tmp / ksteps;
  int n = nt * 16 + (lane & 15);
  int kbase = ks * 32 + (lane >> 4) * 8;
  s8v r;
#pragma unroll
  for (int j = 0; j < 8; j++) r[j] = f2bf_bits(W[(size_t)(kbase + j) * N + n]);
  Bp[id] = r;
}

// ---------------- MFMA bf16 GEMM ----------------
__global__ __launch_bounds__(256) void gemm_mfma(const short* __restrict__ A,
                                                 const s8v* __restrict__ Bp,
                                                 short* __restrict__ C,
                                                 int M, int N, int K) {
  __shared__ short lds[64 * 64];
  int tid = threadIdx.x;
  int wv = tid >> 6, lane = tid & 63;
  int quad = lane >> 4, l16 = lane & 15;
  int brow = blockIdx.y * 64, bcol = blockIdx.x * 64;
  int m = brow + wv * 16 + l16;
  int ksteps = K >> 5;
  f4v acc[4] = {};
  const s8v* Arow = (const s8v*)(A + (size_t)m * K);
  for (int ks = 0; ks < ksteps; ks++) {
    s8v a = Arow[ks * 4 + quad];
#pragma unroll
    for (int nt = 0; nt < 4; nt++) {
      s8v b = Bp[(size_t)(((bcol >> 4) + nt) * ksteps + ks) * 64 + lane];
      acc[nt] = __builtin_amdgcn_mfma_f32_16x16x32_bf16(a, b, acc[nt], 0, 0, 0);
    }
  }
#pragma unroll
  for (int nt = 0; nt < 4; nt++)
#pragma unroll
    for (int r = 0; r < 4; r++)
      lds[(wv * 16 + quad * 4 + r) * 64 + nt * 16 + l16] = f2bf_bits(acc[nt][r]);
  __syncthreads();
#pragma unroll
  for (int rep = 0; rep < 2; rep++) {
    int idx = rep * 256 + tid;
    int row = idx >> 3, c16 = idx & 7;
    uint4 val = ((const uint4*)lds)[idx];
    *(uint4*)(C + (size_t)(brow + row) * N + bcol + c16 * 8) = val;
  }
}

// ---------------- layernorm, wave per node -> packed bf16 out ----------------
__global__ __launch_bounds__(256) void ln_wave(const float* __restrict__ start,
                                               const float* __restrict__ emb2,
                                               const int* __restrict__ m_idx,
                                               const float* __restrict__ lng,
                                               const float* __restrict__ lnb,
                                               unsigned* __restrict__ x0b) {
  int i = blockIdx.x * 4 + (threadIdx.x >> 6);
  int lane = threadIdx.x & 63;
  int g = i >> 6, n = i & 63;
  const float* row = (n == 0) ? (start + (size_t)g * 128) : (emb2 + (size_t)m_idx[i] * 128);
  float2 v = ((const float2*)row)[lane];
  float mu = wred_sum(v.x + v.y) * (1.f / 128.f);
  float dx = v.x - mu, dy = v.y - mu;
  float var = wred_sum(dx * dx + dy * dy) * (1.f / 128.f);
  float rstd = rsqrtf(var + 1e-6f);
  float2 gg = ((const float2*)lng)[lane];
  float2 bb = ((const float2*)lnb)[lane];
  x0b[(size_t)i * 64 + lane] = pk(dx * rstd * gg.x + bb.x, dy * rstd * gg.y + bb.y);
}

// ---------------- attention coefficients, wave per (node,head), xp bf16 ----------------
__global__ __launch_bounds__(256) void al1_wave(const unsigned* __restrict__ xp,
                                                const float* __restrict__ a_src,
                                                const float* __restrict__ a_dst,
                                                float* __restrict__ als,
                                                float* __restrict__ ald) {
  int id = blockIdx.x * 4 + (threadIdx.x >> 6);
  int lane = threadIdx.x & 63;
  int i = id >> 2, h = id & 3;
  float2 x = unpk(xp[(size_t)i * 256 + h * 64 + lane]);
  float2 as = ((const float2*)(a_src + h * 128))[lane];
  float2 ad = ((const float2*)(a_dst + h * 128))[lane];
  float ps = wred_sum(x.x * as.x + x.y * as.y);
  float pd = wred_sum(x.x * ad.x + x.y * ad.y);
  if (lane == 0) { als[id] = ps; ald[id] = pd; }
}

__global__ __launch_bounds__(256) void al2_wave(const unsigned* __restrict__ xp,
                                                const float* __restrict__ a_src,
                                                const float* __restrict__ a_dst,
                                                float* __restrict__ als,
                                                float* __restrict__ ald) {
  int i = blockIdx.x * 4 + (threadIdx.x >> 6);
  int lane = threadIdx.x & 63;
  float2 x = unpk(xp[(size_t)i * 64 + lane]);
  float2 as = ((const float2*)a_src)[lane];
  float2 ad = ((const float2*)a_dst)[lane];
  float ps = wred_sum(x.x * as.x + x.y * as.y);
  float pd = wred_sum(x.x * ad.x + x.y * ad.y);
  if (lane == 0) { als[i] = ps; ald[i] = pd; }
}

// ---------------- softmax weights ----------------
__global__ __launch_bounds__(256) void alpha1_kernel(const float* __restrict__ als,
                                                     const float* __restrict__ ald,
                                                     const int* __restrict__ off,
                                                     const int* __restrict__ esrc,
                                                     float* __restrict__ aw,
                                                     float* __restrict__ selfw,
                                                     float* __restrict__ inv) {
  int id = blockIdx.x * 256 + threadIdx.x;
  if (id >= NN * 4) return;
  int i = id >> 2, h = id & 3;
  float adi = ald[id];
  float selfSc = als[id] + adi;
  selfSc = selfSc > 0.f ? selfSc : 0.2f * selfSc;
  int s0 = off[i], s1 = off[i + 1];
  float m = selfSc;
  for (int e = s0; e < s1; e++) {
    float sc = als[esrc[e] * 4 + h] + adi;
    sc = sc > 0.f ? sc : 0.2f * sc;
    m = fmaxf(m, sc);
  }
  float sw = __expf(selfSc - m);
  float denom = sw;
  for (int e = s0; e < s1; e++) {
    float sc = als[esrc[e] * 4 + h] + adi;
    sc = sc > 0.f ? sc : 0.2f * sc;
    float w = __expf(sc - m);
    aw[e * 4 + h] = w;
    denom += w;
  }
  selfw[id] = sw;
  inv[id] = 1.f / denom;
}

__global__ __launch_bounds__(256) void alpha2_kernel(const float* __restrict__ als,
                                                     const float* __restrict__ ald,
                                                     const int* __restrict__ off,
                                                     const int* __restrict__ esrc,
                                                     float* __restrict__ aw,
                                                     float* __restrict__ selfw,
                                                     float* __restrict__ inv) {
  int i = blockIdx.x * 256 + threadIdx.x;
  if (i >= NN) return;
  float adi = ald[i];
  float selfSc = als[i] + adi;
  selfSc = selfSc > 0.f ? selfSc : 0.2f * selfSc;
  int s0 = off[i], s1 = off[i + 1];
  float m = selfSc;
  for (int e = s0; e < s1; e++) {
    float sc = als[esrc[e]] + adi;
    sc = sc > 0.f ? sc : 0.2f * sc;
    m = fmaxf(m, sc);
  }
  float sw = __expf(selfSc - m);
  float denom = sw;
  for (int e = s0; e < s1; e++) {
    float sc = als[esrc[e]] + adi;
    sc = sc > 0.f ? sc : 0.2f * sc;
    float w = __expf(sc - m);
    aw[e] = w;
    denom += w;
  }
  selfw[i] = sw;
  inv[i] = 1.f / denom;
}

// ---------------- weighted gather, conv1: thread per (node, uint2) ----------------
__global__ __launch_bounds__(256) void agg1w_kernel(const uint2* __restrict__ xp,
                                                    const float* __restrict__ aw,
                                                    const float* __restrict__ selfw,
                                                    const float* __restrict__ inv,
                                                    const int* __restrict__ off,
                                                    const int* __restrict__ esrc,
                                                    const float* __restrict__ b1,
                                                    uint2* __restrict__ x1) {
  long gid = (long)blockIdx.x * 256 + threadIdx.x;
  if (gid >= (long)NN * 128) return;
  int i = (int)(gid >> 7), c4 = (int)(gid & 127), h = c4 >> 5;
  float sw = selfw[i * 4 + h];
  float iv = inv[i * 4 + h];
  uint2 xv = xp[(size_t)i * 128 + c4];
  float2 xa = unpk(xv.x), xb = unpk(xv.y);
  float4 acc = make_float4(sw * xa.x, sw * xa.y, sw * xb.x, sw * xb.y);
  int s0 = off[i], s1 = off[i + 1];
  int e = s0;
  for (; e + 1 < s1; e += 2) {
    int sA = esrc[e], sB = esrc[e + 1];
    float wA = aw[e * 4 + h], wB = aw[(e + 1) * 4 + h];
    uint2 mA = xp[(size_t)sA * 128 + c4];
    uint2 mB = xp[(size_t)sB * 128 + c4];
    float2 a0 = unpk(mA.x), a1 = unpk(mA.y);
    float2 b0 = unpk(mB.x), b1v = unpk(mB.y);
    acc.x = fmaf(wA, a0.x, acc.x); acc.y = fmaf(wA, a0.y, acc.y);
    acc.z = fmaf(wA, a1.x, acc.z); acc.w = fmaf(wA, a1.y, acc.w);
    acc.x = fmaf(wB, b0.x, acc.x); acc.y = fmaf(wB, b0.y, acc.y);
    acc.z = fmaf(wB, b1v.x, acc.z); acc.w = fmaf(wB, b1v.y, acc.w);
  }
  if (e < s1) {
    int sA = esrc[e];
    float wA = aw[e * 4 + h];
    uint2 mA = xp[(size_t)sA * 128 + c4];
    float2 a0 = unpk(mA.x), a1 = unpk(mA.y);
    acc.x = fmaf(wA, a0.x, acc.x); acc.y = fmaf(wA, a0.y, acc.y);
    acc.z = fmaf(wA, a1.x, acc.z); acc.w = fmaf(wA, a1.y, acc.w);
  }
  float4 bb = ((const float4*)b1)[c4];
  float v0 = acc.x * iv + bb.x;
  float v1 = acc.y * iv + bb.y;
  float v2 = acc.z * iv + bb.z;
  float v3 = acc.w * iv + bb.w;
  v0 = v0 > 0.f ? v0 : (__expf(v0) - 1.f);
  v1 = v1 > 0.f ? v1 : (__expf(v1) - 1.f);
  v2 = v2 > 0.f ? v2 : (__expf(v2) - 1.f);
  v3 = v3 > 0.f ? v3 : (__expf(v3) - 1.f);
  uint2 o;
  o.x = pk(v0, v1);
  o.y = pk(v2, v3);
  x1[gid] = o;
}

// ---------------- weighted gather, conv2: thread per (node, uint2) ----------------
__global__ __launch_bounds__(256) void agg2w_kernel(const uint2* __restrict__ xp,
                                                    const float* __restrict__ aw,
                                                    const float* __restrict__ selfw,
                                                    const float* __restrict__ inv,
                                                    const int* __restrict__ off,
                                                    const int* __restrict__ esrc,
                                                    const float* __restrict__ b2,
                                                    float4* __restrict__ x2) {
  long gid = (long)blockIdx.x * 256 + threadIdx.x;
  if (gid >= (long)NN * 32) return;
  int i = (int)(gid >> 5), c4 = (int)(gid & 31);
  float sw = selfw[i];
  float iv = inv[i];
  uint2 xv = xp[(size_t)i * 32 + c4];
  float2 xa = unpk(xv.x), xb = unpk(xv.y);
  float4 acc = make_float4(sw * xa.x, sw * xa.y, sw * xb.x, sw * xb.y);
  int s0 = off[i], s1 = off[i + 1];
  int e = s0;
  for (; e + 1 < s1; e += 2) {
    int sA = esrc[e], sB = esrc[e + 1];
    float wA = aw[e], wB = aw[e + 1];
    uint2 mA = xp[(size_t)sA * 32 + c4];
    uint2 mB = xp[(size_t)sB * 32 + c4];
    float2 a0 = unpk(mA.x), a1 = unpk(mA.y);
    float2 b0 = unpk(mB.x), b1v = unpk(mB.y);
    acc.x = fmaf(wA, a0.x, acc.x); acc.y = fmaf(wA, a0.y, acc.y);
    acc.z = fmaf(wA, a1.x, acc.z); acc.w = fmaf(wA, a1.y, acc.w);
    acc.x = fmaf(wB, b0.x, acc.x); acc.y = fmaf(wB, b0.y, acc.y);
    acc.z = fmaf(wB, b1v.x, acc.z); acc.w = fmaf(wB, b1v.y, acc.w);
  }
  if (e < s1) {
    int sA = esrc[e];
    float wA = aw[e];
    uint2 mA = xp[(size_t)sA * 32 + c4];
    float2 a0 = unpk(mA.x), a1 = unpk(mA.y);
    acc.x = fmaf(wA, a0.x, acc.x); acc.y = fmaf(wA, a0.y, acc.y);
    acc.z = fmaf(wA, a1.x, acc.z); acc.w = fmaf(wA, a1.y, acc.w);
  }
  float4 bb = ((const float4*)b2)[c4];
  float v0 = acc.x * iv + bb.x;
  float v1 = acc.y * iv + bb.y;
  float v2 = acc.z * iv + bb.z;
  float v3 = acc.w * iv + bb.w;
  v0 = v0 > 0.f ? v0 : (__expf(v0) - 1.f);
  v1 = v1 > 0.f ? v1 : (__expf(v1) - 1.f);
  v2 = v2 > 0.f ? v2 : (__expf(v2) - 1.f);
  v3 = v3 > 0.f ? v3 : (__expf(v3) - 1.f);
  x2[gid] = make_float4(v0, v1, v2, v3);
}

// ---------------- masked mean pool ----------------
__global__ __launch_bounds__(128) void pool_kernel(const float* __restrict__ x2,
                                                   const int* __restrict__ m_idx,
                                                   float* __restrict__ pooled) {
  int g = blockIdx.x, c = threadIdx.x;
  float acc = 0.f, cnt = 0.f;
  const float* xr = x2 + (size_t)g * 64 * 128;
  const int* mi = m_idx + g * 64;
  for (int n = 0; n < 64; n++) {
    if (mi[n] >= 1) { cnt += 1.f; acc += xr[n * 128 + c]; }
  }
  pooled[(size_t)g * 128 + c] = acc / cnt;
}

// ---------------- final logit ----------------
__global__ __launch_bounds__(256) void head2_naive(const float* __restrict__ h1,
                                                   const float* __restrict__ Wo2,
                                                   const float* __restrict__ bo2,
                                                   float* __restrict__ out) {
  int g = blockIdx.x * 256 + threadIdx.x;
  if (g >= GG) return;
  float p = bo2[0];
  for (int c = 0; c < 128; c++) p = fmaf(h1[(size_t)g * 128 + c], Wo2[c], p);
  out[g] = p;
}

extern "C" void kernel_launch(void* const* d_in, const int* in_sizes, int n_in, void* d_out,
                              int out_size, void* d_ws, size_t ws_size, hipStream_t stream) {
  (void)n_in; (void)out_size; (void)ws_size;
  // input-order detection (dict vs signature) via in_sizes; inputs are fp32 (proved r5/r7)
  bool dict_order = (in_sizes[2] == NN);
  int IM, IE, IF[25];
  if (dict_order) {
    IM = 2; IE = 3;
    const int f[25] = {0, 1, 4, 5, 6, 7, 8, 9, 10, 11, 12, 13, 14, 15, 16, 17, 18,
                       19, 20, 21, 22, 23, 24, 25, 26};
    for (int k = 0; k < 25; k++) IF[k] = f[k];
  } else {
    IM = 25; IE = 26;
    for (int k = 0; k < 25; k++) IF[k] = k;
  }
  const int* m_idx = (const int*)d_in[IM];
  const int* eidx = (const int*)d_in[IE];
  float* out = (float*)d_out;
  const int* e_src = eidx;
  const int* e_dst = eidx + EE;

  const float* t = (const float*)d_in[IF[0]];
  const float* v = (const float*)d_in[IF[1]];
  const float* Wt = (const float*)d_in[IF[2]];     const float* bt = (const float*)d_in[IF[3]];
  const float* Wv = (const float*)d_in[IF[4]];     const float* bv = (const float*)d_in[IF[5]];
  const float* emb = (const float*)d_in[IF[6]];
  const float* Wnode = (const float*)d_in[IF[7]];  const float* bnode = (const float*)d_in[IF[8]];
  const float* Wstart = (const float*)d_in[IF[9]]; const float* bstart = (const float*)d_in[IF[10]];
  const float* ln_g = (const float*)d_in[IF[11]];  const float* ln_b = (const float*)d_in[IF[12]];
  const float* W1 = (const float*)d_in[IF[13]];
  const float* a_src1 = (const float*)d_in[IF[14]]; const float* a_dst1 = (const float*)d_in[IF[15]];
  const float* b1 = (const float*)d_in[IF[16]];
  const float* W2 = (const float*)d_in[IF[17]];
  const float* a_src2 = (const float*)d_in[IF[18]]; const float* a_dst2 = (const float*)d_in[IF[19]];
  const float* b2 = (const float*)d_in[IF[20]];
  const float* Wo1 = (const float*)d_in[IF[21]];   const float* bo1 = (const float*)d_in[IF[22]];
  const float* Wo2 = (const float*)d_in[IF[23]];   const float* bo2 = (const float*)d_in[IF[24]];

  // workspace layout (peak ~96 MB)
  char* w = (char*)d_ws;
  bf16* xp1b = (bf16*)(w);                           // [NN,512] bf16 [0,32) MB
  bf16* x0b = (bf16*)(w + ((size_t)32 << 20));       // [NN,128] bf16 [32,40) MB
  bf16* x1 = (bf16*)(w + ((size_t)48 << 20));        // [NN,512] bf16 [48,80) MB
  bf16* xp2b = (bf16*)(w);                           // [NN,128] bf16 [0,8)  (xp1b dead)
  float* x2 = (float*)(w + ((size_t)8 << 20));       // [NN,128] f32 [8,24)
  size_t so = (size_t)80 << 20;                      // smalls [80,~96) MB
  float* vt = (float*)(w + so); so += 512 * 256 * 4;
  float* start = (float*)(w + so); so += 512 * 128 * 4;
  float* emb2 = (float*)(w + so); so += 51 * 128 * 4 + 256;
  float* als1 = (float*)(w + so); so += NN * 4 * 4;
  float* ald1 = (float*)(w + so); so += NN * 4 * 4;
  float* als2 = (float*)(w + so); so += NN * 4;
  float* ald2 = (float*)(w + so); so += NN * 4;
  float* aw1 = (float*)(w + so); so += EE * 4 * 4;   // 4 MB
  float* selfw1 = (float*)(w + so); so += NN * 4 * 4;
  float* inv1 = (float*)(w + so); so += NN * 4 * 4;
  float* aw2 = (float*)(w + so); so += EE * 4;       // 1 MB
  float* selfw2 = (float*)(w + so); so += NN * 4;
  float* inv2 = (float*)(w + so); so += NN * 4;
  float* pooled = (float*)(w + so); so += 512 * 128 * 4;
  float* h1 = (float*)(w + so); so += 512 * 128 * 4;
  int* indeg = (int*)(w + so); so += NN * 4;
  int* csroff = (int*)(w + so); so += (NN + 1) * 4 + 252;
  int* cursor = (int*)(w + so); so += NN * 4;
  int* esrc = (int*)(w + so); so += EE * 4;
  s8v* Bp1 = (s8v*)(w + so); so += 32 * 4 * 64 * 16;   // 128 KB (conv1 W1 frags)
  s8v* Bp2 = (s8v*)(w + so); so += 8 * 16 * 64 * 16;   // 128 KB (conv2 W2 frags)

  // ---- CSR build ----
  hipMemsetAsync(indeg, 0, NN * 4, stream);
  hist_kernel<<<EE / 256, 256, 0, stream>>>(e_dst, indeg);
  scan_kernel<<<1, 1024, 0, stream>>>(indeg, csroff, cursor);
  fill_kernel<<<EE / 256, 256, 0, stream>>>(e_src, e_dst, cursor, esrc);

  // pack conv weights into MFMA fragment order
  packB_kernel<<<32, 256, 0, stream>>>(W1, 512, 128, Bp1);
  packB_kernel<<<32, 256, 0, stream>>>(W2, 128, 512, Bp2);

  ngemm_kernel<float><<<(51 * 128 + 255) / 256, 256, 0, stream>>>(emb, Wnode, bnode, emb2, 51, 128, 128, 128, 0);
  gemm_kernel<float, float><<<dim3(2, 8), 256, 0, stream>>>(v, Wv, bv, vt, 512, 128, 768, 256, 0);
  gemm_kernel<float, float><<<dim3(2, 8), 256, 0, stream>>>(t, Wt, bt, vt + 128, 512, 128, 768, 256, 0);
  gemm_kernel<float, float><<<dim3(2, 8), 256, 0, stream>>>(vt, Wstart, bstart, start, 512, 128, 256, 128, 0);
  ln_wave<<<NN / 4, 256, 0, stream>>>(start, emb2, m_idx, ln_g, ln_b, (unsigned*)x0b);

  // conv1: MFMA GEMM (bf16 in/out)
  gemm_mfma<<<dim3(8, NN / 64), 256, 0, stream>>>((const short*)x0b, Bp1, (short*)xp1b, NN, 512, 128);
  al1_wave<<<NN, 256, 0, stream>>>((const unsigned*)xp1b, a_src1, a_dst1, als1, ald1);
  alpha1_kernel<<<NN * 4 / 256, 256, 0, stream>>>(als1, ald1, csroff, esrc, aw1, selfw1, inv1);
  agg1w_kernel<<<(int)(((long)NN * 128 + 255) / 256), 256, 0, stream>>>(
      (const uint2*)xp1b, aw1, selfw1, inv1, csroff, esrc, b1, (uint2*)x1);

  // conv2: MFMA GEMM (bf16 in/out)
  gemm_mfma<<<dim3(2, NN / 64), 256, 0, stream>>>((const short*)x1, Bp2, (short*)xp2b, NN, 128, 512);
  al2_wave<<<NN / 4, 256, 0, stream>>>((const unsigned*)xp2b, a_src2, a_dst2, als2, ald2);
  alpha2_kernel<<<NN / 256, 256, 0, stream>>>(als2, ald2, csroff, esrc, aw2, selfw2, inv2);
  agg2w_kernel<<<(int)(((long)NN * 32 + 255) / 256), 256, 0, stream>>>(
      (const uint2*)xp2b, aw2, selfw2, inv2, csroff, esrc, b2, (float4*)x2);

  pool_kernel<<<GG, 128, 0, stream>>>(x2, m_idx, pooled);
  gemm_kernel<float, float><<<dim3(2, 8), 256, 0, stream>>>(pooled, Wo1, bo1, h1, 512, 128, 128, 128, 1);
  head2_naive<<<(GG + 255) / 256, 256, 0, stream>>>(h1, Wo2, bo2, out);
}

// Round 13
// 471.585 us; speedup vs baseline: 5.2594x; 1.1118x over previous
//
#include <hip/hip_runtime.h>
#include <hip/hip_bf16.h>

typedef __hip_bfloat16 bf16;
typedef __attribute__((ext_vector_type(8))) short s8v;   // 8 bf16 (4 VGPRs)
typedef __attribute__((ext_vector_type(4))) float f4v;   // 4 fp32 acc

#define NN 32768   // total nodes
#define EE 262144  // edges
#define GG 512     // graphs

__device__ __forceinline__ float2 unpk(unsigned u) {
  float2 r;
  r.x = __uint_as_float(u << 16);
  r.y = __uint_as_float(u & 0xffff0000u);
  return r;
}
__device__ __forceinline__ unsigned pk(float x, float y) {
  union { bf16 h[2]; unsigned u; } p;
  p.h[0] = __float2bfloat16(x);
  p.h[1] = __float2bfloat16(y);
  return p.u;
}
__device__ __forceinline__ short f2bf_bits(float x) {
  bf16 h = __float2bfloat16(x);
  return *reinterpret_cast<short*>(&h);
}

__device__ __forceinline__ float wred_sum(float v) {
#pragma unroll
  for (int o = 32; o; o >>= 1) v += __shfl_xor(v, o, 64);
  return v;
}

// ---------------- CSR build ----------------
__global__ __launch_bounds__(256) void hist_kernel(const int* __restrict__ dst,
                                                   int* __restrict__ indeg) {
  int e = blockIdx.x * 256 + threadIdx.x;
  if (e < EE) atomicAdd(&indeg[dst[e]], 1);
}

// single-block 1024-thread exclusive scan over NN=32768 (32/thread)
__global__ __launch_bounds__(1024) void scan_kernel(const int* __restrict__ indeg,
                                                    int* __restrict__ off,
                                                    int* __restrict__ cursor) {
  __shared__ int sh[1024];
  int t = threadIdx.x;
  int loc[32];
  int s = 0;
  int base = t * 32;
#pragma unroll
  for (int j = 0; j < 32; j++) { loc[j] = indeg[base + j]; s += loc[j]; }
  sh[t] = s;
  __syncthreads();
  for (int d = 1; d < 1024; d <<= 1) {
    int v = (t >= d) ? sh[t - d] : 0;
    __syncthreads();
    sh[t] += v;
    __syncthreads();
  }
  int run = (t == 0) ? 0 : sh[t - 1];
#pragma unroll
  for (int j = 0; j < 32; j++) { off[base + j] = run; cursor[base + j] = run; run += loc[j]; }
  if (t == 1023) off[NN] = run;
}

__global__ __launch_bounds__(256) void fill_kernel(const int* __restrict__ src,
                                                   const int* __restrict__ dst,
                                                   int* __restrict__ cursor,
                                                   int* __restrict__ esrc) {
  int e = blockIdx.x * 256 + threadIdx.x;
  if (e < EE) {
    int p = atomicAdd(&cursor[dst[e]], 1);
    esrc[p] = src[e];
  }
}

// ---------------- small GEMM, split-K: block = 64 outputs x 4 K-slices ----------------
// C[m*ldc+n] = A[m,K]@B[K,N] (+bias) (+leaky .01 if act); K%4==0
__global__ __launch_bounds__(256) void sgemm_kernel(const float* __restrict__ A,
                                                    const float* __restrict__ B,
                                                    const float* __restrict__ bias,
                                                    float* __restrict__ C,
                                                    int M, int N, int K, int ldc, int act) {
  __shared__ float red[256];
  int tid = threadIdx.x;
  int lo = tid & 63;
  int slice = tid >> 6;
  long oid = (long)blockIdx.x * 64 + lo;
  bool live = (oid < (long)M * N);
  int m = 0, n = 0;
  if (live) { m = (int)(oid / N); n = (int)(oid % N); }
  int kq = K >> 2;
  int k0 = slice * kq, k1 = k0 + kq;
  float acc = 0.f;
  if (live) {
    const float* Ar = A + (size_t)m * K;
    for (int k = k0; k < k1; k++) acc = fmaf(Ar[k], B[(size_t)k * N + n], acc);
  }
  red[tid] = acc;
  __syncthreads();
  if (slice == 0 && live) {
    float v = red[lo] + red[64 + lo] + red[128 + lo] + red[192 + lo];
    if (bias) v += bias[n];
    if (act == 1) v = v > 0.f ? v : 0.01f * v;
    C[(size_t)m * ldc + n] = v;
  }
}

// ---------------- pack W (f32, KxN row-major) into MFMA B-fragment order ----------------
__global__ __launch_bounds__(256) void packB_kernel(const float* __restrict__ W, int N, int K,
                                                    s8v* __restrict__ Bp) {
  int id = blockIdx.x * 256 + threadIdx.x;
  int total = (N >> 4) * (K >> 5) * 64;
  if (id >= total) return;
  int lane = id & 63;
  int tmp = id >> 6;
  int ksteps = K >> 5;
  int ks = tmp % ksteps;
  int nt = tmp / ksteps;
  int n = nt * 16 + (lane & 15);
  int kbase = ks * 32 + (lane >> 4) * 8;
  s8v r;
#pragma unroll
  for (int j = 0; j < 8; j++) r[j] = f2bf_bits(W[(size_t)(kbase + j) * N + n]);
  Bp[id] = r;
}

// ---------------- MFMA bf16 GEMM ----------------
__global__ __launch_bounds__(256) void gemm_mfma(const short* __restrict__ A,
                                                 const s8v* __restrict__ Bp,
                                                 short* __restrict__ C,
                                                 int M, int N, int K) {
  __shared__ short lds[64 * 64];
  int tid = threadIdx.x;
  int wv = tid >> 6, lane = tid & 63;
  int quad = lane >> 4, l16 = lane & 15;
  int brow = blockIdx.y * 64, bcol = blockIdx.x * 64;
  int m = brow + wv * 16 + l16;
  int ksteps = K >> 5;
  f4v acc[4] = {};
  const s8v* Arow = (const s8v*)(A + (size_t)m * K);
  for (int ks = 0; ks < ksteps; ks++) {
    s8v a = Arow[ks * 4 + quad];
#pragma unroll
    for (int nt = 0; nt < 4; nt++) {
      s8v b = Bp[(size_t)(((bcol >> 4) + nt) * ksteps + ks) * 64 + lane];
      acc[nt] = __builtin_amdgcn_mfma_f32_16x16x32_bf16(a, b, acc[nt], 0, 0, 0);
    }
  }
#pragma unroll
  for (int nt = 0; nt < 4; nt++)
#pragma unroll
    for (int r = 0; r < 4; r++)
      lds[(wv * 16 + quad * 4 + r) * 64 + nt * 16 + l16] = f2bf_bits(acc[nt][r]);
  __syncthreads();
#pragma unroll
  for (int rep = 0; rep < 2; rep++) {
    int idx = rep * 256 + tid;
    int row = idx >> 3, c16 = idx & 7;
    uint4 val = ((const uint4*)lds)[idx];
    *(uint4*)(C + (size_t)(brow + row) * N + bcol + c16 * 8) = val;
  }
}

// ---------------- layernorm, wave per node -> packed bf16 out ----------------
__global__ __launch_bounds__(256) void ln_wave(const float* __restrict__ start,
                                               const float* __restrict__ emb2,
                                               const int* __restrict__ m_idx,
                                               const float* __restrict__ lng,
                                               const float* __restrict__ lnb,
                                               unsigned* __restrict__ x0b) {
  int i = blockIdx.x * 4 + (threadIdx.x >> 6);
  int lane = threadIdx.x & 63;
  int g = i >> 6, n = i & 63;
  const float* row = (n == 0) ? (start + (size_t)g * 128) : (emb2 + (size_t)m_idx[i] * 128);
  float2 v = ((const float2*)row)[lane];
  float mu = wred_sum(v.x + v.y) * (1.f / 128.f);
  float dx = v.x - mu, dy = v.y - mu;
  float var = wred_sum(dx * dx + dy * dy) * (1.f / 128.f);
  float rstd = rsqrtf(var + 1e-6f);
  float2 gg = ((const float2*)lng)[lane];
  float2 bb = ((const float2*)lnb)[lane];
  x0b[(size_t)i * 64 + lane] = pk(dx * rstd * gg.x + bb.x, dy * rstd * gg.y + bb.y);
}

// ---------------- attention coefficients, wave per (node,head), xp bf16 ----------------
__global__ __launch_bounds__(256) void al1_wave(const unsigned* __restrict__ xp,
                                                const float* __restrict__ a_src,
                                                const float* __restrict__ a_dst,
                                                float* __restrict__ als,
                                                float* __restrict__ ald) {
  int id = blockIdx.x * 4 + (threadIdx.x >> 6);
  int lane = threadIdx.x & 63;
  int i = id >> 2, h = id & 3;
  float2 x = unpk(xp[(size_t)i * 256 + h * 64 + lane]);
  float2 as = ((const float2*)(a_src + h * 128))[lane];
  float2 ad = ((const float2*)(a_dst + h * 128))[lane];
  float ps = wred_sum(x.x * as.x + x.y * as.y);
  float pd = wred_sum(x.x * ad.x + x.y * ad.y);
  if (lane == 0) { als[id] = ps; ald[id] = pd; }
}

__global__ __launch_bounds__(256) void al2_wave(const unsigned* __restrict__ xp,
                                                const float* __restrict__ a_src,
                                                const float* __restrict__ a_dst,
                                                float* __restrict__ als,
                                                float* __restrict__ ald) {
  int i = blockIdx.x * 4 + (threadIdx.x >> 6);
  int lane = threadIdx.x & 63;
  float2 x = unpk(xp[(size_t)i * 64 + lane]);
  float2 as = ((const float2*)a_src)[lane];
  float2 ad = ((const float2*)a_dst)[lane];
  float ps = wred_sum(x.x * as.x + x.y * as.y);
  float pd = wred_sum(x.x * ad.x + x.y * ad.y);
  if (lane == 0) { als[i] = ps; ald[i] = pd; }
}

// ---------------- softmax weights ----------------
__global__ __launch_bounds__(256) void alpha1_kernel(const float* __restrict__ als,
                                                     const float* __restrict__ ald,
                                                     const int* __restrict__ off,
                                                     const int* __restrict__ esrc,
                                                     float* __restrict__ aw,
                                                     float* __restrict__ selfw,
                                                     float* __restrict__ inv) {
  int id = blockIdx.x * 256 + threadIdx.x;
  if (id >= NN * 4) return;
  int i = id >> 2, h = id & 3;
  float adi = ald[id];
  float selfSc = als[id] + adi;
  selfSc = selfSc > 0.f ? selfSc : 0.2f * selfSc;
  int s0 = off[i], s1 = off[i + 1];
  float m = selfSc;
  for (int e = s0; e < s1; e++) {
    float sc = als[esrc[e] * 4 + h] + adi;
    sc = sc > 0.f ? sc : 0.2f * sc;
    m = fmaxf(m, sc);
  }
  float sw = __expf(selfSc - m);
  float denom = sw;
  for (int e = s0; e < s1; e++) {
    float sc = als[esrc[e] * 4 + h] + adi;
    sc = sc > 0.f ? sc : 0.2f * sc;
    float w = __expf(sc - m);
    aw[e * 4 + h] = w;
    denom += w;
  }
  selfw[id] = sw;
  inv[id] = 1.f / denom;
}

__global__ __launch_bounds__(256) void alpha2_kernel(const float* __restrict__ als,
                                                     const float* __restrict__ ald,
                                                     const int* __restrict__ off,
                                                     const int* __restrict__ esrc,
                                                     float* __restrict__ aw,
                                                     float* __restrict__ selfw,
                                                     float* __restrict__ inv) {
  int i = blockIdx.x * 256 + threadIdx.x;
  if (i >= NN) return;
  float adi = ald[i];
  float selfSc = als[i] + adi;
  selfSc = selfSc > 0.f ? selfSc : 0.2f * selfSc;
  int s0 = off[i], s1 = off[i + 1];
  float m = selfSc;
  for (int e = s0; e < s1; e++) {
    float sc = als[esrc[e]] + adi;
    sc = sc > 0.f ? sc : 0.2f * sc;
    m = fmaxf(m, sc);
  }
  float sw = __expf(selfSc - m);
  float denom = sw;
  for (int e = s0; e < s1; e++) {
    float sc = als[esrc[e]] + adi;
    sc = sc > 0.f ? sc : 0.2f * sc;
    float w = __expf(sc - m);
    aw[e] = w;
    denom += w;
  }
  selfw[i] = sw;
  inv[i] = 1.f / denom;
}

// ---------------- weighted gather, conv1: thread per (node, uint2) ----------------
__global__ __launch_bounds__(256) void agg1w_kernel(const uint2* __restrict__ xp,
                                                    const float* __restrict__ aw,
                                                    const float* __restrict__ selfw,
                                                    const float* __restrict__ inv,
                                                    const int* __restrict__ off,
                                                    const int* __restrict__ esrc,
                                                    const float* __restrict__ b1,
                                                    uint2* __restrict__ x1) {
  long gid = (long)blockIdx.x * 256 + threadIdx.x;
  if (gid >= (long)NN * 128) return;
  int i = (int)(gid >> 7), c4 = (int)(gid & 127), h = c4 >> 5;
  float sw = selfw[i * 4 + h];
  float iv = inv[i * 4 + h];
  uint2 xv = xp[(size_t)i * 128 + c4];
  float2 xa = unpk(xv.x), xb = unpk(xv.y);
  float4 acc = make_float4(sw * xa.x, sw * xa.y, sw * xb.x, sw * xb.y);
  int s0 = off[i], s1 = off[i + 1];
  int e = s0;
  for (; e + 1 < s1; e += 2) {
    int sA = esrc[e], sB = esrc[e + 1];
    float wA = aw[e * 4 + h], wB = aw[(e + 1) * 4 + h];
    uint2 mA = xp[(size_t)sA * 128 + c4];
    uint2 mB = xp[(size_t)sB * 128 + c4];
    float2 a0 = unpk(mA.x), a1 = unpk(mA.y);
    float2 b0 = unpk(mB.x), b1v = unpk(mB.y);
    acc.x = fmaf(wA, a0.x, acc.x); acc.y = fmaf(wA, a0.y, acc.y);
    acc.z = fmaf(wA, a1.x, acc.z); acc.w = fmaf(wA, a1.y, acc.w);
    acc.x = fmaf(wB, b0.x, acc.x); acc.y = fmaf(wB, b0.y, acc.y);
    acc.z = fmaf(wB, b1v.x, acc.z); acc.w = fmaf(wB, b1v.y, acc.w);
  }
  if (e < s1) {
    int sA = esrc[e];
    float wA = aw[e * 4 + h];
    uint2 mA = xp[(size_t)sA * 128 + c4];
    float2 a0 = unpk(mA.x), a1 = unpk(mA.y);
    acc.x = fmaf(wA, a0.x, acc.x); acc.y = fmaf(wA, a0.y, acc.y);
    acc.z = fmaf(wA, a1.x, acc.z); acc.w = fmaf(wA, a1.y, acc.w);
  }
  float4 bb = ((const float4*)b1)[c4];
  float v0 = acc.x * iv + bb.x;
  float v1 = acc.y * iv + bb.y;
  float v2 = acc.z * iv + bb.z;
  float v3 = acc.w * iv + bb.w;
  v0 = v0 > 0.f ? v0 : (__expf(v0) - 1.f);
  v1 = v1 > 0.f ? v1 : (__expf(v1) - 1.f);
  v2 = v2 > 0.f ? v2 : (__expf(v2) - 1.f);
  v3 = v3 > 0.f ? v3 : (__expf(v3) - 1.f);
  uint2 o;
  o.x = pk(v0, v1);
  o.y = pk(v2, v3);
  x1[gid] = o;
}

// ---------------- weighted gather, conv2: thread per (node, uint2) ----------------
__global__ __launch_bounds__(256) void agg2w_kernel(const uint2* __restrict__ xp,
                                                    const float* __restrict__ aw,
                                                    const float* __restrict__ selfw,
                                                    const float* __restrict__ inv,
                                                    const int* __restrict__ off,
                                                    const int* __restrict__ esrc,
                                                    const float* __restrict__ b2,
                                                    float4* __restrict__ x2) {
  long gid = (long)blockIdx.x * 256 + threadIdx.x;
  if (gid >= (long)NN * 32) return;
  int i = (int)(gid >> 5), c4 = (int)(gid & 31);
  float sw = selfw[i];
  float iv = inv[i];
  uint2 xv = xp[(size_t)i * 32 + c4];
  float2 xa = unpk(xv.x), xb = unpk(xv.y);
  float4 acc = make_float4(sw * xa.x, sw * xa.y, sw * xb.x, sw * xb.y);
  int s0 = off[i], s1 = off[i + 1];
  int e = s0;
  for (; e + 1 < s1; e += 2) {
    int sA = esrc[e], sB = esrc[e + 1];
    float wA = aw[e], wB = aw[e + 1];
    uint2 mA = xp[(size_t)sA * 32 + c4];
    uint2 mB = xp[(size_t)sB * 32 + c4];
    float2 a0 = unpk(mA.x), a1 = unpk(mA.y);
    float2 b0 = unpk(mB.x), b1v = unpk(mB.y);
    acc.x = fmaf(wA, a0.x, acc.x); acc.y = fmaf(wA, a0.y, acc.y);
    acc.z = fmaf(wA, a1.x, acc.z); acc.w = fmaf(wA, a1.y, acc.w);
    acc.x = fmaf(wB, b0.x, acc.x); acc.y = fmaf(wB, b0.y, acc.y);
    acc.z = fmaf(wB, b1v.x, acc.z); acc.w = fmaf(wB, b1v.y, acc.w);
  }
  if (e < s1) {
    int sA = esrc[e];
    float wA = aw[e];
    uint2 mA = xp[(size_t)sA * 32 + c4];
    float2 a0 = unpk(mA.x), a1 = unpk(mA.y);
    acc.x = fmaf(wA, a0.x, acc.x); acc.y = fmaf(wA, a0.y, acc.y);
    acc.z = fmaf(wA, a1.x, acc.z); acc.w = fmaf(wA, a1.y, acc.w);
  }
  float4 bb = ((const float4*)b2)[c4];
  float v0 = acc.x * iv + bb.x;
  float v1 = acc.y * iv + bb.y;
  float v2 = acc.z * iv + bb.z;
  float v3 = acc.w * iv + bb.w;
  v0 = v0 > 0.f ? v0 : (__expf(v0) - 1.f);
  v1 = v1 > 0.f ? v1 : (__expf(v1) - 1.f);
  v2 = v2 > 0.f ? v2 : (__expf(v2) - 1.f);
  v3 = v3 > 0.f ? v3 : (__expf(v3) - 1.f);
  x2[gid] = make_float4(v0, v1, v2, v3);
}

// ---------------- masked mean pool ----------------
__global__ __launch_bounds__(128) void pool_kernel(const float* __restrict__ x2,
                                                   const int* __restrict__ m_idx,
                                                   float* __restrict__ pooled) {
  int g = blockIdx.x, c = threadIdx.x;
  float acc = 0.f, cnt = 0.f;
  const float* xr = x2 + (size_t)g * 64 * 128;
  const int* mi = m_idx + g * 64;
  for (int n = 0; n < 64; n++) {
    if (mi[n] >= 1) { cnt += 1.f; acc += xr[n * 128 + c]; }
  }
  pooled[(size_t)g * 128 + c] = acc / cnt;
}

// ---------------- final logit ----------------
__global__ __launch_bounds__(256) void head2_naive(const float* __restrict__ h1,
                                                   const float* __restrict__ Wo2,
                                                   const float* __restrict__ bo2,
                                                   float* __restrict__ out) {
  int g = blockIdx.x * 256 + threadIdx.x;
  if (g >= GG) return;
  float p = bo2[0];
  for (int c = 0; c < 128; c++) p = fmaf(h1[(size_t)g * 128 + c], Wo2[c], p);
  out[g] = p;
}

extern "C" void kernel_launch(void* const* d_in, const int* in_sizes, int n_in, void* d_out,
                              int out_size, void* d_ws, size_t ws_size, hipStream_t stream) {
  (void)n_in; (void)out_size; (void)ws_size;
  bool dict_order = (in_sizes[2] == NN);
  int IM, IE, IF[25];
  if (dict_order) {
    IM = 2; IE = 3;
    const int f[25] = {0, 1, 4, 5, 6, 7, 8, 9, 10, 11, 12, 13, 14, 15, 16, 17, 18,
                       19, 20, 21, 22, 23, 24, 25, 26};
    for (int k = 0; k < 25; k++) IF[k] = f[k];
  } else {
    IM = 25; IE = 26;
    for (int k = 0; k < 25; k++) IF[k] = k;
  }
  const int* m_idx = (const int*)d_in[IM];
  const int* eidx = (const int*)d_in[IE];
  float* out = (float*)d_out;
  const int* e_src = eidx;
  const int* e_dst = eidx + EE;

  const float* t = (const float*)d_in[IF[0]];
  const float* v = (const float*)d_in[IF[1]];
  const float* Wt = (const float*)d_in[IF[2]];     const float* bt = (const float*)d_in[IF[3]];
  const float* Wv = (const float*)d_in[IF[4]];     const float* bv = (const float*)d_in[IF[5]];
  const float* emb = (const float*)d_in[IF[6]];
  const float* Wnode = (const float*)d_in[IF[7]];  const float* bnode = (const float*)d_in[IF[8]];
  const float* Wstart = (const float*)d_in[IF[9]]; const float* bstart = (const float*)d_in[IF[10]];
  const float* ln_g = (const float*)d_in[IF[11]];  const float* ln_b = (const float*)d_in[IF[12]];
  const float* W1 = (const float*)d_in[IF[13]];
  const float* a_src1 = (const float*)d_in[IF[14]]; const float* a_dst1 = (const float*)d_in[IF[15]];
  const float* b1 = (const float*)d_in[IF[16]];
  const float* W2 = (const float*)d_in[IF[17]];
  const float* a_src2 = (const float*)d_in[IF[18]]; const float* a_dst2 = (const float*)d_in[IF[19]];
  const float* b2 = (const float*)d_in[IF[20]];
  const float* Wo1 = (const float*)d_in[IF[21]];   const float* bo1 = (const float*)d_in[IF[22]];
  const float* Wo2 = (const float*)d_in[IF[23]];   const float* bo2 = (const float*)d_in[IF[24]];

  // workspace layout (peak ~96 MB)
  char* w = (char*)d_ws;
  bf16* xp1b = (bf16*)(w);                           // [NN,512] bf16 [0,32) MB
  bf16* x0b = (bf16*)(w + ((size_t)32 << 20));       // [NN,128] bf16 [32,40) MB
  bf16* x1 = (bf16*)(w + ((size_t)48 << 20));        // [NN,512] bf16 [48,80) MB
  bf16* xp2b = (bf16*)(w);                           // [NN,128] bf16 [0,8)  (xp1b dead)
  float* x2 = (float*)(w + ((size_t)8 << 20));       // [NN,128] f32 [8,24)
  size_t so = (size_t)80 << 20;                      // smalls [80,~96) MB
  float* vt = (float*)(w + so); so += 512 * 256 * 4;
  float* start = (float*)(w + so); so += 512 * 128 * 4;
  float* emb2 = (float*)(w + so); so += 51 * 128 * 4 + 256;
  float* als1 = (float*)(w + so); so += NN * 4 * 4;
  float* ald1 = (float*)(w + so); so += NN * 4 * 4;
  float* als2 = (float*)(w + so); so += NN * 4;
  float* ald2 = (float*)(w + so); so += NN * 4;
  float* aw1 = (float*)(w + so); so += EE * 4 * 4;   // 4 MB
  float* selfw1 = (float*)(w + so); so += NN * 4 * 4;
  float* inv1 = (float*)(w + so); so += NN * 4 * 4;
  float* aw2 = (float*)(w + so); so += EE * 4;       // 1 MB
  float* selfw2 = (float*)(w + so); so += NN * 4;
  float* inv2 = (float*)(w + so); so += NN * 4;
  float* pooled = (float*)(w + so); so += 512 * 128 * 4;
  float* h1 = (float*)(w + so); so += 512 * 128 * 4;
  int* indeg = (int*)(w + so); so += NN * 4;
  int* csroff = (int*)(w + so); so += (NN + 1) * 4 + 252;
  int* cursor = (int*)(w + so); so += NN * 4;
  int* esrc = (int*)(w + so); so += EE * 4;
  s8v* Bp1 = (s8v*)(w + so); so += 32 * 4 * 64 * 16;   // 128 KB (conv1 W1 frags)
  s8v* Bp2 = (s8v*)(w + so); so += 8 * 16 * 64 * 16;   // 128 KB (conv2 W2 frags)

  // ---- CSR build ----
  hipMemsetAsync(indeg, 0, NN * 4, stream);
  hist_kernel<<<EE / 256, 256, 0, stream>>>(e_dst, indeg);
  scan_kernel<<<1, 1024, 0, stream>>>(indeg, csroff, cursor);
  fill_kernel<<<EE / 256, 256, 0, stream>>>(e_src, e_dst, cursor, esrc);

  // pack conv weights into MFMA fragment order
  packB_kernel<<<32, 256, 0, stream>>>(W1, 512, 128, Bp1);
  packB_kernel<<<32, 256, 0, stream>>>(W2, 128, 512, Bp2);

  // small GEMMs: split-K, high-occupancy
  sgemm_kernel<<<(51 * 128 + 63) / 64, 256, 0, stream>>>(emb, Wnode, bnode, emb2, 51, 128, 128, 128, 0);
  sgemm_kernel<<<512 * 128 / 64, 256, 0, stream>>>(v, Wv, bv, vt, 512, 128, 768, 256, 0);
  sgemm_kernel<<<512 * 128 / 64, 256, 0, stream>>>(t, Wt, bt, vt + 128, 512, 128, 768, 256, 0);
  sgemm_kernel<<<512 * 128 / 64, 256, 0, stream>>>(vt, Wstart, bstart, start, 512, 128, 256, 128, 0);
  ln_wave<<<NN / 4, 256, 0, stream>>>(start, emb2, m_idx, ln_g, ln_b, (unsigned*)x0b);

  // conv1: MFMA GEMM (bf16 in/out)
  gemm_mfma<<<dim3(8, NN / 64), 256, 0, stream>>>((const short*)x0b, Bp1, (short*)xp1b, NN, 512, 128);
  al1_wave<<<NN, 256, 0, stream>>>((const unsigned*)xp1b, a_src1, a_dst1, als1, ald1);
  alpha1_kernel<<<NN * 4 / 256, 256, 0, stream>>>(als1, ald1, csroff, esrc, aw1, selfw1, inv1);
  agg1w_kernel<<<(int)(((long)NN * 128 + 255) / 256), 256, 0, stream>>>(
      (const uint2*)xp1b, aw1, selfw1, inv1, csroff, esrc, b1, (uint2*)x1);

  // conv2: MFMA GEMM (bf16 in/out)
  gemm_mfma<<<dim3(2, NN / 64), 256, 0, stream>>>((const short*)x1, Bp2, (short*)xp2b, NN, 128, 512);
  al2_wave<<<NN / 4, 256, 0, stream>>>((const unsigned*)xp2b, a_src2, a_dst2, als2, ald2);
  alpha2_kernel<<<NN / 256, 256, 0, stream>>>(als2, ald2, csroff, esrc, aw2, selfw2, inv2);
  agg2w_kernel<<<(int)(((long)NN * 32 + 255) / 256), 256, 0, stream>>>(
      (const uint2*)xp2b, aw2, selfw2, inv2, csroff, esrc, b2, (float4*)x2);

  pool_kernel<<<GG, 128, 0, stream>>>(x2, m_idx, pooled);
  sgemm_kernel<<<512 * 128 / 64, 256, 0, stream>>>(pooled, Wo1, bo1, h1, 512, 128, 128, 128, 1);
  head2_naive<<<(GG + 255) / 256, 256, 0, stream>>>(h1, Wo2, bo2, out);
}

// Round 14
// 403.540 us; speedup vs baseline: 6.1462x; 1.1686x over previous
//
#include <hip/hip_runtime.h>
#include <hip/hip_bf16.h>

typedef __hip_bfloat16 bf16;
typedef __attribute__((ext_vector_type(8))) short s8v;   // 8 bf16 (4 VGPRs)
typedef __attribute__((ext_vector_type(4))) float f4v;   // 4 fp32 acc

#define NN 32768   // total nodes
#define EE 262144  // edges
#define GG 512     // graphs

__device__ __forceinline__ float2 unpk(unsigned u) {
  float2 r;
  r.x = __uint_as_float(u << 16);
  r.y = __uint_as_float(u & 0xffff0000u);
  return r;
}
__device__ __forceinline__ unsigned pk(float x, float y) {
  union { bf16 h[2]; unsigned u; } p;
  p.h[0] = __float2bfloat16(x);
  p.h[1] = __float2bfloat16(y);
  return p.u;
}
__device__ __forceinline__ short f2bf_bits(float x) {
  bf16 h = __float2bfloat16(x);
  return *reinterpret_cast<short*>(&h);
}
__device__ __forceinline__ void storef(float* p, float v) { *p = v; }
__device__ __forceinline__ void storef(bf16* p, float v) { *p = __float2bfloat16(v); }

__device__ __forceinline__ float wred_sum(float v) {
#pragma unroll
  for (int o = 32; o; o >>= 1) v += __shfl_xor(v, o, 64);
  return v;
}

// ---------------- CSR build ----------------
__global__ __launch_bounds__(256) void hist_kernel(const int* __restrict__ dst,
                                                   int* __restrict__ indeg) {
  int e = blockIdx.x * 256 + threadIdx.x;
  if (e < EE) atomicAdd(&indeg[dst[e]], 1);
}

__global__ __launch_bounds__(1024) void scan_kernel(const int* __restrict__ indeg,
                                                    int* __restrict__ off,
                                                    int* __restrict__ cursor) {
  __shared__ int sh[1024];
  int t = threadIdx.x;
  int loc[32];
  int s = 0;
  int base = t * 32;
#pragma unroll
  for (int j = 0; j < 32; j++) { loc[j] = indeg[base + j]; s += loc[j]; }
  sh[t] = s;
  __syncthreads();
  for (int d = 1; d < 1024; d <<= 1) {
    int v = (t >= d) ? sh[t - d] : 0;
    __syncthreads();
    sh[t] += v;
    __syncthreads();
  }
  int run = (t == 0) ? 0 : sh[t - 1];
#pragma unroll
  for (int j = 0; j < 32; j++) { off[base + j] = run; cursor[base + j] = run; run += loc[j]; }
  if (t == 1023) off[NN] = run;
}

__global__ __launch_bounds__(256) void fill_kernel(const int* __restrict__ src,
                                                   const int* __restrict__ dst,
                                                   int* __restrict__ cursor,
                                                   int* __restrict__ esrc) {
  int e = blockIdx.x * 256 + threadIdx.x;
  if (e < EE) {
    int p = atomicAdd(&cursor[dst[e]], 1);
    esrc[p] = src[e];
  }
}

// ---------------- fp32 -> packed bf16 conversion ----------------
__global__ __launch_bounds__(256) void cvtpk_kernel(const float2* __restrict__ src,
                                                    unsigned* __restrict__ dst, int n2) {
  int id = blockIdx.x * 256 + threadIdx.x;
  if (id < n2) { float2 v = src[id]; dst[id] = pk(v.x, v.y); }
}

// ---------------- small GEMM, split-K (only tiny problems) ----------------
template <typename TC>
__global__ __launch_bounds__(256) void sgemm_kernel(const float* __restrict__ A,
                                                    const float* __restrict__ B,
                                                    const float* __restrict__ bias,
                                                    TC* __restrict__ C,
                                                    int M, int N, int K, int ldc, int act) {
  __shared__ float red[256];
  int tid = threadIdx.x;
  int lo = tid & 63;
  int slice = tid >> 6;
  long oid = (long)blockIdx.x * 64 + lo;
  bool live = (oid < (long)M * N);
  int m = 0, n = 0;
  if (live) { m = (int)(oid / N); n = (int)(oid % N); }
  int kq = K >> 2;
  int k0 = slice * kq, k1 = k0 + kq;
  float acc = 0.f;
  if (live) {
    const float* Ar = A + (size_t)m * K;
    for (int k = k0; k < k1; k++) acc = fmaf(Ar[k], B[(size_t)k * N + n], acc);
  }
  red[tid] = acc;
  __syncthreads();
  if (slice == 0 && live) {
    float v = red[lo] + red[64 + lo] + red[128 + lo] + red[192 + lo];
    if (bias) v += bias[n];
    if (act == 1) v = v > 0.f ? v : 0.01f * v;
    storef(&C[(size_t)m * ldc + n], v);
  }
}

// ---------------- pack W (f32, KxN row-major) into MFMA B-fragment order ----------------
__global__ __launch_bounds__(256) void packB_kernel(const float* __restrict__ W, int N, int K,
                                                    s8v* __restrict__ Bp) {
  int id = blockIdx.x * 256 + threadIdx.x;
  int total = (N >> 4) * (K >> 5) * 64;
  if (id >= total) return;
  int lane = id & 63;
  int tmp = id >> 6;
  int ksteps = K >> 5;
  int ks = tmp % ksteps;
  int nt = tmp / ksteps;
  int n = nt * 16 + (lane & 15);
  int kbase = ks * 32 + (lane >> 4) * 8;
  s8v r;
#pragma unroll
  for (int j = 0; j < 8; j++) r[j] = f2bf_bits(W[(size_t)(kbase + j) * N + n]);
  Bp[id] = r;
}

// ---------------- MFMA bf16 GEMM, optional fp32 bias, bf16 out with ldc ----------------
__global__ __launch_bounds__(256) void gemm_mfma(const short* __restrict__ A,
                                                 const s8v* __restrict__ Bp,
                                                 const float* __restrict__ bias,
                                                 short* __restrict__ C,
                                                 int M, int N, int K, int ldc) {
  __shared__ short lds[64 * 64];
  int tid = threadIdx.x;
  int wv = tid >> 6, lane = tid & 63;
  int quad = lane >> 4, l16 = lane & 15;
  int brow = blockIdx.y * 64, bcol = blockIdx.x * 64;
  int m = brow + wv * 16 + l16;
  int ksteps = K >> 5;
  f4v acc[4] = {};
  const s8v* Arow = (const s8v*)(A + (size_t)m * K);
  for (int ks = 0; ks < ksteps; ks++) {
    s8v a = Arow[ks * 4 + quad];
#pragma unroll
    for (int nt = 0; nt < 4; nt++) {
      s8v b = Bp[(size_t)(((bcol >> 4) + nt) * ksteps + ks) * 64 + lane];
      acc[nt] = __builtin_amdgcn_mfma_f32_16x16x32_bf16(a, b, acc[nt], 0, 0, 0);
    }
  }
#pragma unroll
  for (int nt = 0; nt < 4; nt++) {
    float bv = bias ? bias[bcol + nt * 16 + l16] : 0.f;
#pragma unroll
    for (int r = 0; r < 4; r++)
      lds[(wv * 16 + quad * 4 + r) * 64 + nt * 16 + l16] = f2bf_bits(acc[nt][r] + bv);
  }
  __syncthreads();
#pragma unroll
  for (int rep = 0; rep < 2; rep++) {
    int idx = rep * 256 + tid;
    int row = idx >> 3, c16 = idx & 7;
    uint4 val = ((const uint4*)lds)[idx];
    *(uint4*)(C + (size_t)(brow + row) * ldc + bcol + c16 * 8) = val;
  }
}

// ---------------- layernorm, wave per node; bf16 in -> packed bf16 out ----------------
__global__ __launch_bounds__(256) void ln_wave(const unsigned* __restrict__ start_b,
                                               const unsigned* __restrict__ emb2_b,
                                               const int* __restrict__ m_idx,
                                               const float* __restrict__ lng,
                                               const float* __restrict__ lnb,
                                               unsigned* __restrict__ x0b) {
  int i = blockIdx.x * 4 + (threadIdx.x >> 6);
  int lane = threadIdx.x & 63;
  int g = i >> 6, n = i & 63;
  const unsigned* row = (n == 0) ? (start_b + (size_t)g * 64) : (emb2_b + (size_t)m_idx[i] * 64);
  float2 v = unpk(row[lane]);
  float mu = wred_sum(v.x + v.y) * (1.f / 128.f);
  float dx = v.x - mu, dy = v.y - mu;
  float var = wred_sum(dx * dx + dy * dy) * (1.f / 128.f);
  float rstd = rsqrtf(var + 1e-6f);
  float2 gg = ((const float2*)lng)[lane];
  float2 bb = ((const float2*)lnb)[lane];
  x0b[(size_t)i * 64 + lane] = pk(dx * rstd * gg.x + bb.x, dy * rstd * gg.y + bb.y);
}

// ---------------- attention coefficients, wave per (node,head), xp bf16 ----------------
__global__ __launch_bounds__(256) void al1_wave(const unsigned* __restrict__ xp,
                                                const float* __restrict__ a_src,
                                                const float* __restrict__ a_dst,
                                                float* __restrict__ als,
                                                float* __restrict__ ald) {
  int id = blockIdx.x * 4 + (threadIdx.x >> 6);
  int lane = threadIdx.x & 63;
  int i = id >> 2, h = id & 3;
  float2 x = unpk(xp[(size_t)i * 256 + h * 64 + lane]);
  float2 as = ((const float2*)(a_src + h * 128))[lane];
  float2 ad = ((const float2*)(a_dst + h * 128))[lane];
  float ps = wred_sum(x.x * as.x + x.y * as.y);
  float pd = wred_sum(x.x * ad.x + x.y * ad.y);
  if (lane == 0) { als[id] = ps; ald[id] = pd; }
}

__global__ __launch_bounds__(256) void al2_wave(const unsigned* __restrict__ xp,
                                                const float* __restrict__ a_src,
                                                const float* __restrict__ a_dst,
                                                float* __restrict__ als,
                                                float* __restrict__ ald) {
  int i = blockIdx.x * 4 + (threadIdx.x >> 6);
  int lane = threadIdx.x & 63;
  float2 x = unpk(xp[(size_t)i * 64 + lane]);
  float2 as = ((const float2*)a_src)[lane];
  float2 ad = ((const float2*)a_dst)[lane];
  float ps = wred_sum(x.x * as.x + x.y * as.y);
  float pd = wred_sum(x.x * ad.x + x.y * ad.y);
  if (lane == 0) { als[i] = ps; ald[i] = pd; }
}

// ---------------- softmax weights ----------------
__global__ __launch_bounds__(256) void alpha1_kernel(const float* __restrict__ als,
                                                     const float* __restrict__ ald,
                                                     const int* __restrict__ off,
                                                     const int* __restrict__ esrc,
                                                     float* __restrict__ aw,
                                                     float* __restrict__ selfw,
                                                     float* __restrict__ inv) {
  int id = blockIdx.x * 256 + threadIdx.x;
  if (id >= NN * 4) return;
  int i = id >> 2, h = id & 3;
  float adi = ald[id];
  float selfSc = als[id] + adi;
  selfSc = selfSc > 0.f ? selfSc : 0.2f * selfSc;
  int s0 = off[i], s1 = off[i + 1];
  float m = selfSc;
  for (int e = s0; e < s1; e++) {
    float sc = als[esrc[e] * 4 + h] + adi;
    sc = sc > 0.f ? sc : 0.2f * sc;
    m = fmaxf(m, sc);
  }
  float sw = __expf(selfSc - m);
  float denom = sw;
  for (int e = s0; e < s1; e++) {
    float sc = als[esrc[e] * 4 + h] + adi;
    sc = sc > 0.f ? sc : 0.2f * sc;
    float w = __expf(sc - m);
    aw[e * 4 + h] = w;
    denom += w;
  }
  selfw[id] = sw;
  inv[id] = 1.f / denom;
}

__global__ __launch_bounds__(256) void alpha2_kernel(const float* __restrict__ als,
                                                     const float* __restrict__ ald,
                                                     const int* __restrict__ off,
                                                     const int* __restrict__ esrc,
                                                     float* __restrict__ aw,
                                                     float* __restrict__ selfw,
                                                     float* __restrict__ inv) {
  int i = blockIdx.x * 256 + threadIdx.x;
  if (i >= NN) return;
  float adi = ald[i];
  float selfSc = als[i] + adi;
  selfSc = selfSc > 0.f ? selfSc : 0.2f * selfSc;
  int s0 = off[i], s1 = off[i + 1];
  float m = selfSc;
  for (int e = s0; e < s1; e++) {
    float sc = als[esrc[e]] + adi;
    sc = sc > 0.f ? sc : 0.2f * sc;
    m = fmaxf(m, sc);
  }
  float sw = __expf(selfSc - m);
  float denom = sw;
  for (int e = s0; e < s1; e++) {
    float sc = als[esrc[e]] + adi;
    sc = sc > 0.f ? sc : 0.2f * sc;
    float w = __expf(sc - m);
    aw[e] = w;
    denom += w;
  }
  selfw[i] = sw;
  inv[i] = 1.f / denom;
}

// ---------------- weighted gather, conv1: thread per (node, uint2) ----------------
__global__ __launch_bounds__(256) void agg1w_kernel(const uint2* __restrict__ xp,
                                                    const float* __restrict__ aw,
                                                    const float* __restrict__ selfw,
                                                    const float* __restrict__ inv,
                                                    const int* __restrict__ off,
                                                    const int* __restrict__ esrc,
                                                    const float* __restrict__ b1,
                                                    uint2* __restrict__ x1) {
  long gid = (long)blockIdx.x * 256 + threadIdx.x;
  if (gid >= (long)NN * 128) return;
  int i = (int)(gid >> 7), c4 = (int)(gid & 127), h = c4 >> 5;
  float sw = selfw[i * 4 + h];
  float iv = inv[i * 4 + h];
  uint2 xv = xp[(size_t)i * 128 + c4];
  float2 xa = unpk(xv.x), xb = unpk(xv.y);
  float4 acc = make_float4(sw * xa.x, sw * xa.y, sw * xb.x, sw * xb.y);
  int s0 = off[i], s1 = off[i + 1];
  int e = s0;
  for (; e + 1 < s1; e += 2) {
    int sA = esrc[e], sB = esrc[e + 1];
    float wA = aw[e * 4 + h], wB = aw[(e + 1) * 4 + h];
    uint2 mA = xp[(size_t)sA * 128 + c4];
    uint2 mB = xp[(size_t)sB * 128 + c4];
    float2 a0 = unpk(mA.x), a1 = unpk(mA.y);
    float2 b0 = unpk(mB.x), b1v = unpk(mB.y);
    acc.x = fmaf(wA, a0.x, acc.x); acc.y = fmaf(wA, a0.y, acc.y);
    acc.z = fmaf(wA, a1.x, acc.z); acc.w = fmaf(wA, a1.y, acc.w);
    acc.x = fmaf(wB, b0.x, acc.x); acc.y = fmaf(wB, b0.y, acc.y);
    acc.z = fmaf(wB, b1v.x, acc.z); acc.w = fmaf(wB, b1v.y, acc.w);
  }
  if (e < s1) {
    int sA = esrc[e];
    float wA = aw[e * 4 + h];
    uint2 mA = xp[(size_t)sA * 128 + c4];
    float2 a0 = unpk(mA.x), a1 = unpk(mA.y);
    acc.x = fmaf(wA, a0.x, acc.x); acc.y = fmaf(wA, a0.y, acc.y);
    acc.z = fmaf(wA, a1.x, acc.z); acc.w = fmaf(wA, a1.y, acc.w);
  }
  float4 bb = ((const float4*)b1)[c4];
  float v0 = acc.x * iv + bb.x;
  float v1 = acc.y * iv + bb.y;
  float v2 = acc.z * iv + bb.z;
  float v3 = acc.w * iv + bb.w;
  v0 = v0 > 0.f ? v0 : (__expf(v0) - 1.f);
  v1 = v1 > 0.f ? v1 : (__expf(v1) - 1.f);
  v2 = v2 > 0.f ? v2 : (__expf(v2) - 1.f);
  v3 = v3 > 0.f ? v3 : (__expf(v3) - 1.f);
  uint2 o;
  o.x = pk(v0, v1);
  o.y = pk(v2, v3);
  x1[gid] = o;
}

// ---------------- weighted gather, conv2: thread per (node, uint2) ----------------
__global__ __launch_bounds__(256) void agg2w_kernel(const uint2* __restrict__ xp,
                                                    const float* __restrict__ aw,
                                                    const float* __restrict__ selfw,
                                                    const float* __restrict__ inv,
                                                    const int* __restrict__ off,
                                                    const int* __restrict__ esrc,
                                                    const float* __restrict__ b2,
                                                    float4* __restrict__ x2) {
  long gid = (long)blockIdx.x * 256 + threadIdx.x;
  if (gid >= (long)NN * 32) return;
  int i = (int)(gid >> 5), c4 = (int)(gid & 31);
  float sw = selfw[i];
  float iv = inv[i];
  uint2 xv = xp[(size_t)i * 32 + c4];
  float2 xa = unpk(xv.x), xb = unpk(xv.y);
  float4 acc = make_float4(sw * xa.x, sw * xa.y, sw * xb.x, sw * xb.y);
  int s0 = off[i], s1 = off[i + 1];
  int e = s0;
  for (; e + 1 < s1; e += 2) {
    int sA = esrc[e], sB = esrc[e + 1];
    float wA = aw[e], wB = aw[e + 1];
    uint2 mA = xp[(size_t)sA * 32 + c4];
    uint2 mB = xp[(size_t)sB * 32 + c4];
    float2 a0 = unpk(mA.x), a1 = unpk(mA.y);
    float2 b0 = unpk(mB.x), b1v = unpk(mB.y);
    acc.x = fmaf(wA, a0.x, acc.x); acc.y = fmaf(wA, a0.y, acc.y);
    acc.z = fmaf(wA, a1.x, acc.z); acc.w = fmaf(wA, a1.y, acc.w);
    acc.x = fmaf(wB, b0.x, acc.x); acc.y = fmaf(wB, b0.y, acc.y);
    acc.z = fmaf(wB, b1v.x, acc.z); acc.w = fmaf(wB, b1v.y, acc.w);
  }
  if (e < s1) {
    int sA = esrc[e];
    float wA = aw[e];
    uint2 mA = xp[(size_t)sA * 32 + c4];
    float2 a0 = unpk(mA.x), a1 = unpk(mA.y);
    acc.x = fmaf(wA, a0.x, acc.x); acc.y = fmaf(wA, a0.y, acc.y);
    acc.z = fmaf(wA, a1.x, acc.z); acc.w = fmaf(wA, a1.y, acc.w);
  }
  float4 bb = ((const float4*)b2)[c4];
  float v0 = acc.x * iv + bb.x;
  float v1 = acc.y * iv + bb.y;
  float v2 = acc.z * iv + bb.z;
  float v3 = acc.w * iv + bb.w;
  v0 = v0 > 0.f ? v0 : (__expf(v0) - 1.f);
  v1 = v1 > 0.f ? v1 : (__expf(v1) - 1.f);
  v2 = v2 > 0.f ? v2 : (__expf(v2) - 1.f);
  v3 = v3 > 0.f ? v3 : (__expf(v3) - 1.f);
  x2[gid] = make_float4(v0, v1, v2, v3);
}

// ---------------- masked mean pool ----------------
__global__ __launch_bounds__(128) void pool_kernel(const float* __restrict__ x2,
                                                   const int* __restrict__ m_idx,
                                                   float* __restrict__ pooled) {
  int g = blockIdx.x, c = threadIdx.x;
  float acc = 0.f, cnt = 0.f;
  const float* xr = x2 + (size_t)g * 64 * 128;
  const int* mi = m_idx + g * 64;
  for (int n = 0; n < 64; n++) {
    if (mi[n] >= 1) { cnt += 1.f; acc += xr[n * 128 + c]; }
  }
  pooled[(size_t)g * 128 + c] = acc / cnt;
}

// ---------------- final logit ----------------
__global__ __launch_bounds__(256) void head2_naive(const float* __restrict__ h1,
                                                   const float* __restrict__ Wo2,
                                                   const float* __restrict__ bo2,
                                                   float* __restrict__ out) {
  int g = blockIdx.x * 256 + threadIdx.x;
  if (g >= GG) return;
  float p = bo2[0];
  for (int c = 0; c < 128; c++) p = fmaf(h1[(size_t)g * 128 + c], Wo2[c], p);
  out[g] = p;
}

extern "C" void kernel_launch(void* const* d_in, const int* in_sizes, int n_in, void* d_out,
                              int out_size, void* d_ws, size_t ws_size, hipStream_t stream) {
  (void)n_in; (void)out_size; (void)ws_size;
  bool dict_order = (in_sizes[2] == NN);
  int IM, IE, IF[25];
  if (dict_order) {
    IM = 2; IE = 3;
    const int f[25] = {0, 1, 4, 5, 6, 7, 8, 9, 10, 11, 12, 13, 14, 15, 16, 17, 18,
                       19, 20, 21, 22, 23, 24, 25, 26};
    for (int k = 0; k < 25; k++) IF[k] = f[k];
  } else {
    IM = 25; IE = 26;
    for (int k = 0; k < 25; k++) IF[k] = k;
  }
  const int* m_idx = (const int*)d_in[IM];
  const int* eidx = (const int*)d_in[IE];
  float* out = (float*)d_out;
  const int* e_src = eidx;
  const int* e_dst = eidx + EE;

  const float* t = (const float*)d_in[IF[0]];
  const float* v = (const float*)d_in[IF[1]];
  const float* Wt = (const float*)d_in[IF[2]];     const float* bt = (const float*)d_in[IF[3]];
  const float* Wv = (const float*)d_in[IF[4]];     const float* bv = (const float*)d_in[IF[5]];
  const float* emb = (const float*)d_in[IF[6]];
  const float* Wnode = (const float*)d_in[IF[7]];  const float* bnode = (const float*)d_in[IF[8]];
  const float* Wstart = (const float*)d_in[IF[9]]; const float* bstart = (const float*)d_in[IF[10]];
  const float* ln_g = (const float*)d_in[IF[11]];  const float* ln_b = (const float*)d_in[IF[12]];
  const float* W1 = (const float*)d_in[IF[13]];
  const float* a_src1 = (const float*)d_in[IF[14]]; const float* a_dst1 = (const float*)d_in[IF[15]];
  const float* b1 = (const float*)d_in[IF[16]];
  const float* W2 = (const float*)d_in[IF[17]];
  const float* a_src2 = (const float*)d_in[IF[18]]; const float* a_dst2 = (const float*)d_in[IF[19]];
  const float* b2 = (const float*)d_in[IF[20]];
  const float* Wo1 = (const float*)d_in[IF[21]];   const float* bo1 = (const float*)d_in[IF[22]];
  const float* Wo2 = (const float*)d_in[IF[23]];   const float* bo2 = (const float*)d_in[IF[24]];

  // workspace layout (peak ~96 MB)
  char* w = (char*)d_ws;
  bf16* xp1b = (bf16*)(w);                           // [NN,512] bf16 [0,32) MB
  bf16* x0b = (bf16*)(w + ((size_t)32 << 20));       // [NN,128] bf16 [32,40) MB
  bf16* x1 = (bf16*)(w + ((size_t)48 << 20));        // [NN,512] bf16 [48,80) MB
  bf16* xp2b = (bf16*)(w);                           // [NN,128] bf16 [0,8)  (xp1b dead)
  float* x2 = (float*)(w + ((size_t)8 << 20));       // [NN,128] f32 [8,24)
  size_t so = (size_t)80 << 20;                      // smalls [80,~96) MB
  bf16* t_b = (bf16*)(w + so); so += 512 * 768 * 2;
  bf16* v_b = (bf16*)(w + so); so += 512 * 768 * 2;
  bf16* vt_b = (bf16*)(w + so); so += 512 * 256 * 2;
  bf16* start_b = (bf16*)(w + so); so += 512 * 128 * 2;
  bf16* emb2_b = (bf16*)(w + so); so += 51 * 128 * 2 + 256;
  float* als1 = (float*)(w + so); so += NN * 4 * 4;
  float* ald1 = (float*)(w + so); so += NN * 4 * 4;
  float* als2 = (float*)(w + so); so += NN * 4;
  float* ald2 = (float*)(w + so); so += NN * 4;
  float* aw1 = (float*)(w + so); so += EE * 4 * 4;   // 4 MB
  float* selfw1 = (float*)(w + so); so += NN * 4 * 4;
  float* inv1 = (float*)(w + so); so += NN * 4 * 4;
  float* aw2 = (float*)(w + so); so += EE * 4;       // 1 MB
  float* selfw2 = (float*)(w + so); so += NN * 4;
  float* inv2 = (float*)(w + so); so += NN * 4;
  float* pooled = (float*)(w + so); so += 512 * 128 * 4;
  float* h1 = (float*)(w + so); so += 512 * 128 * 4;
  int* indeg = (int*)(w + so); so += NN * 4;
  int* csroff = (int*)(w + so); so += (NN + 1) * 4 + 252;
  int* cursor = (int*)(w + so); so += NN * 4;
  int* esrc = (int*)(w + so); so += EE * 4;
  s8v* Bp1 = (s8v*)(w + so); so += 32 * 4 * 64 * 16;    // conv1 W1 frags
  s8v* Bp2 = (s8v*)(w + so); so += 8 * 16 * 64 * 16;    // conv2 W2 frags
  s8v* BpWv = (s8v*)(w + so); so += 8 * 24 * 64 * 16;   // Wv frags
  s8v* BpWt = (s8v*)(w + so); so += 8 * 24 * 64 * 16;   // Wt frags
  s8v* BpWs = (s8v*)(w + so); so += 8 * 8 * 64 * 16;    // Wstart frags

  // ---- CSR build ----
  hipMemsetAsync(indeg, 0, NN * 4, stream);
  hist_kernel<<<EE / 256, 256, 0, stream>>>(e_dst, indeg);
  scan_kernel<<<1, 1024, 0, stream>>>(indeg, csroff, cursor);
  fill_kernel<<<EE / 256, 256, 0, stream>>>(e_src, e_dst, cursor, esrc);

  // pack weights into MFMA fragment order
  packB_kernel<<<32, 256, 0, stream>>>(W1, 512, 128, Bp1);
  packB_kernel<<<32, 256, 0, stream>>>(W2, 128, 512, Bp2);
  packB_kernel<<<48, 256, 0, stream>>>(Wv, 128, 768, BpWv);
  packB_kernel<<<48, 256, 0, stream>>>(Wt, 128, 768, BpWt);
  packB_kernel<<<16, 256, 0, stream>>>(Wstart, 128, 256, BpWs);

  // convert t, v to bf16
  cvtpk_kernel<<<768, 256, 0, stream>>>((const float2*)t, (unsigned*)t_b, 512 * 384);
  cvtpk_kernel<<<768, 256, 0, stream>>>((const float2*)v, (unsigned*)v_b, 512 * 384);

  // emb2 (tiny), bf16 out
  sgemm_kernel<bf16><<<(51 * 128 + 63) / 64, 256, 0, stream>>>(emb, Wnode, bnode, emb2_b, 51, 128, 128, 128, 0);

  // ve/te/start via MFMA
  gemm_mfma<<<dim3(2, 8), 256, 0, stream>>>((const short*)v_b, BpWv, bv, (short*)vt_b, 512, 128, 768, 256);
  gemm_mfma<<<dim3(2, 8), 256, 0, stream>>>((const short*)t_b, BpWt, bt, (short*)(vt_b + 128), 512, 128, 768, 256);
  gemm_mfma<<<dim3(2, 8), 256, 0, stream>>>((const short*)vt_b, BpWs, bstart, (short*)start_b, 512, 128, 256, 128);
  ln_wave<<<NN / 4, 256, 0, stream>>>((const unsigned*)start_b, (const unsigned*)emb2_b, m_idx, ln_g, ln_b, (unsigned*)x0b);

  // conv1: MFMA GEMM (bf16 in/out)
  gemm_mfma<<<dim3(8, NN / 64), 256, 0, stream>>>((const short*)x0b, Bp1, nullptr, (short*)xp1b, NN, 512, 128, 512);
  al1_wave<<<NN, 256, 0, stream>>>((const unsigned*)xp1b, a_src1, a_dst1, als1, ald1);
  alpha1_kernel<<<NN * 4 / 256, 256, 0, stream>>>(als1, ald1, csroff, esrc, aw1, selfw1, inv1);
  agg1w_kernel<<<(int)(((long)NN * 128 + 255) / 256), 256, 0, stream>>>(
      (const uint2*)xp1b, aw1, selfw1, inv1, csroff, esrc, b1, (uint2*)x1);

  // conv2: MFMA GEMM (bf16 in/out)
  gemm_mfma<<<dim3(2, NN / 64), 256, 0, stream>>>((const short*)x1, Bp2, nullptr, (short*)xp2b, NN, 128, 512, 128);
  al2_wave<<<NN / 4, 256, 0, stream>>>((const unsigned*)xp2b, a_src2, a_dst2, als2, ald2);
  alpha2_kernel<<<NN / 256, 256, 0, stream>>>(als2, ald2, csroff, esrc, aw2, selfw2, inv2);
  agg2w_kernel<<<(int)(((long)NN * 32 + 255) / 256), 256, 0, stream>>>(
      (const uint2*)xp2b, aw2, selfw2, inv2, csroff, esrc, b2, (float4*)x2);

  pool_kernel<<<GG, 128, 0, stream>>>(x2, m_idx, pooled);
  sgemm_kernel<float><<<512 * 128 / 64, 256, 0, stream>>>(pooled, Wo1, bo1, h1, 512, 128, 128, 128, 1);
  head2_naive<<<(GG + 255) / 256, 256, 0, stream>>>(h1, Wo2, bo2, out);
}

// Round 15
// 379.118 us; speedup vs baseline: 6.5422x; 1.0644x over previous
//
#include <hip/hip_runtime.h>
#include <hip/hip_bf16.h>

typedef __hip_bfloat16 bf16;
typedef __attribute__((ext_vector_type(8))) short s8v;   // 8 bf16 (4 VGPRs)
typedef __attribute__((ext_vector_type(4))) float f4v;   // 4 fp32 acc

#define NN 32768   // total nodes
#define EE 262144  // edges
#define GG 512     // graphs

__device__ __forceinline__ float2 unpk(unsigned u) {
  float2 r;
  r.x = __uint_as_float(u << 16);
  r.y = __uint_as_float(u & 0xffff0000u);
  return r;
}
__device__ __forceinline__ unsigned pk(float x, float y) {
  union { bf16 h[2]; unsigned u; } p;
  p.h[0] = __float2bfloat16(x);
  p.h[1] = __float2bfloat16(y);
  return p.u;
}
__device__ __forceinline__ short f2bf_bits(float x) {
  bf16 h = __float2bfloat16(x);
  return *reinterpret_cast<short*>(&h);
}
__device__ __forceinline__ void storef(float* p, float v) { *p = v; }
__device__ __forceinline__ void storef(bf16* p, float v) { *p = __float2bfloat16(v); }

__device__ __forceinline__ float wred_sum(float v) {
#pragma unroll
  for (int o = 32; o; o >>= 1) v += __shfl_xor(v, o, 64);
  return v;
}

// ---------------- CSR build ----------------
__global__ __launch_bounds__(256) void hist_kernel(const int* __restrict__ dst,
                                                   int* __restrict__ indeg) {
  int e = blockIdx.x * 256 + threadIdx.x;
  if (e < EE) atomicAdd(&indeg[dst[e]], 1);
}

__global__ __launch_bounds__(1024) void scan_kernel(const int* __restrict__ indeg,
                                                    int* __restrict__ off,
                                                    int* __restrict__ cursor) {
  __shared__ int sh[1024];
  int t = threadIdx.x;
  int loc[32];
  int s = 0;
  int base = t * 32;
#pragma unroll
  for (int j = 0; j < 32; j++) { loc[j] = indeg[base + j]; s += loc[j]; }
  sh[t] = s;
  __syncthreads();
  for (int d = 1; d < 1024; d <<= 1) {
    int v = (t >= d) ? sh[t - d] : 0;
    __syncthreads();
    sh[t] += v;
    __syncthreads();
  }
  int run = (t == 0) ? 0 : sh[t - 1];
#pragma unroll
  for (int j = 0; j < 32; j++) { off[base + j] = run; cursor[base + j] = run; run += loc[j]; }
  if (t == 1023) off[NN] = run;
}

__global__ __launch_bounds__(256) void fill_kernel(const int* __restrict__ src,
                                                   const int* __restrict__ dst,
                                                   int* __restrict__ cursor,
                                                   int* __restrict__ esrc) {
  int e = blockIdx.x * 256 + threadIdx.x;
  if (e < EE) {
    int p = atomicAdd(&cursor[dst[e]], 1);
    esrc[p] = src[e];
  }
}

// ---------------- fp32 -> packed bf16 conversion (t and v in one launch) ----------------
__global__ __launch_bounds__(256) void cvtpk2_kernel(const float2* __restrict__ a,
                                                     unsigned* __restrict__ da,
                                                     const float2* __restrict__ b,
                                                     unsigned* __restrict__ db, int n2) {
  int id = blockIdx.x * 256 + threadIdx.x;
  if (id < n2) { float2 v = a[id]; da[id] = pk(v.x, v.y); }
  else if (id < 2 * n2) { int j = id - n2; float2 v = b[j]; db[j] = pk(v.x, v.y); }
}

// ---------------- small GEMM, split-K (tiny problems) ----------------
template <typename TC>
__global__ __launch_bounds__(256) void sgemm_kernel(const float* __restrict__ A,
                                                    const float* __restrict__ B,
                                                    const float* __restrict__ bias,
                                                    TC* __restrict__ C,
                                                    int M, int N, int K, int ldc, int act) {
  __shared__ float red[256];
  int tid = threadIdx.x;
  int lo = tid & 63;
  int slice = tid >> 6;
  long oid = (long)blockIdx.x * 64 + lo;
  bool live = (oid < (long)M * N);
  int m = 0, n = 0;
  if (live) { m = (int)(oid / N); n = (int)(oid % N); }
  int kq = K >> 2;
  int k0 = slice * kq, k1 = k0 + kq;
  float acc = 0.f;
  if (live) {
    const float* Ar = A + (size_t)m * K;
    for (int k = k0; k < k1; k++) acc = fmaf(Ar[k], B[(size_t)k * N + n], acc);
  }
  red[tid] = acc;
  __syncthreads();
  if (slice == 0 && live) {
    float v = red[lo] + red[64 + lo] + red[128 + lo] + red[192 + lo];
    if (bias) v += bias[n];
    if (act == 1) v = v > 0.f ? v : 0.01f * v;
    storef(&C[(size_t)m * ldc + n], v);
  }
}

// ---------------- pack all 5 weights into MFMA B-fragment order, one launch ----------------
__device__ __forceinline__ void packB_one(const float* W, int N, int K, int id, s8v* Bp) {
  int lane = id & 63;
  int tmp = id >> 6;
  int ksteps = K >> 5;
  int ks = tmp % ksteps;
  int nt = tmp / ksteps;
  int n = nt * 16 + (lane & 15);
  int kbase = ks * 32 + (lane >> 4) * 8;
  s8v r;
#pragma unroll
  for (int j = 0; j < 8; j++) r[j] = f2bf_bits(W[(size_t)(kbase + j) * N + n]);
  Bp[id] = r;
}

// blocks: [0,32) W1, [32,64) W2, [64,112) Wv, [112,160) Wt, [160,176) Wstart
__global__ __launch_bounds__(256) void packall_kernel(const float* __restrict__ W1, s8v* Bp1,
                                                      const float* __restrict__ W2, s8v* Bp2,
                                                      const float* __restrict__ Wv, s8v* BpWv,
                                                      const float* __restrict__ Wt, s8v* BpWt,
                                                      const float* __restrict__ Ws, s8v* BpWs) {
  int b = blockIdx.x;
  if (b < 32)        packB_one(W1, 512, 128, b * 256 + threadIdx.x, Bp1);
  else if (b < 64)   packB_one(W2, 128, 512, (b - 32) * 256 + threadIdx.x, Bp2);
  else if (b < 112)  packB_one(Wv, 128, 768, (b - 64) * 256 + threadIdx.x, BpWv);
  else if (b < 160)  packB_one(Wt, 128, 768, (b - 112) * 256 + threadIdx.x, BpWt);
  else               packB_one(Ws, 128, 256, (b - 160) * 256 + threadIdx.x, BpWs);
}

// ---------------- MFMA bf16 GEMM, optional fp32 bias, bf16 out with ldc ----------------
__global__ __launch_bounds__(256) void gemm_mfma(const short* __restrict__ A,
                                                 const s8v* __restrict__ Bp,
                                                 const float* __restrict__ bias,
                                                 short* __restrict__ C,
                                                 int M, int N, int K, int ldc) {
  __shared__ short lds[64 * 64];
  int tid = threadIdx.x;
  int wv = tid >> 6, lane = tid & 63;
  int quad = lane >> 4, l16 = lane & 15;
  int brow = blockIdx.y * 64, bcol = blockIdx.x * 64;
  int m = brow + wv * 16 + l16;
  int ksteps = K >> 5;
  f4v acc[4] = {};
  const s8v* Arow = (const s8v*)(A + (size_t)m * K);
  for (int ks = 0; ks < ksteps; ks++) {
    s8v a = Arow[ks * 4 + quad];
#pragma unroll
    for (int nt = 0; nt < 4; nt++) {
      s8v b = Bp[(size_t)(((bcol >> 4) + nt) * ksteps + ks) * 64 + lane];
      acc[nt] = __builtin_amdgcn_mfma_f32_16x16x32_bf16(a, b, acc[nt], 0, 0, 0);
    }
  }
#pragma unroll
  for (int nt = 0; nt < 4; nt++) {
    float bv = bias ? bias[bcol + nt * 16 + l16] : 0.f;
#pragma unroll
    for (int r = 0; r < 4; r++)
      lds[(wv * 16 + quad * 4 + r) * 64 + nt * 16 + l16] = f2bf_bits(acc[nt][r] + bv);
  }
  __syncthreads();
#pragma unroll
  for (int rep = 0; rep < 2; rep++) {
    int idx = rep * 256 + tid;
    int row = idx >> 3, c16 = idx & 7;
    uint4 val = ((const uint4*)lds)[idx];
    *(uint4*)(C + (size_t)(brow + row) * ldc + bcol + c16 * 8) = val;
  }
}

// ---------------- layernorm, wave per node; bf16 in -> packed bf16 out ----------------
__global__ __launch_bounds__(256) void ln_wave(const unsigned* __restrict__ start_b,
                                               const unsigned* __restrict__ emb2_b,
                                               const int* __restrict__ m_idx,
                                               const float* __restrict__ lng,
                                               const float* __restrict__ lnb,
                                               unsigned* __restrict__ x0b) {
  int i = blockIdx.x * 4 + (threadIdx.x >> 6);
  int lane = threadIdx.x & 63;
  int g = i >> 6, n = i & 63;
  const unsigned* row = (n == 0) ? (start_b + (size_t)g * 64) : (emb2_b + (size_t)m_idx[i] * 64);
  float2 v = unpk(row[lane]);
  float mu = wred_sum(v.x + v.y) * (1.f / 128.f);
  float dx = v.x - mu, dy = v.y - mu;
  float var = wred_sum(dx * dx + dy * dy) * (1.f / 128.f);
  float rstd = rsqrtf(var + 1e-6f);
  float2 gg = ((const float2*)lng)[lane];
  float2 bb = ((const float2*)lnb)[lane];
  x0b[(size_t)i * 64 + lane] = pk(dx * rstd * gg.x + bb.x, dy * rstd * gg.y + bb.y);
}

// ---------------- attention coefficients, wave per (node,head), xp bf16 ----------------
__global__ __launch_bounds__(256) void al1_wave(const unsigned* __restrict__ xp,
                                                const float* __restrict__ a_src,
                                                const float* __restrict__ a_dst,
                                                float* __restrict__ als,
                                                float* __restrict__ ald) {
  int id = blockIdx.x * 4 + (threadIdx.x >> 6);
  int lane = threadIdx.x & 63;
  int i = id >> 2, h = id & 3;
  float2 x = unpk(xp[(size_t)i * 256 + h * 64 + lane]);
  float2 as = ((const float2*)(a_src + h * 128))[lane];
  float2 ad = ((const float2*)(a_dst + h * 128))[lane];
  float ps = wred_sum(x.x * as.x + x.y * as.y);
  float pd = wred_sum(x.x * ad.x + x.y * ad.y);
  if (lane == 0) { als[id] = ps; ald[id] = pd; }
}

__global__ __launch_bounds__(256) void al2_wave(const unsigned* __restrict__ xp,
                                                const float* __restrict__ a_src,
                                                const float* __restrict__ a_dst,
                                                float* __restrict__ als,
                                                float* __restrict__ ald) {
  int i = blockIdx.x * 4 + (threadIdx.x >> 6);
  int lane = threadIdx.x & 63;
  float2 x = unpk(xp[(size_t)i * 64 + lane]);
  float2 as = ((const float2*)a_src)[lane];
  float2 ad = ((const float2*)a_dst)[lane];
  float ps = wred_sum(x.x * as.x + x.y * as.y);
  float pd = wred_sum(x.x * ad.x + x.y * ad.y);
  if (lane == 0) { als[i] = ps; ald[i] = pd; }
}

// ---------------- softmax weights ----------------
__global__ __launch_bounds__(256) void alpha1_kernel(const float* __restrict__ als,
                                                     const float* __restrict__ ald,
                                                     const int* __restrict__ off,
                                                     const int* __restrict__ esrc,
                                                     float* __restrict__ aw,
                                                     float* __restrict__ selfw,
                                                     float* __restrict__ inv) {
  int id = blockIdx.x * 256 + threadIdx.x;
  if (id >= NN * 4) return;
  int i = id >> 2, h = id & 3;
  float adi = ald[id];
  float selfSc = als[id] + adi;
  selfSc = selfSc > 0.f ? selfSc : 0.2f * selfSc;
  int s0 = off[i], s1 = off[i + 1];
  float m = selfSc;
  for (int e = s0; e < s1; e++) {
    float sc = als[esrc[e] * 4 + h] + adi;
    sc = sc > 0.f ? sc : 0.2f * sc;
    m = fmaxf(m, sc);
  }
  float sw = __expf(selfSc - m);
  float denom = sw;
  for (int e = s0; e < s1; e++) {
    float sc = als[esrc[e] * 4 + h] + adi;
    sc = sc > 0.f ? sc : 0.2f * sc;
    float w = __expf(sc - m);
    aw[e * 4 + h] = w;
    denom += w;
  }
  selfw[id] = sw;
  inv[id] = 1.f / denom;
}

__global__ __launch_bounds__(256) void alpha2_kernel(const float* __restrict__ als,
                                                     const float* __restrict__ ald,
                                                     const int* __restrict__ off,
                                                     const int* __restrict__ esrc,
                                                     float* __restrict__ aw,
                                                     float* __restrict__ selfw,
                                                     float* __restrict__ inv) {
  int i = blockIdx.x * 256 + threadIdx.x;
  if (i >= NN) return;
  float adi = ald[i];
  float selfSc = als[i] + adi;
  selfSc = selfSc > 0.f ? selfSc : 0.2f * selfSc;
  int s0 = off[i], s1 = off[i + 1];
  float m = selfSc;
  for (int e = s0; e < s1; e++) {
    float sc = als[esrc[e]] + adi;
    sc = sc > 0.f ? sc : 0.2f * sc;
    m = fmaxf(m, sc);
  }
  float sw = __expf(selfSc - m);
  float denom = sw;
  for (int e = s0; e < s1; e++) {
    float sc = als[esrc[e]] + adi;
    sc = sc > 0.f ? sc : 0.2f * sc;
    float w = __expf(sc - m);
    aw[e] = w;
    denom += w;
  }
  selfw[i] = sw;
  inv[i] = 1.f / denom;
}

// ---------------- weighted gather, conv1: thread per (node, uint4 = 8 cols) ----------------
__global__ __launch_bounds__(256) void agg1w_kernel(const uint4* __restrict__ xp,
                                                    const float* __restrict__ aw,
                                                    const float* __restrict__ selfw,
                                                    const float* __restrict__ inv,
                                                    const int* __restrict__ off,
                                                    const int* __restrict__ esrc,
                                                    const float* __restrict__ b1,
                                                    uint4* __restrict__ x1) {
  long gid = (long)blockIdx.x * 256 + threadIdx.x;
  if (gid >= (long)NN * 64) return;
  int i = (int)(gid >> 6), c8 = (int)(gid & 63), h = c8 >> 4;
  float sw = selfw[i * 4 + h];
  float iv = inv[i * 4 + h];
  uint4 xv = xp[(size_t)i * 64 + c8];
  float2 p0 = unpk(xv.x), p1 = unpk(xv.y), p2 = unpk(xv.z), p3 = unpk(xv.w);
  float a0 = sw * p0.x, a1 = sw * p0.y, a2 = sw * p1.x, a3 = sw * p1.y;
  float a4 = sw * p2.x, a5 = sw * p2.y, a6 = sw * p3.x, a7 = sw * p3.y;
  int s0 = off[i], s1 = off[i + 1];
  int e = s0;
  for (; e + 1 < s1; e += 2) {
    int sA = esrc[e], sB = esrc[e + 1];
    float wA = aw[e * 4 + h], wB = aw[(e + 1) * 4 + h];
    uint4 mA = xp[(size_t)sA * 64 + c8];
    uint4 mB = xp[(size_t)sB * 64 + c8];
    float2 q0 = unpk(mA.x), q1 = unpk(mA.y), q2 = unpk(mA.z), q3 = unpk(mA.w);
    a0 = fmaf(wA, q0.x, a0); a1 = fmaf(wA, q0.y, a1);
    a2 = fmaf(wA, q1.x, a2); a3 = fmaf(wA, q1.y, a3);
    a4 = fmaf(wA, q2.x, a4); a5 = fmaf(wA, q2.y, a5);
    a6 = fmaf(wA, q3.x, a6); a7 = fmaf(wA, q3.y, a7);
    q0 = unpk(mB.x); q1 = unpk(mB.y); q2 = unpk(mB.z); q3 = unpk(mB.w);
    a0 = fmaf(wB, q0.x, a0); a1 = fmaf(wB, q0.y, a1);
    a2 = fmaf(wB, q1.x, a2); a3 = fmaf(wB, q1.y, a3);
    a4 = fmaf(wB, q2.x, a4); a5 = fmaf(wB, q2.y, a5);
    a6 = fmaf(wB, q3.x, a6); a7 = fmaf(wB, q3.y, a7);
  }
  if (e < s1) {
    int sA = esrc[e];
    float wA = aw[e * 4 + h];
    uint4 mA = xp[(size_t)sA * 64 + c8];
    float2 q0 = unpk(mA.x), q1 = unpk(mA.y), q2 = unpk(mA.z), q3 = unpk(mA.w);
    a0 = fmaf(wA, q0.x, a0); a1 = fmaf(wA, q0.y, a1);
    a2 = fmaf(wA, q1.x, a2); a3 = fmaf(wA, q1.y, a3);
    a4 = fmaf(wA, q2.x, a4); a5 = fmaf(wA, q2.y, a5);
    a6 = fmaf(wA, q3.x, a6); a7 = fmaf(wA, q3.y, a7);
  }
  float4 bb0 = ((const float4*)b1)[c8 * 2];
  float4 bb1 = ((const float4*)b1)[c8 * 2 + 1];
  a0 = a0 * iv + bb0.x; a1 = a1 * iv + bb0.y; a2 = a2 * iv + bb0.z; a3 = a3 * iv + bb0.w;
  a4 = a4 * iv + bb1.x; a5 = a5 * iv + bb1.y; a6 = a6 * iv + bb1.z; a7 = a7 * iv + bb1.w;
  a0 = a0 > 0.f ? a0 : (__expf(a0) - 1.f);
  a1 = a1 > 0.f ? a1 : (__expf(a1) - 1.f);
  a2 = a2 > 0.f ? a2 : (__expf(a2) - 1.f);
  a3 = a3 > 0.f ? a3 : (__expf(a3) - 1.f);
  a4 = a4 > 0.f ? a4 : (__expf(a4) - 1.f);
  a5 = a5 > 0.f ? a5 : (__expf(a5) - 1.f);
  a6 = a6 > 0.f ? a6 : (__expf(a6) - 1.f);
  a7 = a7 > 0.f ? a7 : (__expf(a7) - 1.f);
  uint4 o;
  o.x = pk(a0, a1); o.y = pk(a2, a3); o.z = pk(a4, a5); o.w = pk(a6, a7);
  x1[gid] = o;
}

// ---------------- weighted gather, conv2: thread per (node, uint4 = 8 cols) ----------------
__global__ __launch_bounds__(256) void agg2w_kernel(const uint4* __restrict__ xp,
                                                    const float* __restrict__ aw,
                                                    const float* __restrict__ selfw,
                                                    const float* __restrict__ inv,
                                                    const int* __restrict__ off,
                                                    const int* __restrict__ esrc,
                                                    const float* __restrict__ b2,
                                                    float4* __restrict__ x2) {
  long gid = (long)blockIdx.x * 256 + threadIdx.x;
  if (gid >= (long)NN * 16) return;
  int i = (int)(gid >> 4), c8 = (int)(gid & 15);
  float sw = selfw[i];
  float iv = inv[i];
  uint4 xv = xp[(size_t)i * 16 + c8];
  float2 p0 = unpk(xv.x), p1 = unpk(xv.y), p2 = unpk(xv.z), p3 = unpk(xv.w);
  float a0 = sw * p0.x, a1 = sw * p0.y, a2 = sw * p1.x, a3 = sw * p1.y;
  float a4 = sw * p2.x, a5 = sw * p2.y, a6 = sw * p3.x, a7 = sw * p3.y;
  int s0 = off[i], s1 = off[i + 1];
  int e = s0;
  for (; e + 1 < s1; e += 2) {
    int sA = esrc[e], sB = esrc[e + 1];
    float wA = aw[e], wB = aw[e + 1];
    uint4 mA = xp[(size_t)sA * 16 + c8];
    uint4 mB = xp[(size_t)sB * 16 + c8];
    float2 q0 = unpk(mA.x), q1 = unpk(mA.y), q2 = unpk(mA.z), q3 = unpk(mA.w);
    a0 = fmaf(wA, q0.x, a0); a1 = fmaf(wA, q0.y, a1);
    a2 = fmaf(wA, q1.x, a2); a3 = fmaf(wA, q1.y, a3);
    a4 = fmaf(wA, q2.x, a4); a5 = fmaf(wA, q2.y, a5);
    a6 = fmaf(wA, q3.x, a6); a7 = fmaf(wA, q3.y, a7);
    q0 = unpk(mB.x); q1 = unpk(mB.y); q2 = unpk(mB.z); q3 = unpk(mB.w);
    a0 = fmaf(wB, q0.x, a0); a1 = fmaf(wB, q0.y, a1);
    a2 = fmaf(wB, q1.x, a2); a3 = fmaf(wB, q1.y, a3);
    a4 = fmaf(wB, q2.x, a4); a5 = fmaf(wB, q2.y, a5);
    a6 = fmaf(wB, q3.x, a6); a7 = fmaf(wB, q3.y, a7);
  }
  if (e < s1) {
    int sA = esrc[e];
    float wA = aw[e];
    uint4 mA = xp[(size_t)sA * 16 + c8];
    float2 q0 = unpk(mA.x), q1 = unpk(mA.y), q2 = unpk(mA.z), q3 = unpk(mA.w);
    a0 = fmaf(wA, q0.x, a0); a1 = fmaf(wA, q0.y, a1);
    a2 = fmaf(wA, q1.x, a2); a3 = fmaf(wA, q1.y, a3);
    a4 = fmaf(wA, q2.x, a4); a5 = fmaf(wA, q2.y, a5);
    a6 = fmaf(wA, q3.x, a6); a7 = fmaf(wA, q3.y, a7);
  }
  float4 bb0 = ((const float4*)b2)[c8 * 2];
  float4 bb1 = ((const float4*)b2)[c8 * 2 + 1];
  a0 = a0 * iv + bb0.x; a1 = a1 * iv + bb0.y; a2 = a2 * iv + bb0.z; a3 = a3 * iv + bb0.w;
  a4 = a4 * iv + bb1.x; a5 = a5 * iv + bb1.y; a6 = a6 * iv + bb1.z; a7 = a7 * iv + bb1.w;
  a0 = a0 > 0.f ? a0 : (__expf(a0) - 1.f);
  a1 = a1 > 0.f ? a1 : (__expf(a1) - 1.f);
  a2 = a2 > 0.f ? a2 : (__expf(a2) - 1.f);
  a3 = a3 > 0.f ? a3 : (__expf(a3) - 1.f);
  a4 = a4 > 0.f ? a4 : (__expf(a4) - 1.f);
  a5 = a5 > 0.f ? a5 : (__expf(a5) - 1.f);
  a6 = a6 > 0.f ? a6 : (__expf(a6) - 1.f);
  a7 = a7 > 0.f ? a7 : (__expf(a7) - 1.f);
  x2[gid * 2] = make_float4(a0, a1, a2, a3);
  x2[gid * 2 + 1] = make_float4(a4, a5, a6, a7);
}

// ---------------- masked mean pool ----------------
__global__ __launch_bounds__(128) void pool_kernel(const float* __restrict__ x2,
                                                   const int* __restrict__ m_idx,
                                                   float* __restrict__ pooled) {
  int g = blockIdx.x, c = threadIdx.x;
  float acc = 0.f, cnt = 0.f;
  const float* xr = x2 + (size_t)g * 64 * 128;
  const int* mi = m_idx + g * 64;
  for (int n = 0; n < 64; n++) {
    if (mi[n] >= 1) { cnt += 1.f; acc += xr[n * 128 + c]; }
  }
  pooled[(size_t)g * 128 + c] = acc / cnt;
}

// ---------------- final logit ----------------
__global__ __launch_bounds__(256) void head2_naive(const float* __restrict__ h1,
                                                   const float* __restrict__ Wo2,
                                                   const float* __restrict__ bo2,
                                                   float* __restrict__ out) {
  int g = blockIdx.x * 256 + threadIdx.x;
  if (g >= GG) return;
  float p = bo2[0];
  for (int c = 0; c < 128; c++) p = fmaf(h1[(size_t)g * 128 + c], Wo2[c], p);
  out[g] = p;
}

extern "C" void kernel_launch(void* const* d_in, const int* in_sizes, int n_in, void* d_out,
                              int out_size, void* d_ws, size_t ws_size, hipStream_t stream) {
  (void)n_in; (void)out_size; (void)ws_size;
  bool dict_order = (in_sizes[2] == NN);
  int IM, IE, IF[25];
  if (dict_order) {
    IM = 2; IE = 3;
    const int f[25] = {0, 1, 4, 5, 6, 7, 8, 9, 10, 11, 12, 13, 14, 15, 16, 17, 18,
                       19, 20, 21, 22, 23, 24, 25, 26};
    for (int k = 0; k < 25; k++) IF[k] = f[k];
  } else {
    IM = 25; IE = 26;
    for (int k = 0; k < 25; k++) IF[k] = k;
  }
  const int* m_idx = (const int*)d_in[IM];
  const int* eidx = (const int*)d_in[IE];
  float* out = (float*)d_out;
  const int* e_src = eidx;
  const int* e_dst = eidx + EE;

  const float* t = (const float*)d_in[IF[0]];
  const float* v = (const float*)d_in[IF[1]];
  const float* Wt = (const float*)d_in[IF[2]];     const float* bt = (const float*)d_in[IF[3]];
  const float* Wv = (const float*)d_in[IF[4]];     const float* bv = (const float*)d_in[IF[5]];
  const float* emb = (const float*)d_in[IF[6]];
  const float* Wnode = (const float*)d_in[IF[7]];  const float* bnode = (const float*)d_in[IF[8]];
  const float* Wstart = (const float*)d_in[IF[9]]; const float* bstart = (const float*)d_in[IF[10]];
  const float* ln_g = (const float*)d_in[IF[11]];  const float* ln_b = (const float*)d_in[IF[12]];
  const float* W1 = (const float*)d_in[IF[13]];
  const float* a_src1 = (const float*)d_in[IF[14]]; const float* a_dst1 = (const float*)d_in[IF[15]];
  const float* b1 = (const float*)d_in[IF[16]];
  const float* W2 = (const float*)d_in[IF[17]];
  const float* a_src2 = (const float*)d_in[IF[18]]; const float* a_dst2 = (const float*)d_in[IF[19]];
  const float* b2 = (const float*)d_in[IF[20]];
  const float* Wo1 = (const float*)d_in[IF[21]];   const float* bo1 = (const float*)d_in[IF[22]];
  const float* Wo2 = (const float*)d_in[IF[23]];   const float* bo2 = (const float*)d_in[IF[24]];

  // workspace layout (peak ~96 MB)
  char* w = (char*)d_ws;
  bf16* xp1b = (bf16*)(w);                           // [NN,512] bf16 [0,32) MB
  bf16* x0b = (bf16*)(w + ((size_t)32 << 20));       // [NN,128] bf16 [32,40) MB
  bf16* x1 = (bf16*)(w + ((size_t)48 << 20));        // [NN,512] bf16 [48,80) MB
  bf16* xp2b = (bf16*)(w);                           // [NN,128] bf16 [0,8)  (xp1b dead)
  float* x2 = (float*)(w + ((size_t)8 << 20));       // [NN,128] f32 [8,24)
  size_t so = (size_t)80 << 20;                      // smalls [80,~96) MB
  bf16* t_b = (bf16*)(w + so); so += 512 * 768 * 2;
  bf16* v_b = (bf16*)(w + so); so += 512 * 768 * 2;
  bf16* vt_b = (bf16*)(w + so); so += 512 * 256 * 2;
  bf16* start_b = (bf16*)(w + so); so += 512 * 128 * 2;
  bf16* emb2_b = (bf16*)(w + so); so += 51 * 128 * 2 + 256;
  float* als1 = (float*)(w + so); so += NN * 4 * 4;
  float* ald1 = (float*)(w + so); so += NN * 4 * 4;
  float* als2 = (float*)(w + so); so += NN * 4;
  float* ald2 = (float*)(w + so); so += NN * 4;
  float* aw1 = (float*)(w + so); so += EE * 4 * 4;   // 4 MB
  float* selfw1 = (float*)(w + so); so += NN * 4 * 4;
  float* inv1 = (float*)(w + so); so += NN * 4 * 4;
  float* aw2 = (float*)(w + so); so += EE * 4;       // 1 MB
  float* selfw2 = (float*)(w + so); so += NN * 4;
  float* inv2 = (float*)(w + so); so += NN * 4;
  float* pooled = (float*)(w + so); so += 512 * 128 * 4;
  float* h1 = (float*)(w + so); so += 512 * 128 * 4;
  int* indeg = (int*)(w + so); so += NN * 4;
  int* csroff = (int*)(w + so); so += (NN + 1) * 4 + 252;
  int* cursor = (int*)(w + so); so += NN * 4;
  int* esrc = (int*)(w + so); so += EE * 4;
  s8v* Bp1 = (s8v*)(w + so); so += 32 * 4 * 64 * 16;    // conv1 W1 frags
  s8v* Bp2 = (s8v*)(w + so); so += 8 * 16 * 64 * 16;    // conv2 W2 frags
  s8v* BpWv = (s8v*)(w + so); so += 8 * 24 * 64 * 16;   // Wv frags
  s8v* BpWt = (s8v*)(w + so); so += 8 * 24 * 64 * 16;   // Wt frags
  s8v* BpWs = (s8v*)(w + so); so += 8 * 8 * 64 * 16;    // Wstart frags

  // ---- CSR build ----
  hipMemsetAsync(indeg, 0, NN * 4, stream);
  hist_kernel<<<EE / 256, 256, 0, stream>>>(e_dst, indeg);
  scan_kernel<<<1, 1024, 0, stream>>>(indeg, csroff, cursor);
  fill_kernel<<<EE / 256, 256, 0, stream>>>(e_src, e_dst, cursor, esrc);

  // pack all weights + convert t,v (merged launches)
  packall_kernel<<<176, 256, 0, stream>>>(W1, Bp1, W2, Bp2, Wv, BpWv, Wt, BpWt, Wstart, BpWs);
  cvtpk2_kernel<<<1536, 256, 0, stream>>>((const float2*)t, (unsigned*)t_b,
                                          (const float2*)v, (unsigned*)v_b, 512 * 384);

  // emb2 (tiny), bf16 out
  sgemm_kernel<bf16><<<(51 * 128 + 63) / 64, 256, 0, stream>>>(emb, Wnode, bnode, emb2_b, 51, 128, 128, 128, 0);

  // ve/te/start via MFMA
  gemm_mfma<<<dim3(2, 8), 256, 0, stream>>>((const short*)v_b, BpWv, bv, (short*)vt_b, 512, 128, 768, 256);
  gemm_mfma<<<dim3(2, 8), 256, 0, stream>>>((const short*)t_b, BpWt, bt, (short*)(vt_b + 128), 512, 128, 768, 256);
  gemm_mfma<<<dim3(2, 8), 256, 0, stream>>>((const short*)vt_b, BpWs, bstart, (short*)start_b, 512, 128, 256, 128);
  ln_wave<<<NN / 4, 256, 0, stream>>>((const unsigned*)start_b, (const unsigned*)emb2_b, m_idx, ln_g, ln_b, (unsigned*)x0b);

  // conv1: MFMA GEMM (bf16 in/out)
  gemm_mfma<<<dim3(8, NN / 64), 256, 0, stream>>>((const short*)x0b, Bp1, nullptr, (short*)xp1b, NN, 512, 128, 512);
  al1_wave<<<NN, 256, 0, stream>>>((const unsigned*)xp1b, a_src1, a_dst1, als1, ald1);
  alpha1_kernel<<<NN * 4 / 256, 256, 0, stream>>>(als1, ald1, csroff, esrc, aw1, selfw1, inv1);
  agg1w_kernel<<<(int)(((long)NN * 64 + 255) / 256), 256, 0, stream>>>(
      (const uint4*)xp1b, aw1, selfw1, inv1, csroff, esrc, b1, (uint4*)x1);

  // conv2: MFMA GEMM (bf16 in/out)
  gemm_mfma<<<dim3(2, NN / 64), 256, 0, stream>>>((const short*)x1, Bp2, nullptr, (short*)xp2b, NN, 128, 512, 128);
  al2_wave<<<NN / 4, 256, 0, stream>>>((const unsigned*)xp2b, a_src2, a_dst2, als2, ald2);
  alpha2_kernel<<<NN / 256, 256, 0, stream>>>(als2, ald2, csroff, esrc, aw2, selfw2, inv2);
  agg2w_kernel<<<(int)(((long)NN * 16 + 255) / 256), 256, 0, stream>>>(
      (const uint4*)xp2b, aw2, selfw2, inv2, csroff, esrc, b2, (float4*)x2);

  pool_kernel<<<GG, 128, 0, stream>>>(x2, m_idx, pooled);
  sgemm_kernel<float><<<512 * 128 / 64, 256, 0, stream>>>(pooled, Wo1, bo1, h1, 512, 128, 128, 128, 1);
  head2_naive<<<(GG + 255) / 256, 256, 0, stream>>>(h1, Wo2, bo2, out);
}

// Round 16
// 365.000 us; speedup vs baseline: 6.7952x; 1.0387x over previous
//
#include <hip/hip_runtime.h>
#include <hip/hip_bf16.h>

typedef __hip_bfloat16 bf16;
typedef __attribute__((ext_vector_type(8))) short s8v;   // 8 bf16 (4 VGPRs)
typedef __attribute__((ext_vector_type(4))) float f4v;   // 4 fp32 acc

#define NN 32768   // total nodes
#define EE 262144  // edges
#define GG 512     // graphs

__device__ __forceinline__ float2 unpk(unsigned u) {
  float2 r;
  r.x = __uint_as_float(u << 16);
  r.y = __uint_as_float(u & 0xffff0000u);
  return r;
}
__device__ __forceinline__ unsigned pk(float x, float y) {
  union { bf16 h[2]; unsigned u; } p;
  p.h[0] = __float2bfloat16(x);
  p.h[1] = __float2bfloat16(y);
  return p.u;
}
__device__ __forceinline__ short f2bf_bits(float x) {
  bf16 h = __float2bfloat16(x);
  return *reinterpret_cast<short*>(&h);
}
__device__ __forceinline__ void storef(float* p, float v) { *p = v; }
__device__ __forceinline__ void storef(bf16* p, float v) { *p = __float2bfloat16(v); }

__device__ __forceinline__ float wred_sum(float v) {
#pragma unroll
  for (int o = 32; o; o >>= 1) v += __shfl_xor(v, o, 64);
  return v;
}

// ---------------- CSR build ----------------
__global__ __launch_bounds__(256) void hist_kernel(const int* __restrict__ dst,
                                                   int* __restrict__ indeg) {
  int e = blockIdx.x * 256 + threadIdx.x;
  if (e < EE) atomicAdd(&indeg[dst[e]], 1);
}

__global__ __launch_bounds__(1024) void scan_kernel(const int* __restrict__ indeg,
                                                    int* __restrict__ off,
                                                    int* __restrict__ cursor) {
  __shared__ int sh[1024];
  int t = threadIdx.x;
  int loc[32];
  int s = 0;
  int base = t * 32;
#pragma unroll
  for (int j = 0; j < 32; j++) { loc[j] = indeg[base + j]; s += loc[j]; }
  sh[t] = s;
  __syncthreads();
  for (int d = 1; d < 1024; d <<= 1) {
    int v = (t >= d) ? sh[t - d] : 0;
    __syncthreads();
    sh[t] += v;
    __syncthreads();
  }
  int run = (t == 0) ? 0 : sh[t - 1];
#pragma unroll
  for (int j = 0; j < 32; j++) { off[base + j] = run; cursor[base + j] = run; run += loc[j]; }
  if (t == 1023) off[NN] = run;
}

__global__ __launch_bounds__(256) void fill_kernel(const int* __restrict__ src,
                                                   const int* __restrict__ dst,
                                                   int* __restrict__ cursor,
                                                   int* __restrict__ esrc) {
  int e = blockIdx.x * 256 + threadIdx.x;
  if (e < EE) {
    int p = atomicAdd(&cursor[dst[e]], 1);
    esrc[p] = src[e];
  }
}

// ---------------- fp32 -> packed bf16 conversion (t and v in one launch) ----------------
__global__ __launch_bounds__(256) void cvtpk2_kernel(const float2* __restrict__ a,
                                                     unsigned* __restrict__ da,
                                                     const float2* __restrict__ b,
                                                     unsigned* __restrict__ db, int n2) {
  int id = blockIdx.x * 256 + threadIdx.x;
  if (id < n2) { float2 v = a[id]; da[id] = pk(v.x, v.y); }
  else if (id < 2 * n2) { int j = id - n2; float2 v = b[j]; db[j] = pk(v.x, v.y); }
}

// ---------------- small GEMM, split-K (tiny problems) ----------------
template <typename TC>
__global__ __launch_bounds__(256) void sgemm_kernel(const float* __restrict__ A,
                                                    const float* __restrict__ B,
                                                    const float* __restrict__ bias,
                                                    TC* __restrict__ C,
                                                    int M, int N, int K, int ldc, int act) {
  __shared__ float red[256];
  int tid = threadIdx.x;
  int lo = tid & 63;
  int slice = tid >> 6;
  long oid = (long)blockIdx.x * 64 + lo;
  bool live = (oid < (long)M * N);
  int m = 0, n = 0;
  if (live) { m = (int)(oid / N); n = (int)(oid % N); }
  int kq = K >> 2;
  int k0 = slice * kq, k1 = k0 + kq;
  float acc = 0.f;
  if (live) {
    const float* Ar = A + (size_t)m * K;
    for (int k = k0; k < k1; k++) acc = fmaf(Ar[k], B[(size_t)k * N + n], acc);
  }
  red[tid] = acc;
  __syncthreads();
  if (slice == 0 && live) {
    float v = red[lo] + red[64 + lo] + red[128 + lo] + red[192 + lo];
    if (bias) v += bias[n];
    if (act == 1) v = v > 0.f ? v : 0.01f * v;
    storef(&C[(size_t)m * ldc + n], v);
  }
}

// ---------------- pack all 5 weights into MFMA B-fragment order, one launch ----------------
__device__ __forceinline__ void packB_one(const float* W, int N, int K, int id, s8v* Bp) {
  int lane = id & 63;
  int tmp = id >> 6;
  int ksteps = K >> 5;
  int ks = tmp % ksteps;
  int nt = tmp / ksteps;
  int n = nt * 16 + (lane & 15);
  int kbase = ks * 32 + (lane >> 4) * 8;
  s8v r;
#pragma unroll
  for (int j = 0; j < 8; j++) r[j] = f2bf_bits(W[(size_t)(kbase + j) * N + n]);
  Bp[id] = r;
}

// blocks: [0,32) W1, [32,64) W2, [64,112) Wv, [112,160) Wt, [160,176) Wstart
__global__ __launch_bounds__(256) void packall_kernel(const float* __restrict__ W1, s8v* Bp1,
                                                      const float* __restrict__ W2, s8v* Bp2,
                                                      const float* __restrict__ Wv, s8v* BpWv,
                                                      const float* __restrict__ Wt, s8v* BpWt,
                                                      const float* __restrict__ Ws, s8v* BpWs) {
  int b = blockIdx.x;
  if (b < 32)        packB_one(W1, 512, 128, b * 256 + threadIdx.x, Bp1);
  else if (b < 64)   packB_one(W2, 128, 512, (b - 32) * 256 + threadIdx.x, Bp2);
  else if (b < 112)  packB_one(Wv, 128, 768, (b - 64) * 256 + threadIdx.x, BpWv);
  else if (b < 160)  packB_one(Wt, 128, 768, (b - 112) * 256 + threadIdx.x, BpWt);
  else               packB_one(Ws, 128, 256, (b - 160) * 256 + threadIdx.x, BpWs);
}

// ---------------- fold a_src/a_dst through W1: ws1[h*128+k] = sum_c W1[k,h*128+c]*a[h,c] ----------------
__global__ __launch_bounds__(256) void fold1_kernel(const float* __restrict__ W1,
                                                    const float* __restrict__ a_src1,
                                                    const float* __restrict__ a_dst1,
                                                    float* __restrict__ ws1,
                                                    float* __restrict__ wd1) {
  int id = blockIdx.x * 256 + threadIdx.x;
  if (id >= 512) return;
  int h = id >> 7, k = id & 127;
  float s = 0.f, d = 0.f;
  for (int c = 0; c < 128; c++) {
    float w = W1[(size_t)k * 512 + h * 128 + c];
    s = fmaf(w, a_src1[h * 128 + c], s);
    d = fmaf(w, a_dst1[h * 128 + c], d);
  }
  ws1[id] = s;
  wd1[id] = d;
}

// ---------------- MFMA bf16 GEMM, optional fp32 bias, bf16 out with ldc ----------------
__global__ __launch_bounds__(256) void gemm_mfma(const short* __restrict__ A,
                                                 const s8v* __restrict__ Bp,
                                                 const float* __restrict__ bias,
                                                 short* __restrict__ C,
                                                 int M, int N, int K, int ldc) {
  __shared__ short lds[64 * 64];
  int tid = threadIdx.x;
  int wv = tid >> 6, lane = tid & 63;
  int quad = lane >> 4, l16 = lane & 15;
  int brow = blockIdx.y * 64, bcol = blockIdx.x * 64;
  int m = brow + wv * 16 + l16;
  int ksteps = K >> 5;
  f4v acc[4] = {};
  const s8v* Arow = (const s8v*)(A + (size_t)m * K);
  for (int ks = 0; ks < ksteps; ks++) {
    s8v a = Arow[ks * 4 + quad];
#pragma unroll
    for (int nt = 0; nt < 4; nt++) {
      s8v b = Bp[(size_t)(((bcol >> 4) + nt) * ksteps + ks) * 64 + lane];
      acc[nt] = __builtin_amdgcn_mfma_f32_16x16x32_bf16(a, b, acc[nt], 0, 0, 0);
    }
  }
#pragma unroll
  for (int nt = 0; nt < 4; nt++) {
    float bv = bias ? bias[bcol + nt * 16 + l16] : 0.f;
#pragma unroll
    for (int r = 0; r < 4; r++)
      lds[(wv * 16 + quad * 4 + r) * 64 + nt * 16 + l16] = f2bf_bits(acc[nt][r] + bv);
  }
  __syncthreads();
#pragma unroll
  for (int rep = 0; rep < 2; rep++) {
    int idx = rep * 256 + tid;
    int row = idx >> 3, c16 = idx & 7;
    uint4 val = ((const uint4*)lds)[idx];
    *(uint4*)(C + (size_t)(brow + row) * ldc + bcol + c16 * 8) = val;
  }
}

// ---------------- MFMA head-GEMM for conv1: A row = y1[m,512] offset by head*128, K=128;
// epilogue bias + ELU; C = x1 [M,512] bf16 ----------------
__global__ __launch_bounds__(256) void gemm_mfma_head(const short* __restrict__ A,
                                                      const s8v* __restrict__ Bp,
                                                      const float* __restrict__ bias,
                                                      short* __restrict__ C, int M) {
  __shared__ short lds[64 * 64];
  int tid = threadIdx.x;
  int wv = tid >> 6, lane = tid & 63;
  int quad = lane >> 4, l16 = lane & 15;
  int brow = blockIdx.y * 64, bcol = blockIdx.x * 64;
  int h = bcol >> 7;
  int m = brow + wv * 16 + l16;
  f4v acc[4] = {};
  const s8v* Arow = (const s8v*)(A + (size_t)m * 512 + h * 128);
#pragma unroll
  for (int ks = 0; ks < 4; ks++) {
    s8v a = Arow[ks * 4 + quad];
#pragma unroll
    for (int nt = 0; nt < 4; nt++) {
      s8v b = Bp[(size_t)(((bcol >> 4) + nt) * 4 + ks) * 64 + lane];
      acc[nt] = __builtin_amdgcn_mfma_f32_16x16x32_bf16(a, b, acc[nt], 0, 0, 0);
    }
  }
#pragma unroll
  for (int nt = 0; nt < 4; nt++) {
    float bv = bias[bcol + nt * 16 + l16];
#pragma unroll
    for (int r = 0; r < 4; r++) {
      float vv = acc[nt][r] + bv;
      vv = vv > 0.f ? vv : (__expf(vv) - 1.f);
      lds[(wv * 16 + quad * 4 + r) * 64 + nt * 16 + l16] = f2bf_bits(vv);
    }
  }
  __syncthreads();
#pragma unroll
  for (int rep = 0; rep < 2; rep++) {
    int idx = rep * 256 + tid;
    int row = idx >> 3, c16 = idx & 7;
    uint4 val = ((const uint4*)lds)[idx];
    *(uint4*)(C + (size_t)(brow + row) * 512 + bcol + c16 * 8) = val;
  }
}

// Bp for head-GEMM: K=128 within-head; pack W1 [128,512] with ksteps=4
__global__ __launch_bounds__(256) void packB1h_kernel(const float* __restrict__ W1,
                                                      s8v* __restrict__ Bp) {
  int id = blockIdx.x * 256 + threadIdx.x;
  if (id >= 32 * 4 * 64) return;  // 32 ntiles * 4 ksteps * 64 lanes... (512/16=32 nt, 128/32=4 ks)
  packB_one(W1, 512, 128, id, Bp);
}

// ---------------- layernorm, wave per node; bf16 in -> packed bf16 out ----------------
__global__ __launch_bounds__(256) void ln_wave(const unsigned* __restrict__ start_b,
                                               const unsigned* __restrict__ emb2_b,
                                               const int* __restrict__ m_idx,
                                               const float* __restrict__ lng,
                                               const float* __restrict__ lnb,
                                               unsigned* __restrict__ x0b) {
  int i = blockIdx.x * 4 + (threadIdx.x >> 6);
  int lane = threadIdx.x & 63;
  int g = i >> 6, n = i & 63;
  const unsigned* row = (n == 0) ? (start_b + (size_t)g * 64) : (emb2_b + (size_t)m_idx[i] * 64);
  float2 v = unpk(row[lane]);
  float mu = wred_sum(v.x + v.y) * (1.f / 128.f);
  float dx = v.x - mu, dy = v.y - mu;
  float var = wred_sum(dx * dx + dy * dy) * (1.f / 128.f);
  float rstd = rsqrtf(var + 1e-6f);
  float2 gg = ((const float2*)lng)[lane];
  float2 bb = ((const float2*)lnb)[lane];
  x0b[(size_t)i * 64 + lane] = pk(dx * rstd * gg.x + bb.x, dy * rstd * gg.y + bb.y);
}

// ---------------- conv1 scores from x0 via folded vectors (wave per node, 8 reductions) ----------------
__global__ __launch_bounds__(256) void al1x_wave(const unsigned* __restrict__ x0b,
                                                 const float* __restrict__ ws1,
                                                 const float* __restrict__ wd1,
                                                 float* __restrict__ als,
                                                 float* __restrict__ ald) {
  int i = blockIdx.x * 4 + (threadIdx.x >> 6);
  int lane = threadIdx.x & 63;
  float2 x = unpk(x0b[(size_t)i * 64 + lane]);
#pragma unroll
  for (int h = 0; h < 4; h++) {
    float2 s2 = ((const float2*)(ws1 + h * 128))[lane];
    float2 d2 = ((const float2*)(wd1 + h * 128))[lane];
    float ps = wred_sum(x.x * s2.x + x.y * s2.y);
    float pd = wred_sum(x.x * d2.x + x.y * d2.y);
    if (lane == 0) { als[i * 4 + h] = ps; ald[i * 4 + h] = pd; }
  }
}

__global__ __launch_bounds__(256) void al2_wave(const unsigned* __restrict__ xp,
                                                const float* __restrict__ a_src,
                                                const float* __restrict__ a_dst,
                                                float* __restrict__ als,
                                                float* __restrict__ ald) {
  int i = blockIdx.x * 4 + (threadIdx.x >> 6);
  int lane = threadIdx.x & 63;
  float2 x = unpk(xp[(size_t)i * 64 + lane]);
  float2 as = ((const float2*)a_src)[lane];
  float2 ad = ((const float2*)a_dst)[lane];
  float ps = wred_sum(x.x * as.x + x.y * as.y);
  float pd = wred_sum(x.x * ad.x + x.y * ad.y);
  if (lane == 0) { als[i] = ps; ald[i] = pd; }
}

// ---------------- softmax weights ----------------
__global__ __launch_bounds__(256) void alpha1_kernel(const float* __restrict__ als,
                                                     const float* __restrict__ ald,
                                                     const int* __restrict__ off,
                                                     const int* __restrict__ esrc,
                                                     float* __restrict__ aw,
                                                     float* __restrict__ selfw,
                                                     float* __restrict__ inv) {
  int id = blockIdx.x * 256 + threadIdx.x;
  if (id >= NN * 4) return;
  int i = id >> 2, h = id & 3;
  float adi = ald[id];
  float selfSc = als[id] + adi;
  selfSc = selfSc > 0.f ? selfSc : 0.2f * selfSc;
  int s0 = off[i], s1 = off[i + 1];
  float m = selfSc;
  for (int e = s0; e < s1; e++) {
    float sc = als[esrc[e] * 4 + h] + adi;
    sc = sc > 0.f ? sc : 0.2f * sc;
    m = fmaxf(m, sc);
  }
  float sw = __expf(selfSc - m);
  float denom = sw;
  for (int e = s0; e < s1; e++) {
    float sc = als[esrc[e] * 4 + h] + adi;
    sc = sc > 0.f ? sc : 0.2f * sc;
    float w = __expf(sc - m);
    aw[e * 4 + h] = w;
    denom += w;
  }
  selfw[id] = sw;
  inv[id] = 1.f / denom;
}

__global__ __launch_bounds__(256) void alpha2_kernel(const float* __restrict__ als,
                                                     const float* __restrict__ ald,
                                                     const int* __restrict__ off,
                                                     const int* __restrict__ esrc,
                                                     float* __restrict__ aw,
                                                     float* __restrict__ selfw,
                                                     float* __restrict__ inv) {
  int i = blockIdx.x * 256 + threadIdx.x;
  if (i >= NN) return;
  float adi = ald[i];
  float selfSc = als[i] + adi;
  selfSc = selfSc > 0.f ? selfSc : 0.2f * selfSc;
  int s0 = off[i], s1 = off[i + 1];
  float m = selfSc;
  for (int e = s0; e < s1; e++) {
    float sc = als[esrc[e]] + adi;
    sc = sc > 0.f ? sc : 0.2f * sc;
    m = fmaxf(m, sc);
  }
  float sw = __expf(selfSc - m);
  float denom = sw;
  for (int e = s0; e < s1; e++) {
    float sc = als[esrc[e]] + adi;
    sc = sc > 0.f ? sc : 0.2f * sc;
    float w = __expf(sc - m);
    aw[e] = w;
    denom += w;
  }
  selfw[i] = sw;
  inv[i] = 1.f / denom;
}

// ---------------- conv1 aggregation in INPUT space: thread per (node, uint4 of x0) ----------------
// y1[i,h,0:128] = selfw_h*x0_i + sum_e aw[e,h]*x0_src, normalized by inv_h. bf16 out.
__global__ __launch_bounds__(256) void agg1y_kernel(const uint4* __restrict__ x0,
                                                    const float4* __restrict__ aw4,
                                                    const float4* __restrict__ selfw4,
                                                    const float4* __restrict__ inv4,
                                                    const int* __restrict__ off,
                                                    const int* __restrict__ esrc,
                                                    uint4* __restrict__ y1) {
  long gid = (long)blockIdx.x * 256 + threadIdx.x;
  if (gid >= (long)NN * 16) return;
  int i = (int)(gid >> 4), c8 = (int)(gid & 15);
  float4 sw = selfw4[i];
  uint4 xv = x0[(size_t)i * 16 + c8];
  float x[8];
  { float2 p0 = unpk(xv.x), p1 = unpk(xv.y), p2 = unpk(xv.z), p3 = unpk(xv.w);
    x[0]=p0.x; x[1]=p0.y; x[2]=p1.x; x[3]=p1.y; x[4]=p2.x; x[5]=p2.y; x[6]=p3.x; x[7]=p3.y; }
  float acc[4][8];
#pragma unroll
  for (int j = 0; j < 8; j++) {
    acc[0][j] = sw.x * x[j]; acc[1][j] = sw.y * x[j];
    acc[2][j] = sw.z * x[j]; acc[3][j] = sw.w * x[j];
  }
  int s0 = off[i], s1 = off[i + 1];
  for (int e = s0; e < s1; e++) {
    int s = esrc[e];
    float4 wv = aw4[e];
    uint4 m = x0[(size_t)s * 16 + c8];
    float2 q0 = unpk(m.x), q1 = unpk(m.y), q2 = unpk(m.z), q3 = unpk(m.w);
    float q[8] = {q0.x, q0.y, q1.x, q1.y, q2.x, q2.y, q3.x, q3.y};
#pragma unroll
    for (int j = 0; j < 8; j++) {
      acc[0][j] = fmaf(wv.x, q[j], acc[0][j]);
      acc[1][j] = fmaf(wv.y, q[j], acc[1][j]);
      acc[2][j] = fmaf(wv.z, q[j], acc[2][j]);
      acc[3][j] = fmaf(wv.w, q[j], acc[3][j]);
    }
  }
  float4 iv = inv4[i];
  float ivh[4] = {iv.x, iv.y, iv.z, iv.w};
#pragma unroll
  for (int h = 0; h < 4; h++) {
    uint4 o;
    o.x = pk(acc[h][0] * ivh[h], acc[h][1] * ivh[h]);
    o.y = pk(acc[h][2] * ivh[h], acc[h][3] * ivh[h]);
    o.z = pk(acc[h][4] * ivh[h], acc[h][5] * ivh[h]);
    o.w = pk(acc[h][6] * ivh[h], acc[h][7] * ivh[h]);
    y1[((size_t)i * 4 + h) * 16 + c8] = o;
  }
}

// ---------------- weighted gather, conv2: thread per (node, uint4 = 8 cols) ----------------
__global__ __launch_bounds__(256) void agg2w_kernel(const uint4* __restrict__ xp,
                                                    const float* __restrict__ aw,
                                                    const float* __restrict__ selfw,
                                                    const float* __restrict__ inv,
                                                    const int* __restrict__ off,
                                                    const int* __restrict__ esrc,
                                                    const float* __restrict__ b2,
                                                    float4* __restrict__ x2) {
  long gid = (long)blockIdx.x * 256 + threadIdx.x;
  if (gid >= (long)NN * 16) return;
  int i = (int)(gid >> 4), c8 = (int)(gid & 15);
  float sw = selfw[i];
  float iv = inv[i];
  uint4 xv = xp[(size_t)i * 16 + c8];
  float2 p0 = unpk(xv.x), p1 = unpk(xv.y), p2 = unpk(xv.z), p3 = unpk(xv.w);
  float a0 = sw * p0.x, a1 = sw * p0.y, a2 = sw * p1.x, a3 = sw * p1.y;
  float a4 = sw * p2.x, a5 = sw * p2.y, a6 = sw * p3.x, a7 = sw * p3.y;
  int s0 = off[i], s1 = off[i + 1];
  int e = s0;
  for (; e + 1 < s1; e += 2) {
    int sA = esrc[e], sB = esrc[e + 1];
    float wA = aw[e], wB = aw[e + 1];
    uint4 mA = xp[(size_t)sA * 16 + c8];
    uint4 mB = xp[(size_t)sB * 16 + c8];
    float2 q0 = unpk(mA.x), q1 = unpk(mA.y), q2 = unpk(mA.z), q3 = unpk(mA.w);
    a0 = fmaf(wA, q0.x, a0); a1 = fmaf(wA, q0.y, a1);
    a2 = fmaf(wA, q1.x, a2); a3 = fmaf(wA, q1.y, a3);
    a4 = fmaf(wA, q2.x, a4); a5 = fmaf(wA, q2.y, a5);
    a6 = fmaf(wA, q3.x, a6); a7 = fmaf(wA, q3.y, a7);
    q0 = unpk(mB.x); q1 = unpk(mB.y); q2 = unpk(mB.z); q3 = unpk(mB.w);
    a0 = fmaf(wB, q0.x, a0); a1 = fmaf(wB, q0.y, a1);
    a2 = fmaf(wB, q1.x, a2); a3 = fmaf(wB, q1.y, a3);
    a4 = fmaf(wB, q2.x, a4); a5 = fmaf(wB, q2.y, a5);
    a6 = fmaf(wB, q3.x, a6); a7 = fmaf(wB, q3.y, a7);
  }
  if (e < s1) {
    int sA = esrc[e];
    float wA = aw[e];
    uint4 mA = xp[(size_t)sA * 16 + c8];
    float2 q0 = unpk(mA.x), q1 = unpk(mA.y), q2 = unpk(mA.z), q3 = unpk(mA.w);
    a0 = fmaf(wA, q0.x, a0); a1 = fmaf(wA, q0.y, a1);
    a2 = fmaf(wA, q1.x, a2); a3 = fmaf(wA, q1.y, a3);
    a4 = fmaf(wA, q2.x, a4); a5 = fmaf(wA, q2.y, a5);
    a6 = fmaf(wA, q3.x, a6); a7 = fmaf(wA, q3.y, a7);
  }
  float4 bb0 = ((const float4*)b2)[c8 * 2];
  float4 bb1 = ((const float4*)b2)[c8 * 2 + 1];
  a0 = a0 * iv + bb0.x; a1 = a1 * iv + bb0.y; a2 = a2 * iv + bb0.z; a3 = a3 * iv + bb0.w;
  a4 = a4 * iv + bb1.x; a5 = a5 * iv + bb1.y; a6 = a6 * iv + bb1.z; a7 = a7 * iv + bb1.w;
  a0 = a0 > 0.f ? a0 : (__expf(a0) - 1.f);
  a1 = a1 > 0.f ? a1 : (__expf(a1) - 1.f);
  a2 = a2 > 0.f ? a2 : (__expf(a2) - 1.f);
  a3 = a3 > 0.f ? a3 : (__expf(a3) - 1.f);
  a4 = a4 > 0.f ? a4 : (__expf(a4) - 1.f);
  a5 = a5 > 0.f ? a5 : (__expf(a5) - 1.f);
  a6 = a6 > 0.f ? a6 : (__expf(a6) - 1.f);
  a7 = a7 > 0.f ? a7 : (__expf(a7) - 1.f);
  x2[gid * 2] = make_float4(a0, a1, a2, a3);
  x2[gid * 2 + 1] = make_float4(a4, a5, a6, a7);
}

// ---------------- masked mean pool ----------------
__global__ __launch_bounds__(128) void pool_kernel(const float* __restrict__ x2,
                                                   const int* __restrict__ m_idx,
                                                   float* __restrict__ pooled) {
  int g = blockIdx.x, c = threadIdx.x;
  float acc = 0.f, cnt = 0.f;
  const float* xr = x2 + (size_t)g * 64 * 128;
  const int* mi = m_idx + g * 64;
  for (int n = 0; n < 64; n++) {
    if (mi[n] >= 1) { cnt += 1.f; acc += xr[n * 128 + c]; }
  }
  pooled[(size_t)g * 128 + c] = acc / cnt;
}

// ---------------- final logit ----------------
__global__ __launch_bounds__(256) void head2_naive(const float* __restrict__ h1,
                                                   const float* __restrict__ Wo2,
                                                   const float* __restrict__ bo2,
                                                   float* __restrict__ out) {
  int g = blockIdx.x * 256 + threadIdx.x;
  if (g >= GG) return;
  float p = bo2[0];
  for (int c = 0; c < 128; c++) p = fmaf(h1[(size_t)g * 128 + c], Wo2[c], p);
  out[g] = p;
}

extern "C" void kernel_launch(void* const* d_in, const int* in_sizes, int n_in, void* d_out,
                              int out_size, void* d_ws, size_t ws_size, hipStream_t stream) {
  (void)n_in; (void)out_size; (void)ws_size;
  bool dict_order = (in_sizes[2] == NN);
  int IM, IE, IF[25];
  if (dict_order) {
    IM = 2; IE = 3;
    const int f[25] = {0, 1, 4, 5, 6, 7, 8, 9, 10, 11, 12, 13, 14, 15, 16, 17, 18,
                       19, 20, 21, 22, 23, 24, 25, 26};
    for (int k = 0; k < 25; k++) IF[k] = f[k];
  } else {
    IM = 25; IE = 26;
    for (int k = 0; k < 25; k++) IF[k] = k;
  }
  const int* m_idx = (const int*)d_in[IM];
  const int* eidx = (const int*)d_in[IE];
  float* out = (float*)d_out;
  const int* e_src = eidx;
  const int* e_dst = eidx + EE;

  const float* t = (const float*)d_in[IF[0]];
  const float* v = (const float*)d_in[IF[1]];
  const float* Wt = (const float*)d_in[IF[2]];     const float* bt = (const float*)d_in[IF[3]];
  const float* Wv = (const float*)d_in[IF[4]];     const float* bv = (const float*)d_in[IF[5]];
  const float* emb = (const float*)d_in[IF[6]];
  const float* Wnode = (const float*)d_in[IF[7]];  const float* bnode = (const float*)d_in[IF[8]];
  const float* Wstart = (const float*)d_in[IF[9]]; const float* bstart = (const float*)d_in[IF[10]];
  const float* ln_g = (const float*)d_in[IF[11]];  const float* ln_b = (const float*)d_in[IF[12]];
  const float* W1 = (const float*)d_in[IF[13]];
  const float* a_src1 = (const float*)d_in[IF[14]]; const float* a_dst1 = (const float*)d_in[IF[15]];
  const float* b1 = (const float*)d_in[IF[16]];
  const float* W2 = (const float*)d_in[IF[17]];
  const float* a_src2 = (const float*)d_in[IF[18]]; const float* a_dst2 = (const float*)d_in[IF[19]];
  const float* b2 = (const float*)d_in[IF[20]];
  const float* Wo1 = (const float*)d_in[IF[21]];   const float* bo1 = (const float*)d_in[IF[22]];
  const float* Wo2 = (const float*)d_in[IF[23]];   const float* bo2 = (const float*)d_in[IF[24]];

  // workspace layout (peak ~96 MB)
  char* w = (char*)d_ws;
  bf16* y1 = (bf16*)(w);                             // [NN,4,128] bf16 [0,32) MB (conv1 aggregated)
  bf16* x0b = (bf16*)(w + ((size_t)32 << 20));       // [NN,128] bf16 [32,40) MB
  bf16* x1 = (bf16*)(w + ((size_t)48 << 20));        // [NN,512] bf16 [48,80) MB
  bf16* xp2b = (bf16*)(w);                           // [NN,128] bf16 [0,8)  (y1 dead)
  float* x2 = (float*)(w + ((size_t)8 << 20));       // [NN,128] f32 [8,24)
  size_t so = (size_t)80 << 20;                      // smalls [80,~96) MB
  bf16* t_b = (bf16*)(w + so); so += 512 * 768 * 2;
  bf16* v_b = (bf16*)(w + so); so += 512 * 768 * 2;
  bf16* vt_b = (bf16*)(w + so); so += 512 * 256 * 2;
  bf16* start_b = (bf16*)(w + so); so += 512 * 128 * 2;
  bf16* emb2_b = (bf16*)(w + so); so += 51 * 128 * 2 + 256;
  float* als1 = (float*)(w + so); so += NN * 4 * 4;
  float* ald1 = (float*)(w + so); so += NN * 4 * 4;
  float* als2 = (float*)(w + so); so += NN * 4;
  float* ald2 = (float*)(w + so); so += NN * 4;
  float* aw1 = (float*)(w + so); so += EE * 4 * 4;   // 4 MB
  float* selfw1 = (float*)(w + so); so += NN * 4 * 4;
  float* inv1 = (float*)(w + so); so += NN * 4 * 4;
  float* aw2 = (float*)(w + so); so += EE * 4;       // 1 MB
  float* selfw2 = (float*)(w + so); so += NN * 4;
  float* inv2 = (float*)(w + so); so += NN * 4;
  float* pooled = (float*)(w + so); so += 512 * 128 * 4;
  float* h1 = (float*)(w + so); so += 512 * 128 * 4;
  float* ws1 = (float*)(w + so); so += 512 * 4;
  float* wd1 = (float*)(w + so); so += 512 * 4;
  int* indeg = (int*)(w + so); so += NN * 4;
  int* csroff = (int*)(w + so); so += (NN + 1) * 4 + 252;
  int* cursor = (int*)(w + so); so += NN * 4;
  int* esrc = (int*)(w + so); so += EE * 4;
  s8v* Bp1 = (s8v*)(w + so); so += 32 * 4 * 64 * 16;    // conv1 W1 frags (K=128,N=512)
  s8v* Bp2 = (s8v*)(w + so); so += 8 * 16 * 64 * 16;    // conv2 W2 frags
  s8v* BpWv = (s8v*)(w + so); so += 8 * 24 * 64 * 16;   // Wv frags
  s8v* BpWt = (s8v*)(w + so); so += 8 * 24 * 64 * 16;   // Wt frags
  s8v* BpWs = (s8v*)(w + so); so += 8 * 8 * 64 * 16;    // Wstart frags

  // ---- CSR build ----
  hipMemsetAsync(indeg, 0, NN * 4, stream);
  hist_kernel<<<EE / 256, 256, 0, stream>>>(e_dst, indeg);
  scan_kernel<<<1, 1024, 0, stream>>>(indeg, csroff, cursor);
  fill_kernel<<<EE / 256, 256, 0, stream>>>(e_src, e_dst, cursor, esrc);

  // pack all weights + convert t,v + fold conv1 score vectors
  packall_kernel<<<176, 256, 0, stream>>>(W1, Bp1, W2, Bp2, Wv, BpWv, Wt, BpWt, Wstart, BpWs);
  cvtpk2_kernel<<<1536, 256, 0, stream>>>((const float2*)t, (unsigned*)t_b,
                                          (const float2*)v, (unsigned*)v_b, 512 * 384);
  fold1_kernel<<<2, 256, 0, stream>>>(W1, a_src1, a_dst1, ws1, wd1);

  // emb2 (tiny), bf16 out
  sgemm_kernel<bf16><<<(51 * 128 + 63) / 64, 256, 0, stream>>>(emb, Wnode, bnode, emb2_b, 51, 128, 128, 128, 0);

  // ve/te/start via MFMA
  gemm_mfma<<<dim3(2, 8), 256, 0, stream>>>((const short*)v_b, BpWv, bv, (short*)vt_b, 512, 128, 768, 256);
  gemm_mfma<<<dim3(2, 8), 256, 0, stream>>>((const short*)t_b, BpWt, bt, (short*)(vt_b + 128), 512, 128, 768, 256);
  gemm_mfma<<<dim3(2, 8), 256, 0, stream>>>((const short*)vt_b, BpWs, bstart, (short*)start_b, 512, 128, 256, 128);
  ln_wave<<<NN / 4, 256, 0, stream>>>((const unsigned*)start_b, (const unsigned*)emb2_b, m_idx, ln_g, ln_b, (unsigned*)x0b);

  // conv1: scores from x0 (folded), aggregate in input space, then per-head MFMA GEMM + bias + ELU
  al1x_wave<<<NN / 4, 256, 0, stream>>>((const unsigned*)x0b, ws1, wd1, als1, ald1);
  alpha1_kernel<<<NN * 4 / 256, 256, 0, stream>>>(als1, ald1, csroff, esrc, aw1, selfw1, inv1);
  agg1y_kernel<<<(int)(((long)NN * 16 + 255) / 256), 256, 0, stream>>>(
      (const uint4*)x0b, (const float4*)aw1, (const float4*)selfw1, (const float4*)inv1,
      csroff, esrc, (uint4*)y1);
  gemm_mfma_head<<<dim3(8, NN / 64), 256, 0, stream>>>((const short*)y1, Bp1, b1, (short*)x1, NN);

  // conv2: MFMA GEMM (bf16 in/out), transform-first
  gemm_mfma<<<dim3(2, NN / 64), 256, 0, stream>>>((const short*)x1, Bp2, nullptr, (short*)xp2b, NN, 128, 512, 128);
  al2_wave<<<NN / 4, 256, 0, stream>>>((const unsigned*)xp2b, a_src2, a_dst2, als2, ald2);
  alpha2_kernel<<<NN / 256, 256, 0, stream>>>(als2, ald2, csroff, esrc, aw2, selfw2, inv2);
  agg2w_kernel<<<(int)(((long)NN * 16 + 255) / 256), 256, 0, stream>>>(
      (const uint4*)xp2b, aw2, selfw2, inv2, csroff, esrc, b2, (float4*)x2);

  pool_kernel<<<GG, 128, 0, stream>>>(x2, m_idx, pooled);
  sgemm_kernel<float><<<512 * 128 / 64, 256, 0, stream>>>(pooled, Wo1, bo1, h1, 512, 128, 128, 128, 1);
  head2_naive<<<(GG + 255) / 256, 256, 0, stream>>>(h1, Wo2, bo2, out);
}

// Round 17
// 343.688 us; speedup vs baseline: 7.2166x; 1.0620x over previous
//
#include <hip/hip_runtime.h>
#include <hip/hip_bf16.h>

typedef __hip_bfloat16 bf16;
typedef __attribute__((ext_vector_type(8))) short s8v;   // 8 bf16 (4 VGPRs)
typedef __attribute__((ext_vector_type(4))) float f4v;   // 4 fp32 acc

#define NN 32768   // total nodes
#define EE 262144  // edges
#define GG 512     // graphs

__device__ __forceinline__ float2 unpk(unsigned u) {
  float2 r;
  r.x = __uint_as_float(u << 16);
  r.y = __uint_as_float(u & 0xffff0000u);
  return r;
}
__device__ __forceinline__ unsigned pk(float x, float y) {
  union { bf16 h[2]; unsigned u; } p;
  p.h[0] = __float2bfloat16(x);
  p.h[1] = __float2bfloat16(y);
  return p.u;
}
__device__ __forceinline__ short f2bf_bits(float x) {
  bf16 h = __float2bfloat16(x);
  return *reinterpret_cast<short*>(&h);
}
__device__ __forceinline__ void storef(float* p, float v) { *p = v; }
__device__ __forceinline__ void storef(bf16* p, float v) { *p = __float2bfloat16(v); }

__device__ __forceinline__ float wred_sum(float v) {
#pragma unroll
  for (int o = 32; o; o >>= 1) v += __shfl_xor(v, o, 64);
  return v;
}

// ---------------- CSR build ----------------
__global__ __launch_bounds__(256) void hist_kernel(const int* __restrict__ dst,
                                                   int* __restrict__ indeg) {
  int e = blockIdx.x * 256 + threadIdx.x;
  if (e < EE) atomicAdd(&indeg[dst[e]], 1);
}

__global__ __launch_bounds__(1024) void scan_kernel(const int* __restrict__ indeg,
                                                    int* __restrict__ off,
                                                    int* __restrict__ cursor) {
  __shared__ int sh[1024];
  int t = threadIdx.x;
  int loc[32];
  int s = 0;
  int base = t * 32;
#pragma unroll
  for (int j = 0; j < 32; j++) { loc[j] = indeg[base + j]; s += loc[j]; }
  sh[t] = s;
  __syncthreads();
  for (int d = 1; d < 1024; d <<= 1) {
    int v = (t >= d) ? sh[t - d] : 0;
    __syncthreads();
    sh[t] += v;
    __syncthreads();
  }
  int run = (t == 0) ? 0 : sh[t - 1];
#pragma unroll
  for (int j = 0; j < 32; j++) { off[base + j] = run; cursor[base + j] = run; run += loc[j]; }
  if (t == 1023) off[NN] = run;
}

__global__ __launch_bounds__(256) void fill_kernel(const int* __restrict__ src,
                                                   const int* __restrict__ dst,
                                                   int* __restrict__ cursor,
                                                   int* __restrict__ esrc) {
  int e = blockIdx.x * 256 + threadIdx.x;
  if (e < EE) {
    int p = atomicAdd(&cursor[dst[e]], 1);
    esrc[p] = src[e];
  }
}

// ---------------- fp32 -> packed bf16 conversion (t and v in one launch) ----------------
__global__ __launch_bounds__(256) void cvtpk2_kernel(const float2* __restrict__ a,
                                                     unsigned* __restrict__ da,
                                                     const float2* __restrict__ b,
                                                     unsigned* __restrict__ db, int n2) {
  int id = blockIdx.x * 256 + threadIdx.x;
  if (id < n2) { float2 v = a[id]; da[id] = pk(v.x, v.y); }
  else if (id < 2 * n2) { int j = id - n2; float2 v = b[j]; db[j] = pk(v.x, v.y); }
}

// ---------------- small GEMM, split-K (tiny problems) ----------------
template <typename TC>
__global__ __launch_bounds__(256) void sgemm_kernel(const float* __restrict__ A,
                                                    const float* __restrict__ B,
                                                    const float* __restrict__ bias,
                                                    TC* __restrict__ C,
                                                    int M, int N, int K, int ldc, int act) {
  __shared__ float red[256];
  int tid = threadIdx.x;
  int lo = tid & 63;
  int slice = tid >> 6;
  long oid = (long)blockIdx.x * 64 + lo;
  bool live = (oid < (long)M * N);
  int m = 0, n = 0;
  if (live) { m = (int)(oid / N); n = (int)(oid % N); }
  int kq = K >> 2;
  int k0 = slice * kq, k1 = k0 + kq;
  float acc = 0.f;
  if (live) {
    const float* Ar = A + (size_t)m * K;
    for (int k = k0; k < k1; k++) acc = fmaf(Ar[k], B[(size_t)k * N + n], acc);
  }
  red[tid] = acc;
  __syncthreads();
  if (slice == 0 && live) {
    float v = red[lo] + red[64 + lo] + red[128 + lo] + red[192 + lo];
    if (bias) v += bias[n];
    if (act == 1) v = v > 0.f ? v : 0.01f * v;
    storef(&C[(size_t)m * ldc + n], v);
  }
}

// ---------------- pack all 5 weights into MFMA B-fragment order, one launch ----------------
__device__ __forceinline__ void packB_one(const float* W, int N, int K, int id, s8v* Bp) {
  int lane = id & 63;
  int tmp = id >> 6;
  int ksteps = K >> 5;
  int ks = tmp % ksteps;
  int nt = tmp / ksteps;
  int n = nt * 16 + (lane & 15);
  int kbase = ks * 32 + (lane >> 4) * 8;
  s8v r;
#pragma unroll
  for (int j = 0; j < 8; j++) r[j] = f2bf_bits(W[(size_t)(kbase + j) * N + n]);
  Bp[id] = r;
}

// blocks: [0,32) W1, [32,64) W2, [64,112) Wv, [112,160) Wt, [160,176) Wstart
__global__ __launch_bounds__(256) void packall_kernel(const float* __restrict__ W1, s8v* Bp1,
                                                      const float* __restrict__ W2, s8v* Bp2,
                                                      const float* __restrict__ Wv, s8v* BpWv,
                                                      const float* __restrict__ Wt, s8v* BpWt,
                                                      const float* __restrict__ Ws, s8v* BpWs) {
  int b = blockIdx.x;
  if (b < 32)        packB_one(W1, 512, 128, b * 256 + threadIdx.x, Bp1);
  else if (b < 64)   packB_one(W2, 128, 512, (b - 32) * 256 + threadIdx.x, Bp2);
  else if (b < 112)  packB_one(Wv, 128, 768, (b - 64) * 256 + threadIdx.x, BpWv);
  else if (b < 160)  packB_one(Wt, 128, 768, (b - 112) * 256 + threadIdx.x, BpWt);
  else               packB_one(Ws, 128, 256, (b - 160) * 256 + threadIdx.x, BpWs);
}

// ---------------- fold a_src/a_dst through W1 ----------------
__global__ __launch_bounds__(256) void fold1_kernel(const float* __restrict__ W1,
                                                    const float* __restrict__ a_src1,
                                                    const float* __restrict__ a_dst1,
                                                    float* __restrict__ ws1,
                                                    float* __restrict__ wd1) {
  int id = blockIdx.x * 256 + threadIdx.x;
  if (id >= 512) return;
  int h = id >> 7, k = id & 127;
  float s = 0.f, d = 0.f;
  for (int c = 0; c < 128; c++) {
    float w = W1[(size_t)k * 512 + h * 128 + c];
    s = fmaf(w, a_src1[h * 128 + c], s);
    d = fmaf(w, a_dst1[h * 128 + c], d);
  }
  ws1[id] = s;
  wd1[id] = d;
}

// ---------------- MFMA bf16 GEMM, optional fp32 bias, bf16 out with ldc ----------------
__global__ __launch_bounds__(256) void gemm_mfma(const short* __restrict__ A,
                                                 const s8v* __restrict__ Bp,
                                                 const float* __restrict__ bias,
                                                 short* __restrict__ C,
                                                 int M, int N, int K, int ldc) {
  __shared__ short lds[64 * 64];
  int tid = threadIdx.x;
  int wv = tid >> 6, lane = tid & 63;
  int quad = lane >> 4, l16 = lane & 15;
  int brow = blockIdx.y * 64, bcol = blockIdx.x * 64;
  int m = brow + wv * 16 + l16;
  int ksteps = K >> 5;
  f4v acc[4] = {};
  const s8v* Arow = (const s8v*)(A + (size_t)m * K);
  for (int ks = 0; ks < ksteps; ks++) {
    s8v a = Arow[ks * 4 + quad];
#pragma unroll
    for (int nt = 0; nt < 4; nt++) {
      s8v b = Bp[(size_t)(((bcol >> 4) + nt) * ksteps + ks) * 64 + lane];
      acc[nt] = __builtin_amdgcn_mfma_f32_16x16x32_bf16(a, b, acc[nt], 0, 0, 0);
    }
  }
#pragma unroll
  for (int nt = 0; nt < 4; nt++) {
    float bv = bias ? bias[bcol + nt * 16 + l16] : 0.f;
#pragma unroll
    for (int r = 0; r < 4; r++)
      lds[(wv * 16 + quad * 4 + r) * 64 + nt * 16 + l16] = f2bf_bits(acc[nt][r] + bv);
  }
  __syncthreads();
#pragma unroll
  for (int rep = 0; rep < 2; rep++) {
    int idx = rep * 256 + tid;
    int row = idx >> 3, c16 = idx & 7;
    uint4 val = ((const uint4*)lds)[idx];
    *(uint4*)(C + (size_t)(brow + row) * ldc + bcol + c16 * 8) = val;
  }
}

// ---------------- conv2 MFMA GEMM: N=128 in one block (8 n-tiles), A read once ----------------
__global__ __launch_bounds__(256) void gemm_mfma8(const short* __restrict__ A,
                                                  const s8v* __restrict__ Bp,
                                                  short* __restrict__ C, int M) {
  __shared__ short lds[64 * 128];
  int tid = threadIdx.x;
  int wv = tid >> 6, lane = tid & 63;
  int quad = lane >> 4, l16 = lane & 15;
  int brow = blockIdx.y * 64;
  int m = brow + wv * 16 + l16;
  f4v acc[8] = {};
  const s8v* Arow = (const s8v*)(A + (size_t)m * 512);
  for (int ks = 0; ks < 16; ks++) {
    s8v a = Arow[ks * 4 + quad];
#pragma unroll
    for (int nt = 0; nt < 8; nt++) {
      s8v b = Bp[(size_t)(nt * 16 + ks) * 64 + lane];
      acc[nt] = __builtin_amdgcn_mfma_f32_16x16x32_bf16(a, b, acc[nt], 0, 0, 0);
    }
  }
#pragma unroll
  for (int nt = 0; nt < 8; nt++)
#pragma unroll
    for (int r = 0; r < 4; r++)
      lds[(wv * 16 + quad * 4 + r) * 128 + nt * 16 + l16] = f2bf_bits(acc[nt][r]);
  __syncthreads();
#pragma unroll
  for (int rep = 0; rep < 4; rep++) {
    int idx = rep * 256 + tid;
    int row = idx >> 4, c16 = idx & 15;
    uint4 val = ((const uint4*)lds)[idx];
    *(uint4*)(C + (size_t)(brow + row) * 128 + c16 * 8) = val;
  }
}

// ---------------- MFMA head-GEMM for conv1 (bias + ELU epilogue) ----------------
__global__ __launch_bounds__(256) void gemm_mfma_head(const short* __restrict__ A,
                                                      const s8v* __restrict__ Bp,
                                                      const float* __restrict__ bias,
                                                      short* __restrict__ C, int M) {
  __shared__ short lds[64 * 64];
  int tid = threadIdx.x;
  int wv = tid >> 6, lane = tid & 63;
  int quad = lane >> 4, l16 = lane & 15;
  int brow = blockIdx.y * 64, bcol = blockIdx.x * 64;
  int h = bcol >> 7;
  int m = brow + wv * 16 + l16;
  f4v acc[4] = {};
  const s8v* Arow = (const s8v*)(A + (size_t)m * 512 + h * 128);
#pragma unroll
  for (int ks = 0; ks < 4; ks++) {
    s8v a = Arow[ks * 4 + quad];
#pragma unroll
    for (int nt = 0; nt < 4; nt++) {
      s8v b = Bp[(size_t)(((bcol >> 4) + nt) * 4 + ks) * 64 + lane];
      acc[nt] = __builtin_amdgcn_mfma_f32_16x16x32_bf16(a, b, acc[nt], 0, 0, 0);
    }
  }
#pragma unroll
  for (int nt = 0; nt < 4; nt++) {
    float bv = bias[bcol + nt * 16 + l16];
#pragma unroll
    for (int r = 0; r < 4; r++) {
      float vv = acc[nt][r] + bv;
      vv = vv > 0.f ? vv : (__expf(vv) - 1.f);
      lds[(wv * 16 + quad * 4 + r) * 64 + nt * 16 + l16] = f2bf_bits(vv);
    }
  }
  __syncthreads();
#pragma unroll
  for (int rep = 0; rep < 2; rep++) {
    int idx = rep * 256 + tid;
    int row = idx >> 3, c16 = idx & 7;
    uint4 val = ((const uint4*)lds)[idx];
    *(uint4*)(C + (size_t)(brow + row) * 512 + bcol + c16 * 8) = val;
  }
}

// ---------------- fused layernorm + conv1 scores (wave per node) ----------------
__global__ __launch_bounds__(256) void ln_al1_wave(const unsigned* __restrict__ start_b,
                                                   const unsigned* __restrict__ emb2_b,
                                                   const int* __restrict__ m_idx,
                                                   const float* __restrict__ lng,
                                                   const float* __restrict__ lnb,
                                                   const float* __restrict__ ws1,
                                                   const float* __restrict__ wd1,
                                                   unsigned* __restrict__ x0b,
                                                   float* __restrict__ als,
                                                   float* __restrict__ ald) {
  int i = blockIdx.x * 4 + (threadIdx.x >> 6);
  int lane = threadIdx.x & 63;
  int g = i >> 6, n = i & 63;
  const unsigned* row = (n == 0) ? (start_b + (size_t)g * 64) : (emb2_b + (size_t)m_idx[i] * 64);
  float2 v = unpk(row[lane]);
  float mu = wred_sum(v.x + v.y) * (1.f / 128.f);
  float dx = v.x - mu, dy = v.y - mu;
  float var = wred_sum(dx * dx + dy * dy) * (1.f / 128.f);
  float rstd = rsqrtf(var + 1e-6f);
  float2 gg = ((const float2*)lng)[lane];
  float2 bb = ((const float2*)lnb)[lane];
  float xx = dx * rstd * gg.x + bb.x;
  float xy = dy * rstd * gg.y + bb.y;
  x0b[(size_t)i * 64 + lane] = pk(xx, xy);
#pragma unroll
  for (int h = 0; h < 4; h++) {
    float2 s2 = ((const float2*)(ws1 + h * 128))[lane];
    float2 d2 = ((const float2*)(wd1 + h * 128))[lane];
    float ps = wred_sum(xx * s2.x + xy * s2.y);
    float pd = wred_sum(xx * d2.x + xy * d2.y);
    if (lane == 0) { als[i * 4 + h] = ps; ald[i * 4 + h] = pd; }
  }
}

__global__ __launch_bounds__(256) void al2_wave(const unsigned* __restrict__ xp,
                                                const float* __restrict__ a_src,
                                                const float* __restrict__ a_dst,
                                                float* __restrict__ als,
                                                float* __restrict__ ald) {
  int i = blockIdx.x * 4 + (threadIdx.x >> 6);
  int lane = threadIdx.x & 63;
  float2 x = unpk(xp[(size_t)i * 64 + lane]);
  float2 as = ((const float2*)a_src)[lane];
  float2 ad = ((const float2*)a_dst)[lane];
  float ps = wred_sum(x.x * as.x + x.y * as.y);
  float pd = wred_sum(x.x * ad.x + x.y * ad.y);
  if (lane == 0) { als[i] = ps; ald[i] = pd; }
}

// ---------------- softmax weights, single pass (scores bounded, no max-sub needed) ----------------
__global__ __launch_bounds__(256) void alpha1_kernel(const float* __restrict__ als,
                                                     const float* __restrict__ ald,
                                                     const int* __restrict__ off,
                                                     const int* __restrict__ esrc,
                                                     float* __restrict__ aw,
                                                     float* __restrict__ selfw,
                                                     float* __restrict__ inv) {
  int id = blockIdx.x * 256 + threadIdx.x;
  if (id >= NN * 4) return;
  int i = id >> 2, h = id & 3;
  float adi = ald[id];
  float selfSc = als[id] + adi;
  selfSc = selfSc > 0.f ? selfSc : 0.2f * selfSc;
  float sw = __expf(selfSc);
  float denom = sw;
  int s0 = off[i], s1 = off[i + 1];
  for (int e = s0; e < s1; e++) {
    float sc = als[esrc[e] * 4 + h] + adi;
    sc = sc > 0.f ? sc : 0.2f * sc;
    float w = __expf(sc);
    aw[e * 4 + h] = w;
    denom += w;
  }
  selfw[id] = sw;
  inv[id] = 1.f / denom;
}

__global__ __launch_bounds__(256) void alpha2_kernel(const float* __restrict__ als,
                                                     const float* __restrict__ ald,
                                                     const int* __restrict__ off,
                                                     const int* __restrict__ esrc,
                                                     float* __restrict__ aw,
                                                     float* __restrict__ selfw,
                                                     float* __restrict__ inv) {
  int i = blockIdx.x * 256 + threadIdx.x;
  if (i >= NN) return;
  float adi = ald[i];
  float selfSc = als[i] + adi;
  selfSc = selfSc > 0.f ? selfSc : 0.2f * selfSc;
  float sw = __expf(selfSc);
  float denom = sw;
  int s0 = off[i], s1 = off[i + 1];
  for (int e = s0; e < s1; e++) {
    float sc = als[esrc[e]] + adi;
    sc = sc > 0.f ? sc : 0.2f * sc;
    float w = __expf(sc);
    aw[e] = w;
    denom += w;
  }
  selfw[i] = sw;
  inv[i] = 1.f / denom;
}

// ---------------- conv1 aggregation in input space: thread per (node, uint4 of x0) ----------------
__global__ __launch_bounds__(256) void agg1y_kernel(const uint4* __restrict__ x0,
                                                    const float4* __restrict__ aw4,
                                                    const float4* __restrict__ selfw4,
                                                    const float4* __restrict__ inv4,
                                                    const int* __restrict__ off,
                                                    const int* __restrict__ esrc,
                                                    uint4* __restrict__ y1) {
  long gid = (long)blockIdx.x * 256 + threadIdx.x;
  if (gid >= (long)NN * 16) return;
  int i = (int)(gid >> 4), c8 = (int)(gid & 15);
  float4 sw = selfw4[i];
  uint4 xv = x0[(size_t)i * 16 + c8];
  float x[8];
  { float2 p0 = unpk(xv.x), p1 = unpk(xv.y), p2 = unpk(xv.z), p3 = unpk(xv.w);
    x[0]=p0.x; x[1]=p0.y; x[2]=p1.x; x[3]=p1.y; x[4]=p2.x; x[5]=p2.y; x[6]=p3.x; x[7]=p3.y; }
  float acc[4][8];
#pragma unroll
  for (int j = 0; j < 8; j++) {
    acc[0][j] = sw.x * x[j]; acc[1][j] = sw.y * x[j];
    acc[2][j] = sw.z * x[j]; acc[3][j] = sw.w * x[j];
  }
  int s0 = off[i], s1 = off[i + 1];
  for (int e = s0; e < s1; e++) {
    int s = esrc[e];
    float4 wv = aw4[e];
    uint4 m = x0[(size_t)s * 16 + c8];
    float2 q0 = unpk(m.x), q1 = unpk(m.y), q2 = unpk(m.z), q3 = unpk(m.w);
    float q[8] = {q0.x, q0.y, q1.x, q1.y, q2.x, q2.y, q3.x, q3.y};
#pragma unroll
    for (int j = 0; j < 8; j++) {
      acc[0][j] = fmaf(wv.x, q[j], acc[0][j]);
      acc[1][j] = fmaf(wv.y, q[j], acc[1][j]);
      acc[2][j] = fmaf(wv.z, q[j], acc[2][j]);
      acc[3][j] = fmaf(wv.w, q[j], acc[3][j]);
    }
  }
  float4 iv = inv4[i];
  float ivh[4] = {iv.x, iv.y, iv.z, iv.w};
#pragma unroll
  for (int h = 0; h < 4; h++) {
    uint4 o;
    o.x = pk(acc[h][0] * ivh[h], acc[h][1] * ivh[h]);
    o.y = pk(acc[h][2] * ivh[h], acc[h][3] * ivh[h]);
    o.z = pk(acc[h][4] * ivh[h], acc[h][5] * ivh[h]);
    o.w = pk(acc[h][6] * ivh[h], acc[h][7] * ivh[h]);
    y1[((size_t)i * 4 + h) * 16 + c8] = o;
  }
}

// ---------------- weighted gather, conv2: thread per (node, uint4 = 8 cols) ----------------
__global__ __launch_bounds__(256) void agg2w_kernel(const uint4* __restrict__ xp,
                                                    const float* __restrict__ aw,
                                                    const float* __restrict__ selfw,
                                                    const float* __restrict__ inv,
                                                    const int* __restrict__ off,
                                                    const int* __restrict__ esrc,
                                                    const float* __restrict__ b2,
                                                    float4* __restrict__ x2) {
  long gid = (long)blockIdx.x * 256 + threadIdx.x;
  if (gid >= (long)NN * 16) return;
  int i = (int)(gid >> 4), c8 = (int)(gid & 15);
  float sw = selfw[i];
  float iv = inv[i];
  uint4 xv = xp[(size_t)i * 16 + c8];
  float2 p0 = unpk(xv.x), p1 = unpk(xv.y), p2 = unpk(xv.z), p3 = unpk(xv.w);
  float a0 = sw * p0.x, a1 = sw * p0.y, a2 = sw * p1.x, a3 = sw * p1.y;
  float a4 = sw * p2.x, a5 = sw * p2.y, a6 = sw * p3.x, a7 = sw * p3.y;
  int s0 = off[i], s1 = off[i + 1];
  int e = s0;
  for (; e + 1 < s1; e += 2) {
    int sA = esrc[e], sB = esrc[e + 1];
    float wA = aw[e], wB = aw[e + 1];
    uint4 mA = xp[(size_t)sA * 16 + c8];
    uint4 mB = xp[(size_t)sB * 16 + c8];
    float2 q0 = unpk(mA.x), q1 = unpk(mA.y), q2 = unpk(mA.z), q3 = unpk(mA.w);
    a0 = fmaf(wA, q0.x, a0); a1 = fmaf(wA, q0.y, a1);
    a2 = fmaf(wA, q1.x, a2); a3 = fmaf(wA, q1.y, a3);
    a4 = fmaf(wA, q2.x, a4); a5 = fmaf(wA, q2.y, a5);
    a6 = fmaf(wA, q3.x, a6); a7 = fmaf(wA, q3.y, a7);
    q0 = unpk(mB.x); q1 = unpk(mB.y); q2 = unpk(mB.z); q3 = unpk(mB.w);
    a0 = fmaf(wB, q0.x, a0); a1 = fmaf(wB, q0.y, a1);
    a2 = fmaf(wB, q1.x, a2); a3 = fmaf(wB, q1.y, a3);
    a4 = fmaf(wB, q2.x, a4); a5 = fmaf(wB, q2.y, a5);
    a6 = fmaf(wB, q3.x, a6); a7 = fmaf(wB, q3.y, a7);
  }
  if (e < s1) {
    int sA = esrc[e];
    float wA = aw[e];
    uint4 mA = xp[(size_t)sA * 16 + c8];
    float2 q0 = unpk(mA.x), q1 = unpk(mA.y), q2 = unpk(mA.z), q3 = unpk(mA.w);
    a0 = fmaf(wA, q0.x, a0); a1 = fmaf(wA, q0.y, a1);
    a2 = fmaf(wA, q1.x, a2); a3 = fmaf(wA, q1.y, a3);
    a4 = fmaf(wA, q2.x, a4); a5 = fmaf(wA, q2.y, a5);
    a6 = fmaf(wA, q3.x, a6); a7 = fmaf(wA, q3.y, a7);
  }
  float4 bb0 = ((const float4*)b2)[c8 * 2];
  float4 bb1 = ((const float4*)b2)[c8 * 2 + 1];
  a0 = a0 * iv + bb0.x; a1 = a1 * iv + bb0.y; a2 = a2 * iv + bb0.z; a3 = a3 * iv + bb0.w;
  a4 = a4 * iv + bb1.x; a5 = a5 * iv + bb1.y; a6 = a6 * iv + bb1.z; a7 = a7 * iv + bb1.w;
  a0 = a0 > 0.f ? a0 : (__expf(a0) - 1.f);
  a1 = a1 > 0.f ? a1 : (__expf(a1) - 1.f);
  a2 = a2 > 0.f ? a2 : (__expf(a2) - 1.f);
  a3 = a3 > 0.f ? a3 : (__expf(a3) - 1.f);
  a4 = a4 > 0.f ? a4 : (__expf(a4) - 1.f);
  a5 = a5 > 0.f ? a5 : (__expf(a5) - 1.f);
  a6 = a6 > 0.f ? a6 : (__expf(a6) - 1.f);
  a7 = a7 > 0.f ? a7 : (__expf(a7) - 1.f);
  x2[gid * 2] = make_float4(a0, a1, a2, a3);
  x2[gid * 2 + 1] = make_float4(a4, a5, a6, a7);
}

// ---------------- fused pool + h1 GEMM + head2: one block (128 thr) per graph ----------------
__global__ __launch_bounds__(128) void tail_kernel(const float* __restrict__ x2,
                                                   const int* __restrict__ m_idx,
                                                   const float* __restrict__ Wo1,
                                                   const float* __restrict__ bo1,
                                                   const float* __restrict__ Wo2,
                                                   const float* __restrict__ bo2,
                                                   float* __restrict__ out) {
  __shared__ float pl[128];
  __shared__ float red[128];
  int g = blockIdx.x, c = threadIdx.x;
  float acc = 0.f, cnt = 0.f;
  const float* xr = x2 + (size_t)g * 64 * 128;
  const int* mi = m_idx + g * 64;
  for (int n = 0; n < 64; n++) {
    if (mi[n] >= 1) { cnt += 1.f; acc += xr[n * 128 + c]; }
  }
  pl[c] = acc / cnt;
  __syncthreads();
  float h = bo1[c];
  for (int k = 0; k < 128; k++) h = fmaf(pl[k], Wo1[(size_t)k * 128 + c], h);
  h = h > 0.f ? h : 0.01f * h;
  red[c] = h * Wo2[c];
  __syncthreads();
  for (int d = 64; d; d >>= 1) {
    if (c < d) red[c] += red[c + d];
    __syncthreads();
  }
  if (c == 0) out[g] = red[0] + bo2[0];
}

extern "C" void kernel_launch(void* const* d_in, const int* in_sizes, int n_in, void* d_out,
                              int out_size, void* d_ws, size_t ws_size, hipStream_t stream) {
  (void)n_in; (void)out_size; (void)ws_size;
  bool dict_order = (in_sizes[2] == NN);
  int IM, IE, IF[25];
  if (dict_order) {
    IM = 2; IE = 3;
    const int f[25] = {0, 1, 4, 5, 6, 7, 8, 9, 10, 11, 12, 13, 14, 15, 16, 17, 18,
                       19, 20, 21, 22, 23, 24, 25, 26};
    for (int k = 0; k < 25; k++) IF[k] = f[k];
  } else {
    IM = 25; IE = 26;
    for (int k = 0; k < 25; k++) IF[k] = k;
  }
  const int* m_idx = (const int*)d_in[IM];
  const int* eidx = (const int*)d_in[IE];
  float* out = (float*)d_out;
  const int* e_src = eidx;
  const int* e_dst = eidx + EE;

  const float* t = (const float*)d_in[IF[0]];
  const float* v = (const float*)d_in[IF[1]];
  const float* Wt = (const float*)d_in[IF[2]];     const float* bt = (const float*)d_in[IF[3]];
  const float* Wv = (const float*)d_in[IF[4]];     const float* bv = (const float*)d_in[IF[5]];
  const float* emb = (const float*)d_in[IF[6]];
  const float* Wnode = (const float*)d_in[IF[7]];  const float* bnode = (const float*)d_in[IF[8]];
  const float* Wstart = (const float*)d_in[IF[9]]; const float* bstart = (const float*)d_in[IF[10]];
  const float* ln_g = (const float*)d_in[IF[11]];  const float* ln_b = (const float*)d_in[IF[12]];
  const float* W1 = (const float*)d_in[IF[13]];
  const float* a_src1 = (const float*)d_in[IF[14]]; const float* a_dst1 = (const float*)d_in[IF[15]];
  const float* b1 = (const float*)d_in[IF[16]];
  const float* W2 = (const float*)d_in[IF[17]];
  const float* a_src2 = (const float*)d_in[IF[18]]; const float* a_dst2 = (const float*)d_in[IF[19]];
  const float* b2 = (const float*)d_in[IF[20]];
  const float* Wo1 = (const float*)d_in[IF[21]];   const float* bo1 = (const float*)d_in[IF[22]];
  const float* Wo2 = (const float*)d_in[IF[23]];   const float* bo2 = (const float*)d_in[IF[24]];

  // workspace layout (peak ~96 MB)
  char* w = (char*)d_ws;
  bf16* y1 = (bf16*)(w);                             // [NN,4,128] bf16 [0,32) MB
  bf16* x0b = (bf16*)(w + ((size_t)32 << 20));       // [NN,128] bf16 [32,40) MB
  bf16* x1 = (bf16*)(w + ((size_t)48 << 20));        // [NN,512] bf16 [48,80) MB
  bf16* xp2b = (bf16*)(w);                           // [NN,128] bf16 [0,8)  (y1 dead)
  float* x2 = (float*)(w + ((size_t)8 << 20));       // [NN,128] f32 [8,24)
  size_t so = (size_t)80 << 20;                      // smalls [80,~96) MB
  bf16* t_b = (bf16*)(w + so); so += 512 * 768 * 2;
  bf16* v_b = (bf16*)(w + so); so += 512 * 768 * 2;
  bf16* vt_b = (bf16*)(w + so); so += 512 * 256 * 2;
  bf16* start_b = (bf16*)(w + so); so += 512 * 128 * 2;
  bf16* emb2_b = (bf16*)(w + so); so += 51 * 128 * 2 + 256;
  float* als1 = (float*)(w + so); so += NN * 4 * 4;
  float* ald1 = (float*)(w + so); so += NN * 4 * 4;
  float* als2 = (float*)(w + so); so += NN * 4;
  float* ald2 = (float*)(w + so); so += NN * 4;
  float* aw1 = (float*)(w + so); so += EE * 4 * 4;   // 4 MB
  float* selfw1 = (float*)(w + so); so += NN * 4 * 4;
  float* inv1 = (float*)(w + so); so += NN * 4 * 4;
  float* aw2 = (float*)(w + so); so += EE * 4;       // 1 MB
  float* selfw2 = (float*)(w + so); so += NN * 4;
  float* inv2 = (float*)(w + so); so += NN * 4;
  float* ws1 = (float*)(w + so); so += 512 * 4;
  float* wd1 = (float*)(w + so); so += 512 * 4;
  int* indeg = (int*)(w + so); so += NN * 4;
  int* csroff = (int*)(w + so); so += (NN + 1) * 4 + 252;
  int* cursor = (int*)(w + so); so += NN * 4;
  int* esrc = (int*)(w + so); so += EE * 4;
  s8v* Bp1 = (s8v*)(w + so); so += 32 * 4 * 64 * 16;    // conv1 W1 frags (K=128,N=512)
  s8v* Bp2 = (s8v*)(w + so); so += 8 * 16 * 64 * 16;    // conv2 W2 frags
  s8v* BpWv = (s8v*)(w + so); so += 8 * 24 * 64 * 16;   // Wv frags
  s8v* BpWt = (s8v*)(w + so); so += 8 * 24 * 64 * 16;   // Wt frags
  s8v* BpWs = (s8v*)(w + so); so += 8 * 8 * 64 * 16;    // Wstart frags

  // ---- CSR build ----
  hipMemsetAsync(indeg, 0, NN * 4, stream);
  hist_kernel<<<EE / 256, 256, 0, stream>>>(e_dst, indeg);
  scan_kernel<<<1, 1024, 0, stream>>>(indeg, csroff, cursor);
  fill_kernel<<<EE / 256, 256, 0, stream>>>(e_src, e_dst, cursor, esrc);

  // pack weights + convert t,v + fold conv1 score vectors
  packall_kernel<<<176, 256, 0, stream>>>(W1, Bp1, W2, Bp2, Wv, BpWv, Wt, BpWt, Wstart, BpWs);
  cvtpk2_kernel<<<1536, 256, 0, stream>>>((const float2*)t, (unsigned*)t_b,
                                          (const float2*)v, (unsigned*)v_b, 512 * 384);
  fold1_kernel<<<2, 256, 0, stream>>>(W1, a_src1, a_dst1, ws1, wd1);

  // emb2 (tiny), bf16 out
  sgemm_kernel<bf16><<<(51 * 128 + 63) / 64, 256, 0, stream>>>(emb, Wnode, bnode, emb2_b, 51, 128, 128, 128, 0);

  // ve/te/start via MFMA
  gemm_mfma<<<dim3(2, 8), 256, 0, stream>>>((const short*)v_b, BpWv, bv, (short*)vt_b, 512, 128, 768, 256);
  gemm_mfma<<<dim3(2, 8), 256, 0, stream>>>((const short*)t_b, BpWt, bt, (short*)(vt_b + 128), 512, 128, 768, 256);
  gemm_mfma<<<dim3(2, 8), 256, 0, stream>>>((const short*)vt_b, BpWs, bstart, (short*)start_b, 512, 128, 256, 128);

  // fused LN + conv1 scores
  ln_al1_wave<<<NN / 4, 256, 0, stream>>>((const unsigned*)start_b, (const unsigned*)emb2_b,
                                          m_idx, ln_g, ln_b, ws1, wd1, (unsigned*)x0b, als1, ald1);
  alpha1_kernel<<<NN * 4 / 256, 256, 0, stream>>>(als1, ald1, csroff, esrc, aw1, selfw1, inv1);
  agg1y_kernel<<<(int)(((long)NN * 16 + 255) / 256), 256, 0, stream>>>(
      (const uint4*)x0b, (const float4*)aw1, (const float4*)selfw1, (const float4*)inv1,
      csroff, esrc, (uint4*)y1);
  gemm_mfma_head<<<dim3(8, NN / 64), 256, 0, stream>>>((const short*)y1, Bp1, b1, (short*)x1, NN);

  // conv2: MFMA GEMM (N=128 in one block), then scores, weights, gather
  gemm_mfma8<<<dim3(1, NN / 64), 256, 0, stream>>>((const short*)x1, Bp2, (short*)xp2b, NN);
  al2_wave<<<NN / 4, 256, 0, stream>>>((const unsigned*)xp2b, a_src2, a_dst2, als2, ald2);
  alpha2_kernel<<<NN / 256, 256, 0, stream>>>(als2, ald2, csroff, esrc, aw2, selfw2, inv2);
  agg2w_kernel<<<(int)(((long)NN * 16 + 255) / 256), 256, 0, stream>>>(
      (const uint4*)xp2b, aw2, selfw2, inv2, csroff, esrc, b2, (float4*)x2);

  // fused pool + h1 + head
  tail_kernel<<<GG, 128, 0, stream>>>(x2, m_idx, Wo1, bo1, Wo2, bo2, out);
}

// Round 18
// 333.552 us; speedup vs baseline: 7.4359x; 1.0304x over previous
//
#include <hip/hip_runtime.h>
#include <hip/hip_bf16.h>

typedef __hip_bfloat16 bf16;
typedef __attribute__((ext_vector_type(8))) short s8v;   // 8 bf16 (4 VGPRs)
typedef __attribute__((ext_vector_type(4))) float f4v;   // 4 fp32 acc

#define NN 32768   // total nodes
#define EE 262144  // edges
#define GG 512     // graphs
#define LDW 520    // padded LDS row stride (bf16 elems): 520*2B -> bank stride 4, 2-way (free)

__device__ __forceinline__ float2 unpk(unsigned u) {
  float2 r;
  r.x = __uint_as_float(u << 16);
  r.y = __uint_as_float(u & 0xffff0000u);
  return r;
}
__device__ __forceinline__ unsigned pk(float x, float y) {
  union { bf16 h[2]; unsigned u; } p;
  p.h[0] = __float2bfloat16(x);
  p.h[1] = __float2bfloat16(y);
  return p.u;
}
__device__ __forceinline__ short f2bf_bits(float x) {
  bf16 h = __float2bfloat16(x);
  return *reinterpret_cast<short*>(&h);
}
__device__ __forceinline__ void storef(float* p, float v) { *p = v; }
__device__ __forceinline__ void storef(bf16* p, float v) { *p = __float2bfloat16(v); }

__device__ __forceinline__ float wred_sum(float v) {
#pragma unroll
  for (int o = 32; o; o >>= 1) v += __shfl_xor(v, o, 64);
  return v;
}

// ---------------- CSR build ----------------
__global__ __launch_bounds__(256) void hist_kernel(const int* __restrict__ dst,
                                                   int* __restrict__ indeg) {
  int e = blockIdx.x * 256 + threadIdx.x;
  if (e < EE) atomicAdd(&indeg[dst[e]], 1);
}

__global__ __launch_bounds__(1024) void scan_kernel(const int* __restrict__ indeg,
                                                    int* __restrict__ off,
                                                    int* __restrict__ cursor) {
  __shared__ int sh[1024];
  int t = threadIdx.x;
  int loc[32];
  int s = 0;
  int base = t * 32;
#pragma unroll
  for (int j = 0; j < 32; j++) { loc[j] = indeg[base + j]; s += loc[j]; }
  sh[t] = s;
  __syncthreads();
  for (int d = 1; d < 1024; d <<= 1) {
    int v = (t >= d) ? sh[t - d] : 0;
    __syncthreads();
    sh[t] += v;
    __syncthreads();
  }
  int run = (t == 0) ? 0 : sh[t - 1];
#pragma unroll
  for (int j = 0; j < 32; j++) { off[base + j] = run; cursor[base + j] = run; run += loc[j]; }
  if (t == 1023) off[NN] = run;
}

__global__ __launch_bounds__(256) void fill_kernel(const int* __restrict__ src,
                                                   const int* __restrict__ dst,
                                                   int* __restrict__ cursor,
                                                   int* __restrict__ esrc) {
  int e = blockIdx.x * 256 + threadIdx.x;
  if (e < EE) {
    int p = atomicAdd(&cursor[dst[e]], 1);
    esrc[p] = src[e];
  }
}

// ---------------- fp32 -> packed bf16 conversion (t and v in one launch) ----------------
__global__ __launch_bounds__(256) void cvtpk2_kernel(const float2* __restrict__ a,
                                                     unsigned* __restrict__ da,
                                                     const float2* __restrict__ b,
                                                     unsigned* __restrict__ db, int n2) {
  int id = blockIdx.x * 256 + threadIdx.x;
  if (id < n2) { float2 v = a[id]; da[id] = pk(v.x, v.y); }
  else if (id < 2 * n2) { int j = id - n2; float2 v = b[j]; db[j] = pk(v.x, v.y); }
}

// ---------------- small GEMM, split-K (tiny problems) ----------------
template <typename TC>
__global__ __launch_bounds__(256) void sgemm_kernel(const float* __restrict__ A,
                                                    const float* __restrict__ B,
                                                    const float* __restrict__ bias,
                                                    TC* __restrict__ C,
                                                    int M, int N, int K, int ldc, int act) {
  __shared__ float red[256];
  int tid = threadIdx.x;
  int lo = tid & 63;
  int slice = tid >> 6;
  long oid = (long)blockIdx.x * 64 + lo;
  bool live = (oid < (long)M * N);
  int m = 0, n = 0;
  if (live) { m = (int)(oid / N); n = (int)(oid % N); }
  int kq = K >> 2;
  int k0 = slice * kq, k1 = k0 + kq;
  float acc = 0.f;
  if (live) {
    const float* Ar = A + (size_t)m * K;
    for (int k = k0; k < k1; k++) acc = fmaf(Ar[k], B[(size_t)k * N + n], acc);
  }
  red[tid] = acc;
  __syncthreads();
  if (slice == 0 && live) {
    float v = red[lo] + red[64 + lo] + red[128 + lo] + red[192 + lo];
    if (bias) v += bias[n];
    if (act == 1) v = v > 0.f ? v : 0.01f * v;
    storef(&C[(size_t)m * ldc + n], v);
  }
}

// ---------------- pack all 5 weights into MFMA B-fragment order, one launch ----------------
__device__ __forceinline__ void packB_one(const float* W, int N, int K, int id, s8v* Bp) {
  int lane = id & 63;
  int tmp = id >> 6;
  int ksteps = K >> 5;
  int ks = tmp % ksteps;
  int nt = tmp / ksteps;
  int n = nt * 16 + (lane & 15);
  int kbase = ks * 32 + (lane >> 4) * 8;
  s8v r;
#pragma unroll
  for (int j = 0; j < 8; j++) r[j] = f2bf_bits(W[(size_t)(kbase + j) * N + n]);
  Bp[id] = r;
}

// blocks: [0,32) W1, [32,64) W2, [64,112) Wv, [112,160) Wt, [160,176) Wstart
__global__ __launch_bounds__(256) void packall_kernel(const float* __restrict__ W1, s8v* Bp1,
                                                      const float* __restrict__ W2, s8v* Bp2,
                                                      const float* __restrict__ Wv, s8v* BpWv,
                                                      const float* __restrict__ Wt, s8v* BpWt,
                                                      const float* __restrict__ Ws, s8v* BpWs) {
  int b = blockIdx.x;
  if (b < 32)        packB_one(W1, 512, 128, b * 256 + threadIdx.x, Bp1);
  else if (b < 64)   packB_one(W2, 128, 512, (b - 32) * 256 + threadIdx.x, Bp2);
  else if (b < 112)  packB_one(Wv, 128, 768, (b - 64) * 256 + threadIdx.x, BpWv);
  else if (b < 160)  packB_one(Wt, 128, 768, (b - 112) * 256 + threadIdx.x, BpWt);
  else               packB_one(Ws, 128, 256, (b - 160) * 256 + threadIdx.x, BpWs);
}

// ---------------- fold a_src/a_dst through W1 ----------------
__global__ __launch_bounds__(256) void fold1_kernel(const float* __restrict__ W1,
                                                    const float* __restrict__ a_src1,
                                                    const float* __restrict__ a_dst1,
                                                    float* __restrict__ ws1,
                                                    float* __restrict__ wd1) {
  int id = blockIdx.x * 256 + threadIdx.x;
  if (id >= 512) return;
  int h = id >> 7, k = id & 127;
  float s = 0.f, d = 0.f;
  for (int c = 0; c < 128; c++) {
    float w = W1[(size_t)k * 512 + h * 128 + c];
    s = fmaf(w, a_src1[h * 128 + c], s);
    d = fmaf(w, a_dst1[h * 128 + c], d);
  }
  ws1[id] = s;
  wd1[id] = d;
}

// ---------------- MFMA bf16 GEMM, optional fp32 bias, bf16 out with ldc ----------------
__global__ __launch_bounds__(256) void gemm_mfma(const short* __restrict__ A,
                                                 const s8v* __restrict__ Bp,
                                                 const float* __restrict__ bias,
                                                 short* __restrict__ C,
                                                 int M, int N, int K, int ldc) {
  __shared__ short lds[64 * 64];
  int tid = threadIdx.x;
  int wv = tid >> 6, lane = tid & 63;
  int quad = lane >> 4, l16 = lane & 15;
  int brow = blockIdx.y * 64, bcol = blockIdx.x * 64;
  int m = brow + wv * 16 + l16;
  int ksteps = K >> 5;
  f4v acc[4] = {};
  const s8v* Arow = (const s8v*)(A + (size_t)m * K);
  for (int ks = 0; ks < ksteps; ks++) {
    s8v a = Arow[ks * 4 + quad];
#pragma unroll
    for (int nt = 0; nt < 4; nt++) {
      s8v b = Bp[(size_t)(((bcol >> 4) + nt) * ksteps + ks) * 64 + lane];
      acc[nt] = __builtin_amdgcn_mfma_f32_16x16x32_bf16(a, b, acc[nt], 0, 0, 0);
    }
  }
#pragma unroll
  for (int nt = 0; nt < 4; nt++) {
    float bv = bias ? bias[bcol + nt * 16 + l16] : 0.f;
#pragma unroll
    for (int r = 0; r < 4; r++)
      lds[(wv * 16 + quad * 4 + r) * 64 + nt * 16 + l16] = f2bf_bits(acc[nt][r] + bv);
  }
  __syncthreads();
#pragma unroll
  for (int rep = 0; rep < 2; rep++) {
    int idx = rep * 256 + tid;
    int row = idx >> 3, c16 = idx & 7;
    uint4 val = ((const uint4*)lds)[idx];
    *(uint4*)(C + (size_t)(brow + row) * ldc + bcol + c16 * 8) = val;
  }
}

// ---------------- merged ve/te GEMM: grid y<8 -> v, else t (writes vt halves) ----------------
__global__ __launch_bounds__(256) void gemm_mfma_vt(const short* __restrict__ Av,
                                                    const s8v* __restrict__ Bpv,
                                                    const float* __restrict__ biasv,
                                                    const short* __restrict__ At,
                                                    const s8v* __restrict__ Bpt,
                                                    const float* __restrict__ biast,
                                                    short* __restrict__ C) {
  __shared__ short lds[64 * 64];
  bool isT = blockIdx.y >= 8;
  const short* A = isT ? At : Av;
  const s8v* Bp = isT ? Bpt : Bpv;
  const float* bias = isT ? biast : biasv;
  int coff = isT ? 128 : 0;
  int browIdx = isT ? (blockIdx.y - 8) : blockIdx.y;
  int tid = threadIdx.x;
  int wv = tid >> 6, lane = tid & 63;
  int quad = lane >> 4, l16 = lane & 15;
  int brow = browIdx * 64, bcol = blockIdx.x * 64;
  int m = brow + wv * 16 + l16;
  f4v acc[4] = {};
  const s8v* Arow = (const s8v*)(A + (size_t)m * 768);
  for (int ks = 0; ks < 24; ks++) {
    s8v a = Arow[ks * 4 + quad];
#pragma unroll
    for (int nt = 0; nt < 4; nt++) {
      s8v b = Bp[(size_t)(((bcol >> 4) + nt) * 24 + ks) * 64 + lane];
      acc[nt] = __builtin_amdgcn_mfma_f32_16x16x32_bf16(a, b, acc[nt], 0, 0, 0);
    }
  }
#pragma unroll
  for (int nt = 0; nt < 4; nt++) {
    float bv = bias[bcol + nt * 16 + l16];
#pragma unroll
    for (int r = 0; r < 4; r++)
      lds[(wv * 16 + quad * 4 + r) * 64 + nt * 16 + l16] = f2bf_bits(acc[nt][r] + bv);
  }
  __syncthreads();
#pragma unroll
  for (int rep = 0; rep < 2; rep++) {
    int idx = rep * 256 + tid;
    int row = idx >> 3, c16 = idx & 7;
    uint4 val = ((const uint4*)lds)[idx];
    *(uint4*)(C + (size_t)(brow + row) * 256 + coff + bcol + c16 * 8) = val;
  }
}

// ---------------- FUSED conv1 head-GEMM + ELU + conv2 GEMM + al2 scores ----------------
// block = 64 rows (nodes); x1 tile lives in LDS; xp2 written to global; als2/ald2 computed.
__global__ __launch_bounds__(256) void conv12_kernel(const short* __restrict__ y1,
                                                     const s8v* __restrict__ Bp1,
                                                     const float* __restrict__ b1,
                                                     const s8v* __restrict__ Bp2,
                                                     const float* __restrict__ a_src2,
                                                     const float* __restrict__ a_dst2,
                                                     short* __restrict__ xp2,
                                                     float* __restrict__ als2,
                                                     float* __restrict__ ald2) {
  __shared__ short lds[64 * LDW];
  int tid = threadIdx.x;
  int wv = tid >> 6, lane = tid & 63;
  int quad = lane >> 4, l16 = lane & 15;
  int brow = blockIdx.y * 64;
  int m = brow + wv * 16 + l16;
  // phase 1: x1 = ELU(y1 @ W1_head + b1) -> LDS (head by head, acc reuse)
  for (int h = 0; h < 4; h++) {
    f4v acc[8] = {};
    const s8v* Arow = (const s8v*)(y1 + (size_t)m * 512 + h * 128);
#pragma unroll
    for (int ks = 0; ks < 4; ks++) {
      s8v a = Arow[ks * 4 + quad];
#pragma unroll
      for (int nt = 0; nt < 8; nt++) {
        s8v b = Bp1[(size_t)((h * 8 + nt) * 4 + ks) * 64 + lane];
        acc[nt] = __builtin_amdgcn_mfma_f32_16x16x32_bf16(a, b, acc[nt], 0, 0, 0);
      }
    }
#pragma unroll
    for (int nt = 0; nt < 8; nt++) {
      float bv = b1[h * 128 + nt * 16 + l16];
#pragma unroll
      for (int r = 0; r < 4; r++) {
        float vv = acc[nt][r] + bv;
        vv = vv > 0.f ? vv : (__expf(vv) - 1.f);
        lds[(wv * 16 + quad * 4 + r) * LDW + h * 128 + nt * 16 + l16] = f2bf_bits(vv);
      }
    }
  }
  __syncthreads();
  // phase 2: xp2 = x1 @ W2 (K=512, N=128), A from LDS (wave reads only its own rows)
  f4v acc2[8] = {};
  int arow = (wv * 16 + l16) * LDW;
  for (int ks = 0; ks < 16; ks++) {
    s8v a = *(const s8v*)(lds + arow + ks * 32 + quad * 8);
#pragma unroll
    for (int nt = 0; nt < 8; nt++) {
      s8v b = Bp2[(size_t)(nt * 16 + ks) * 64 + lane];
      acc2[nt] = __builtin_amdgcn_mfma_f32_16x16x32_bf16(a, b, acc2[nt], 0, 0, 0);
    }
  }
  // restage xp2 tile into own rows (reads of those rows are complete for this wave)
#pragma unroll
  for (int nt = 0; nt < 8; nt++)
#pragma unroll
    for (int r = 0; r < 4; r++)
      lds[(wv * 16 + quad * 4 + r) * LDW + nt * 16 + l16] = f2bf_bits(acc2[nt][r]);
  // phase 3: al2 scores for this wave's 16 rows (from LDS)
  float2 as = ((const float2*)a_src2)[lane];
  float2 ad = ((const float2*)a_dst2)[lane];
  for (int r = 0; r < 16; r++) {
    int row = wv * 16 + r;
    float2 x = unpk(*(const unsigned*)(lds + row * LDW + lane * 2));
    float ps = wred_sum(x.x * as.x + x.y * as.y);
    float pd = wred_sum(x.x * ad.x + x.y * ad.y);
    if (lane == 0) { als2[brow + row] = ps; ald2[brow + row] = pd; }
  }
  __syncthreads();
  // coalesced store of xp2 tile
#pragma unroll
  for (int rep = 0; rep < 4; rep++) {
    int idx = rep * 256 + tid;
    int row = idx >> 4, c16 = idx & 15;
    uint4 val = *(const uint4*)(lds + row * LDW + c16 * 8);
    *(uint4*)(xp2 + (size_t)(brow + row) * 128 + c16 * 8) = val;
  }
}

// ---------------- fused layernorm + conv1 scores (wave per node) ----------------
__global__ __launch_bounds__(256) void ln_al1_wave(const unsigned* __restrict__ start_b,
                                                   const unsigned* __restrict__ emb2_b,
                                                   const int* __restrict__ m_idx,
                                                   const float* __restrict__ lng,
                                                   const float* __restrict__ lnb,
                                                   const float* __restrict__ ws1,
                                                   const float* __restrict__ wd1,
                                                   unsigned* __restrict__ x0b,
                                                   float* __restrict__ als,
                                                   float* __restrict__ ald) {
  int i = blockIdx.x * 4 + (threadIdx.x >> 6);
  int lane = threadIdx.x & 63;
  int g = i >> 6, n = i & 63;
  const unsigned* row = (n == 0) ? (start_b + (size_t)g * 64) : (emb2_b + (size_t)m_idx[i] * 64);
  float2 v = unpk(row[lane]);
  float mu = wred_sum(v.x + v.y) * (1.f / 128.f);
  float dx = v.x - mu, dy = v.y - mu;
  float var = wred_sum(dx * dx + dy * dy) * (1.f / 128.f);
  float rstd = rsqrtf(var + 1e-6f);
  float2 gg = ((const float2*)lng)[lane];
  float2 bb = ((const float2*)lnb)[lane];
  float xx = dx * rstd * gg.x + bb.x;
  float xy = dy * rstd * gg.y + bb.y;
  x0b[(size_t)i * 64 + lane] = pk(xx, xy);
#pragma unroll
  for (int h = 0; h < 4; h++) {
    float2 s2 = ((const float2*)(ws1 + h * 128))[lane];
    float2 d2 = ((const float2*)(wd1 + h * 128))[lane];
    float ps = wred_sum(xx * s2.x + xy * s2.y);
    float pd = wred_sum(xx * d2.x + xy * d2.y);
    if (lane == 0) { als[i * 4 + h] = ps; ald[i * 4 + h] = pd; }
  }
}

// ---------------- softmax weights, single pass (scores bounded) ----------------
__global__ __launch_bounds__(256) void alpha1_kernel(const float* __restrict__ als,
                                                     const float* __restrict__ ald,
                                                     const int* __restrict__ off,
                                                     const int* __restrict__ esrc,
                                                     float* __restrict__ aw,
                                                     float* __restrict__ selfw,
                                                     float* __restrict__ inv) {
  int id = blockIdx.x * 256 + threadIdx.x;
  if (id >= NN * 4) return;
  int i = id >> 2, h = id & 3;
  float adi = ald[id];
  float selfSc = als[id] + adi;
  selfSc = selfSc > 0.f ? selfSc : 0.2f * selfSc;
  float sw = __expf(selfSc);
  float denom = sw;
  int s0 = off[i], s1 = off[i + 1];
  for (int e = s0; e < s1; e++) {
    float sc = als[esrc[e] * 4 + h] + adi;
    sc = sc > 0.f ? sc : 0.2f * sc;
    float w = __expf(sc);
    aw[e * 4 + h] = w;
    denom += w;
  }
  selfw[id] = sw;
  inv[id] = 1.f / denom;
}

__global__ __launch_bounds__(256) void alpha2_kernel(const float* __restrict__ als,
                                                     const float* __restrict__ ald,
                                                     const int* __restrict__ off,
                                                     const int* __restrict__ esrc,
                                                     float* __restrict__ aw,
                                                     float* __restrict__ selfw,
                                                     float* __restrict__ inv) {
  int i = blockIdx.x * 256 + threadIdx.x;
  if (i >= NN) return;
  float adi = ald[i];
  float selfSc = als[i] + adi;
  selfSc = selfSc > 0.f ? selfSc : 0.2f * selfSc;
  float sw = __expf(selfSc);
  float denom = sw;
  int s0 = off[i], s1 = off[i + 1];
  for (int e = s0; e < s1; e++) {
    float sc = als[esrc[e]] + adi;
    sc = sc > 0.f ? sc : 0.2f * sc;
    float w = __expf(sc);
    aw[e] = w;
    denom += w;
  }
  selfw[i] = sw;
  inv[i] = 1.f / denom;
}

// ---------------- conv1 aggregation in input space: thread per (node, uint4 of x0) ----------------
__global__ __launch_bounds__(256) void agg1y_kernel(const uint4* __restrict__ x0,
                                                    const float4* __restrict__ aw4,
                                                    const float4* __restrict__ selfw4,
                                                    const float4* __restrict__ inv4,
                                                    const int* __restrict__ off,
                                                    const int* __restrict__ esrc,
                                                    uint4* __restrict__ y1) {
  long gid = (long)blockIdx.x * 256 + threadIdx.x;
  if (gid >= (long)NN * 16) return;
  int i = (int)(gid >> 4), c8 = (int)(gid & 15);
  float4 sw = selfw4[i];
  uint4 xv = x0[(size_t)i * 16 + c8];
  float x[8];
  { float2 p0 = unpk(xv.x), p1 = unpk(xv.y), p2 = unpk(xv.z), p3 = unpk(xv.w);
    x[0]=p0.x; x[1]=p0.y; x[2]=p1.x; x[3]=p1.y; x[4]=p2.x; x[5]=p2.y; x[6]=p3.x; x[7]=p3.y; }
  float acc[4][8];
#pragma unroll
  for (int j = 0; j < 8; j++) {
    acc[0][j] = sw.x * x[j]; acc[1][j] = sw.y * x[j];
    acc[2][j] = sw.z * x[j]; acc[3][j] = sw.w * x[j];
  }
  int s0 = off[i], s1 = off[i + 1];
  for (int e = s0; e < s1; e++) {
    int s = esrc[e];
    float4 wv = aw4[e];
    uint4 m = x0[(size_t)s * 16 + c8];
    float2 q0 = unpk(m.x), q1 = unpk(m.y), q2 = unpk(m.z), q3 = unpk(m.w);
    float q[8] = {q0.x, q0.y, q1.x, q1.y, q2.x, q2.y, q3.x, q3.y};
#pragma unroll
    for (int j = 0; j < 8; j++) {
      acc[0][j] = fmaf(wv.x, q[j], acc[0][j]);
      acc[1][j] = fmaf(wv.y, q[j], acc[1][j]);
      acc[2][j] = fmaf(wv.z, q[j], acc[2][j]);
      acc[3][j] = fmaf(wv.w, q[j], acc[3][j]);
    }
  }
  float4 iv = inv4[i];
  float ivh[4] = {iv.x, iv.y, iv.z, iv.w};
#pragma unroll
  for (int h = 0; h < 4; h++) {
    uint4 o;
    o.x = pk(acc[h][0] * ivh[h], acc[h][1] * ivh[h]);
    o.y = pk(acc[h][2] * ivh[h], acc[h][3] * ivh[h]);
    o.z = pk(acc[h][4] * ivh[h], acc[h][5] * ivh[h]);
    o.w = pk(acc[h][6] * ivh[h], acc[h][7] * ivh[h]);
    y1[((size_t)i * 4 + h) * 16 + c8] = o;
  }
}

// ---------------- weighted gather, conv2: thread per (node, uint4 = 8 cols) ----------------
__global__ __launch_bounds__(256) void agg2w_kernel(const uint4* __restrict__ xp,
                                                    const float* __restrict__ aw,
                                                    const float* __restrict__ selfw,
                                                    const float* __restrict__ inv,
                                                    const int* __restrict__ off,
                                                    const int* __restrict__ esrc,
                                                    const float* __restrict__ b2,
                                                    float4* __restrict__ x2) {
  long gid = (long)blockIdx.x * 256 + threadIdx.x;
  if (gid >= (long)NN * 16) return;
  int i = (int)(gid >> 4), c8 = (int)(gid & 15);
  float sw = selfw[i];
  float iv = inv[i];
  uint4 xv = xp[(size_t)i * 16 + c8];
  float2 p0 = unpk(xv.x), p1 = unpk(xv.y), p2 = unpk(xv.z), p3 = unpk(xv.w);
  float a0 = sw * p0.x, a1 = sw * p0.y, a2 = sw * p1.x, a3 = sw * p1.y;
  float a4 = sw * p2.x, a5 = sw * p2.y, a6 = sw * p3.x, a7 = sw * p3.y;
  int s0 = off[i], s1 = off[i + 1];
  int e = s0;
  for (; e + 1 < s1; e += 2) {
    int sA = esrc[e], sB = esrc[e + 1];
    float wA = aw[e], wB = aw[e + 1];
    uint4 mA = xp[(size_t)sA * 16 + c8];
    uint4 mB = xp[(size_t)sB * 16 + c8];
    float2 q0 = unpk(mA.x), q1 = unpk(mA.y), q2 = unpk(mA.z), q3 = unpk(mA.w);
    a0 = fmaf(wA, q0.x, a0); a1 = fmaf(wA, q0.y, a1);
    a2 = fmaf(wA, q1.x, a2); a3 = fmaf(wA, q1.y, a3);
    a4 = fmaf(wA, q2.x, a4); a5 = fmaf(wA, q2.y, a5);
    a6 = fmaf(wA, q3.x, a6); a7 = fmaf(wA, q3.y, a7);
    q0 = unpk(mB.x); q1 = unpk(mB.y); q2 = unpk(mB.z); q3 = unpk(mB.w);
    a0 = fmaf(wB, q0.x, a0); a1 = fmaf(wB, q0.y, a1);
    a2 = fmaf(wB, q1.x, a2); a3 = fmaf(wB, q1.y, a3);
    a4 = fmaf(wB, q2.x, a4); a5 = fmaf(wB, q2.y, a5);
    a6 = fmaf(wB, q3.x, a6); a7 = fmaf(wB, q3.y, a7);
  }
  if (e < s1) {
    int sA = esrc[e];
    float wA = aw[e];
    uint4 mA = xp[(size_t)sA * 16 + c8];
    float2 q0 = unpk(mA.x), q1 = unpk(mA.y), q2 = unpk(mA.z), q3 = unpk(mA.w);
    a0 = fmaf(wA, q0.x, a0); a1 = fmaf(wA, q0.y, a1);
    a2 = fmaf(wA, q1.x, a2); a3 = fmaf(wA, q1.y, a3);
    a4 = fmaf(wA, q2.x, a4); a5 = fmaf(wA, q2.y, a5);
    a6 = fmaf(wA, q3.x, a6); a7 = fmaf(wA, q3.y, a7);
  }
  float4 bb0 = ((const float4*)b2)[c8 * 2];
  float4 bb1 = ((const float4*)b2)[c8 * 2 + 1];
  a0 = a0 * iv + bb0.x; a1 = a1 * iv + bb0.y; a2 = a2 * iv + bb0.z; a3 = a3 * iv + bb0.w;
  a4 = a4 * iv + bb1.x; a5 = a5 * iv + bb1.y; a6 = a6 * iv + bb1.z; a7 = a7 * iv + bb1.w;
  a0 = a0 > 0.f ? a0 : (__expf(a0) - 1.f);
  a1 = a1 > 0.f ? a1 : (__expf(a1) - 1.f);
  a2 = a2 > 0.f ? a2 : (__expf(a2) - 1.f);
  a3 = a3 > 0.f ? a3 : (__expf(a3) - 1.f);
  a4 = a4 > 0.f ? a4 : (__expf(a4) - 1.f);
  a5 = a5 > 0.f ? a5 : (__expf(a5) - 1.f);
  a6 = a6 > 0.f ? a6 : (__expf(a6) - 1.f);
  a7 = a7 > 0.f ? a7 : (__expf(a7) - 1.f);
  x2[gid * 2] = make_float4(a0, a1, a2, a3);
  x2[gid * 2 + 1] = make_float4(a4, a5, a6, a7);
}

// ---------------- fused pool + h1 GEMM + head2: one block (128 thr) per graph ----------------
__global__ __launch_bounds__(128) void tail_kernel(const float* __restrict__ x2,
                                                   const int* __restrict__ m_idx,
                                                   const float* __restrict__ Wo1,
                                                   const float* __restrict__ bo1,
                                                   const float* __restrict__ Wo2,
                                                   const float* __restrict__ bo2,
                                                   float* __restrict__ out) {
  __shared__ float pl[128];
  __shared__ float red[128];
  int g = blockIdx.x, c = threadIdx.x;
  float acc = 0.f, cnt = 0.f;
  const float* xr = x2 + (size_t)g * 64 * 128;
  const int* mi = m_idx + g * 64;
  for (int n = 0; n < 64; n++) {
    if (mi[n] >= 1) { cnt += 1.f; acc += xr[n * 128 + c]; }
  }
  pl[c] = acc / cnt;
  __syncthreads();
  float h = bo1[c];
  for (int k = 0; k < 128; k++) h = fmaf(pl[k], Wo1[(size_t)k * 128 + c], h);
  h = h > 0.f ? h : 0.01f * h;
  red[c] = h * Wo2[c];
  __syncthreads();
  for (int d = 64; d; d >>= 1) {
    if (c < d) red[c] += red[c + d];
    __syncthreads();
  }
  if (c == 0) out[g] = red[0] + bo2[0];
}

extern "C" void kernel_launch(void* const* d_in, const int* in_sizes, int n_in, void* d_out,
                              int out_size, void* d_ws, size_t ws_size, hipStream_t stream) {
  (void)n_in; (void)out_size; (void)ws_size;
  bool dict_order = (in_sizes[2] == NN);
  int IM, IE, IF[25];
  if (dict_order) {
    IM = 2; IE = 3;
    const int f[25] = {0, 1, 4, 5, 6, 7, 8, 9, 10, 11, 12, 13, 14, 15, 16, 17, 18,
                       19, 20, 21, 22, 23, 24, 25, 26};
    for (int k = 0; k < 25; k++) IF[k] = f[k];
  } else {
    IM = 25; IE = 26;
    for (int k = 0; k < 25; k++) IF[k] = k;
  }
  const int* m_idx = (const int*)d_in[IM];
  const int* eidx = (const int*)d_in[IE];
  float* out = (float*)d_out;
  const int* e_src = eidx;
  const int* e_dst = eidx + EE;

  const float* t = (const float*)d_in[IF[0]];
  const float* v = (const float*)d_in[IF[1]];
  const float* Wt = (const float*)d_in[IF[2]];     const float* bt = (const float*)d_in[IF[3]];
  const float* Wv = (const float*)d_in[IF[4]];     const float* bv = (const float*)d_in[IF[5]];
  const float* emb = (const float*)d_in[IF[6]];
  const float* Wnode = (const float*)d_in[IF[7]];  const float* bnode = (const float*)d_in[IF[8]];
  const float* Wstart = (const float*)d_in[IF[9]]; const float* bstart = (const float*)d_in[IF[10]];
  const float* ln_g = (const float*)d_in[IF[11]];  const float* ln_b = (const float*)d_in[IF[12]];
  const float* W1 = (const float*)d_in[IF[13]];
  const float* a_src1 = (const float*)d_in[IF[14]]; const float* a_dst1 = (const float*)d_in[IF[15]];
  const float* b1 = (const float*)d_in[IF[16]];
  const float* W2 = (const float*)d_in[IF[17]];
  const float* a_src2 = (const float*)d_in[IF[18]]; const float* a_dst2 = (const float*)d_in[IF[19]];
  const float* b2 = (const float*)d_in[IF[20]];
  const float* Wo1 = (const float*)d_in[IF[21]];   const float* bo1 = (const float*)d_in[IF[22]];
  const float* Wo2 = (const float*)d_in[IF[23]];   const float* bo2 = (const float*)d_in[IF[24]];

  // workspace layout (peak ~96 MB)
  char* w = (char*)d_ws;
  bf16* y1 = (bf16*)(w);                             // [NN,512] bf16 [0,32) MB
  bf16* x0b = (bf16*)(w + ((size_t)32 << 20));       // [NN,128] bf16 [32,40) MB
  bf16* xp2b = (bf16*)(w + ((size_t)40 << 20));      // [NN,128] bf16 [40,48) MB (y1 LIVE during conv12)
  float* x2 = (float*)(w + ((size_t)48 << 20));      // [NN,128] f32 [48,64)
  size_t so = (size_t)80 << 20;                      // smalls [80,~96) MB
  bf16* t_b = (bf16*)(w + so); so += 512 * 768 * 2;
  bf16* v_b = (bf16*)(w + so); so += 512 * 768 * 2;
  bf16* vt_b = (bf16*)(w + so); so += 512 * 256 * 2;
  bf16* start_b = (bf16*)(w + so); so += 512 * 128 * 2;
  bf16* emb2_b = (bf16*)(w + so); so += 51 * 128 * 2 + 256;
  float* als1 = (float*)(w + so); so += NN * 4 * 4;
  float* ald1 = (float*)(w + so); so += NN * 4 * 4;
  float* als2 = (float*)(w + so); so += NN * 4;
  float* ald2 = (float*)(w + so); so += NN * 4;
  float* aw1 = (float*)(w + so); so += EE * 4 * 4;   // 4 MB
  float* selfw1 = (float*)(w + so); so += NN * 4 * 4;
  float* inv1 = (float*)(w + so); so += NN * 4 * 4;
  float* aw2 = (float*)(w + so); so += EE * 4;       // 1 MB
  float* selfw2 = (float*)(w + so); so += NN * 4;
  float* inv2 = (float*)(w + so); so += NN * 4;
  float* ws1 = (float*)(w + so); so += 512 * 4;
  float* wd1 = (float*)(w + so); so += 512 * 4;
  int* indeg = (int*)(w + so); so += NN * 4;
  int* csroff = (int*)(w + so); so += (NN + 1) * 4 + 252;
  int* cursor = (int*)(w + so); so += NN * 4;
  int* esrc = (int*)(w + so); so += EE * 4;
  s8v* Bp1 = (s8v*)(w + so); so += 32 * 4 * 64 * 16;    // conv1 W1 frags (K=128,N=512)
  s8v* Bp2 = (s8v*)(w + so); so += 8 * 16 * 64 * 16;    // conv2 W2 frags
  s8v* BpWv = (s8v*)(w + so); so += 8 * 24 * 64 * 16;   // Wv frags
  s8v* BpWt = (s8v*)(w + so); so += 8 * 24 * 64 * 16;   // Wt frags
  s8v* BpWs = (s8v*)(w + so); so += 8 * 8 * 64 * 16;    // Wstart frags

  // ---- CSR build ----
  hipMemsetAsync(indeg, 0, NN * 4, stream);
  hist_kernel<<<EE / 256, 256, 0, stream>>>(e_dst, indeg);
  scan_kernel<<<1, 1024, 0, stream>>>(indeg, csroff, cursor);
  fill_kernel<<<EE / 256, 256, 0, stream>>>(e_src, e_dst, cursor, esrc);

  // pack weights + convert t,v + fold conv1 score vectors
  packall_kernel<<<176, 256, 0, stream>>>(W1, Bp1, W2, Bp2, Wv, BpWv, Wt, BpWt, Wstart, BpWs);
  cvtpk2_kernel<<<1536, 256, 0, stream>>>((const float2*)t, (unsigned*)t_b,
                                          (const float2*)v, (unsigned*)v_b, 512 * 384);
  fold1_kernel<<<2, 256, 0, stream>>>(W1, a_src1, a_dst1, ws1, wd1);

  // emb2 (tiny), bf16 out
  sgemm_kernel<bf16><<<(51 * 128 + 63) / 64, 256, 0, stream>>>(emb, Wnode, bnode, emb2_b, 51, 128, 128, 128, 0);

  // ve+te merged, then start, via MFMA
  gemm_mfma_vt<<<dim3(2, 16), 256, 0, stream>>>((const short*)v_b, BpWv, bv,
                                                (const short*)t_b, BpWt, bt, (short*)vt_b);
  gemm_mfma<<<dim3(2, 8), 256, 0, stream>>>((const short*)vt_b, BpWs, bstart, (short*)start_b, 512, 128, 256, 128);

  // fused LN + conv1 scores
  ln_al1_wave<<<NN / 4, 256, 0, stream>>>((const unsigned*)start_b, (const unsigned*)emb2_b,
                                          m_idx, ln_g, ln_b, ws1, wd1, (unsigned*)x0b, als1, ald1);
  alpha1_kernel<<<NN * 4 / 256, 256, 0, stream>>>(als1, ald1, csroff, esrc, aw1, selfw1, inv1);
  agg1y_kernel<<<(int)(((long)NN * 16 + 255) / 256), 256, 0, stream>>>(
      (const uint4*)x0b, (const float4*)aw1, (const float4*)selfw1, (const float4*)inv1,
      csroff, esrc, (uint4*)y1);

  // FUSED conv1 head-GEMM + ELU + conv2 GEMM + al2
  conv12_kernel<<<dim3(1, NN / 64), 256, 0, stream>>>((const short*)y1, Bp1, b1, Bp2,
                                                      a_src2, a_dst2, (short*)xp2b, als2, ald2);

  alpha2_kernel<<<NN / 256, 256, 0, stream>>>(als2, ald2, csroff, esrc, aw2, selfw2, inv2);
  agg2w_kernel<<<(int)(((long)NN * 16 + 255) / 256), 256, 0, stream>>>(
      (const uint4*)xp2b, aw2, selfw2, inv2, csroff, esrc, b2, (float4*)x2);

  // fused pool + h1 + head
  tail_kernel<<<GG, 128, 0, stream>>>(x2, m_idx, Wo1, bo1, Wo2, bo2, out);
}